// Round 2
// baseline (1227.027 us; speedup 1.0000x reference)
//
#include <hip/hip_runtime.h>
#include <hip/hip_bf16.h>

// ---------------------------------------------------------------------------
// PadTransformer R6: R5 + pipelined 256x128 GEMM (gemm_pipe) for ff1/ff2/out:
// 8 waves, BK=64, triple-buffered LDS, 2-deep global_load_lds prefetch,
// counted s_waitcnt vmcnt(6) (never 0 mid-loop), raw s_barrier phases,
// s_setprio around MFMA clusters (T3+T4+T5 on top of the R3 T2 swizzle).
// qkv / attention / LN unchanged.
// ---------------------------------------------------------------------------

typedef __bf16 bf16x8 __attribute__((ext_vector_type(8)));
typedef float  f32x4  __attribute__((ext_vector_type(4)));

__device__ __forceinline__ f32x4 mfma16(bf16x8 a, bf16x8 b, f32x4 c) {
    return __builtin_amdgcn_mfma_f32_16x16x32_bf16(a, b, c, 0, 0, 0);
}

__device__ __forceinline__ void load_lds16(const __bf16* g, __bf16* l) {
    __builtin_amdgcn_global_load_lds(
        (const __attribute__((address_space(1))) void*)g,
        (__attribute__((address_space(3))) void*)l, 16, 0, 0);
}

// bijective XCD swizzle; valid when nwg % 8 == 0 (true for every launch here)
__device__ __forceinline__ int swz8(int o, int nwg) {
    return (o & 7) * (nwg >> 3) + (o >> 3);
}

// ---------------------------------------------------------------------------
__global__ __launch_bounds__(256) void cast_k(const float* __restrict__ in,
                                              __bf16* __restrict__ out, int n4) {
    int i = blockIdx.x * 256 + threadIdx.x;
    if (i >= n4) return;
    float4 f = ((const float4*)in)[i];
    union { uint2 u; __bf16 h[4]; } ob;
    ob.h[0] = (__bf16)f.x; ob.h[1] = (__bf16)f.y;
    ob.h[2] = (__bf16)f.z; ob.h[3] = (__bf16)f.w;
    ((uint2*)out)[i] = ob.u;
}

// ---------------------------------------------------------------------------
// Pipelined GEMM: C[256 x 128] tile of A[M][K] * B[N][K]^T + bias.
// 512 threads = 8 waves (4M x 2N), per-wave 64x64 output (4x4 16x16 frags).
// Triple-buffered LDS K-tiles, 2-deep prefetch, vmcnt(6) per tile.
// Tile order: 1D grid, column-major (by fastest) so each XCD sweeps full M
// of one B-panel run (B panel L2-resident, A streamed via L3).
__global__ __launch_bounds__(512, 1) void gemm_pipe(
    const __bf16* __restrict__ A, const __bf16* __restrict__ B,
    const float* __restrict__ bias, __bf16* __restrict__ C,
    int Mt, int N, int K, float scale, int relu)
{
    __shared__ __bf16 As[3][256 * 64];   // 96 KiB
    __shared__ __bf16 Bs[3][128 * 64];   // 48 KiB
    const int tid = threadIdx.x;
    const int wid = tid >> 6, lane = tid & 63;
    const int lq = lane >> 4, lc = lane & 15;
    const int wm = (wid >> 1) * 64, wn = (wid & 1) * 64;
    const int nwg = gridDim.x;
    const int w = swz8(blockIdx.x, nwg);
    const int bm = (w % Mt) * 256, bn = (w / Mt) * 128;
    const int NT = K >> 6;

    // stage pass p of K-tile t (A: p in 0..3, B: p in 0..1); R3 swizzle on
    // the GLOBAL source, linear LDS dest (both-sides rule).
    auto stageA = [&](int t, int p) {
        const int cc = p * 512 + tid;
        const int row = cc >> 3, gk = ((cc & 7) ^ (row & 7)) * 8;
        load_lds16(A + (size_t)(bm + row) * K + (t * 64 + gk),
                   &As[t % 3][cc * 8]);
    };
    auto stageB = [&](int t, int p) {
        const int cc = p * 512 + tid;
        const int row = cc >> 3, gk = ((cc & 7) ^ (row & 7)) * 8;
        load_lds16(B + (size_t)(bn + row) * K + (t * 64 + gk),
                   &Bs[t % 3][cc * 8]);
    };

    // prologue: stage tiles 0 and 1 (12 loads/wave), wait tile 0 landed
#pragma unroll
    for (int p = 0; p < 4; ++p) stageA(0, p);
#pragma unroll
    for (int p = 0; p < 2; ++p) stageB(0, p);
#pragma unroll
    for (int p = 0; p < 4; ++p) stageA(1, p);
#pragma unroll
    for (int p = 0; p < 2; ++p) stageB(1, p);
    asm volatile("s_waitcnt vmcnt(6)" ::: "memory");
    __builtin_amdgcn_s_barrier();
    __builtin_amdgcn_sched_barrier(0);

    const int sw = lc & 7;
    const f32x4 fz = {0.f, 0.f, 0.f, 0.f};
    f32x4 acc[4][4];
#pragma unroll
    for (int i = 0; i < 4; ++i)
#pragma unroll
        for (int j = 0; j < 4; ++j) acc[i][j] = fz;

    for (int t = 0; t < NT; ++t) {
        const __bf16* Ab = As[t % 3];
        const __bf16* Bb = Bs[t % 3];
        const int pf = (t + 2 < NT);
        bf16x8 af[2][4], bw[2][2];

        // ---- phase A: stage 3, read A-frags + B js {0,1}, MFMA 16 ----
        if (pf) { stageA(t + 2, 0); stageA(t + 2, 1); stageA(t + 2, 2); }
#pragma unroll
        for (int kk = 0; kk < 2; ++kk) {
            const int slot = ((kk * 4 + lq) ^ sw) * 8;
#pragma unroll
            for (int i = 0; i < 4; ++i)
                af[kk][i] = *(const bf16x8*)&Ab[(wm + i * 16 + lc) * 64 + slot];
#pragma unroll
            for (int j = 0; j < 2; ++j)
                bw[kk][j] = *(const bf16x8*)&Bb[(wn + j * 16 + lc) * 64 + slot];
        }
        __builtin_amdgcn_s_barrier();
        __builtin_amdgcn_sched_barrier(0);
        __builtin_amdgcn_s_setprio(1);
#pragma unroll
        for (int kk = 0; kk < 2; ++kk)
#pragma unroll
            for (int i = 0; i < 4; ++i)
#pragma unroll
                for (int j = 0; j < 2; ++j)
                    acc[i][j] = mfma16(af[kk][i], bw[kk][j], acc[i][j]);
        __builtin_amdgcn_s_setprio(0);
        __builtin_amdgcn_s_barrier();
        __builtin_amdgcn_sched_barrier(0);

        // ---- phase B: stage 3, read B js {2,3} (A frags reused), MFMA 16 ----
        if (pf) { stageA(t + 2, 3); stageB(t + 2, 0); stageB(t + 2, 1); }
#pragma unroll
        for (int kk = 0; kk < 2; ++kk) {
            const int slot = ((kk * 4 + lq) ^ sw) * 8;
#pragma unroll
            for (int j = 0; j < 2; ++j)
                bw[kk][j] = *(const bf16x8*)&Bb[(wn + (j + 2) * 16 + lc) * 64 + slot];
        }
        __builtin_amdgcn_s_barrier();
        __builtin_amdgcn_sched_barrier(0);
        __builtin_amdgcn_s_setprio(1);
#pragma unroll
        for (int kk = 0; kk < 2; ++kk)
#pragma unroll
            for (int i = 0; i < 4; ++i)
#pragma unroll
                for (int j = 0; j < 2; ++j)
                    acc[i][j + 2] = mfma16(af[kk][i], bw[kk][j], acc[i][j + 2]);
        __builtin_amdgcn_s_setprio(0);
        // end of tile: ensure tile t+1 fully landed before next reads;
        // leave tile t+2's 6 loads in flight (never drain mid-loop).
        if (pf)                asm volatile("s_waitcnt vmcnt(6)" ::: "memory");
        else if (t + 1 < NT)   asm volatile("s_waitcnt vmcnt(0)" ::: "memory");
        __builtin_amdgcn_s_barrier();
        __builtin_amdgcn_sched_barrier(0);
    }

    // epilogue: bias + scale + relu, bf16 store (same numerics as R5)
#pragma unroll
    for (int j = 0; j < 4; ++j) {
        const int col = bn + wn + j * 16 + lc;
        const float bv = bias[col];
#pragma unroll
        for (int i = 0; i < 4; ++i) {
#pragma unroll
            for (int r = 0; r < 4; ++r) {
                float v = (acc[i][j][r] + bv) * scale;
                if (relu) v = fmaxf(v, 0.f);
                const int row = bm + wm + i * 16 + lq * 4 + r;
                C[(size_t)row * N + col] = (__bf16)v;
            }
        }
    }
}

// ---------------------------------------------------------------------------
// Legacy core (kept for gemm_qkv): C[128 x 64] tile, BK=64, R3 swizzle.
template <int BN>
__device__ __forceinline__ void gemm_core(
    const __bf16* __restrict__ A, const __bf16* __restrict__ B,
    const float* __restrict__ bias, __bf16* __restrict__ C,
    int M, int N, int K, float scale, int relu, int bm, int bn,
    __bf16* As, __bf16* Bs)
{
    const int tid = threadIdx.x;
    const int wave = tid >> 6, lane = tid & 63;
    const int lq = lane >> 4, lc = lane & 15;
    const int WN = BN / 2;
    const int JT = WN / 16;
    const int wm = (wave >> 1) * 64, wn = (wave & 1) * WN;

    const f32x4 fz = {0.f, 0.f, 0.f, 0.f};
    f32x4 acc[4][4];
#pragma unroll
    for (int i = 0; i < 4; ++i)
#pragma unroll
        for (int j = 0; j < JT; ++j) acc[i][j] = fz;

    const int sw = lc & 7;

    for (int k0 = 0; k0 < K; k0 += 64) {
        __syncthreads();
#pragma unroll
        for (int i = 0; i < 4; ++i) {
            const int c = tid + 256 * i;
            const int row = c >> 3, gk = ((c & 7) ^ (row & 7)) * 8;
            load_lds16(A + (size_t)(bm + row) * K + (k0 + gk),
                       As + (size_t)c * 8);
        }
#pragma unroll
        for (int i = 0; i < BN / 32; ++i) {
            const int c = tid + 256 * i;
            const int row = c >> 3, gk = ((c & 7) ^ (row & 7)) * 8;
            load_lds16(B + (size_t)(bn + row) * K + (k0 + gk),
                       Bs + (size_t)c * 8);
        }
        __syncthreads();
#pragma unroll
        for (int kk = 0; kk < 2; ++kk) {
            bf16x8 af[4], bw[4];
            const int slot = ((kk * 4 + lq) ^ sw) * 8;
#pragma unroll
            for (int i = 0; i < 4; ++i)
                af[i] = *(const bf16x8*)&As[(wm + i * 16 + lc) * 64 + slot];
#pragma unroll
            for (int j = 0; j < JT; ++j)
                bw[j] = *(const bf16x8*)&Bs[(wn + j * 16 + lc) * 64 + slot];
#pragma unroll
            for (int i = 0; i < 4; ++i)
#pragma unroll
                for (int j = 0; j < JT; ++j)
                    acc[i][j] = mfma16(af[i], bw[j], acc[i][j]);
        }
    }

#pragma unroll
    for (int j = 0; j < JT; ++j) {
        const int col = bn + wn + j * 16 + lc;
        const float bv = bias[col];
#pragma unroll
        for (int i = 0; i < 4; ++i) {
#pragma unroll
            for (int r = 0; r < 4; ++r) {
                float v = (acc[i][j][r] + bv) * scale;
                if (relu) v = fmaxf(v, 0.f);
                const int row = bm + wm + i * 16 + lq * 4 + r;
                C[(size_t)row * N + col] = (__bf16)v;
            }
        }
    }
}

// Fused q/k/v projection: flat grid 1536 blocks, BN=64.
__global__ __launch_bounds__(256) void gemm_qkv(
    const __bf16* __restrict__ TGT, const __bf16* __restrict__ KIN,
    const __bf16* __restrict__ VIN, const __bf16* __restrict__ W,
    const float* __restrict__ bias, __bf16* __restrict__ PROJ,
    __bf16* __restrict__ KB, __bf16* __restrict__ VB)
{
    __shared__ __bf16 As[128 * 64];
    __shared__ __bf16 Bs[64 * 64];
    const int bid = swz8(blockIdx.x, 1536);   // XCD-contiguous tile runs
    const __bf16* A; __bf16* Cout; int M, t, seg; float scale;
    if (bid < 1024)      { seg = 0; t = bid;        A = TGT; Cout = PROJ; M = 8192; scale = 0.125f; }
    else if (bid < 1280) { seg = 1; t = bid - 1024; A = KIN; Cout = KB;   M = 2048; scale = 1.f; }
    else                 { seg = 2; t = bid - 1280; A = VIN; Cout = VB;   M = 2048; scale = 1.f; }
    gemm_core<64>(A, W + (size_t)seg * 1048576, bias + seg * 1024, Cout,
                  M, 1024, 1024, scale, 0, (t >> 4) * 128, (t & 15) * 64, As, Bs);
}

// ---------------------------------------------------------------------------
// transpose V per (n,h): vt[(n*16+h)*64 + d][s] = v[(s*2+n)*1024 + h*64 + d]
__global__ __launch_bounds__(256) void transpose_v(const __bf16* __restrict__ v,
                                                   __bf16* __restrict__ vt) {
    __shared__ __bf16 t[64][72];
    const int tid = threadIdx.x;
    const int s0 = blockIdx.x * 64, h = blockIdx.y, n = blockIdx.z;
#pragma unroll
    for (int i = 0; i < 2; ++i) {
        const int cc = tid + 256 * i, row = cc >> 3, kc = (cc & 7) * 8;
        *(uint4*)&t[row][kc] =
            *(const uint4*)(v + ((size_t)((s0 + row) * 2 + n)) * 1024 + h * 64 + kc);
    }
    __syncthreads();
#pragma unroll
    for (int i = 0; i < 2; ++i) {
        const int cc = tid + 256 * i, d = cc >> 3, jc = (cc & 7) * 8;
        __attribute__((aligned(16))) __bf16 tmp[8];
#pragma unroll
        for (int u = 0; u < 8; ++u) tmp[u] = t[jc + u][d];
        *(uint4*)(vt + ((size_t)((n * 16 + h) * 64 + d)) * 1024 + s0 + jc) = *(uint4*)tmp;
    }
}

// ---------------------------------------------------------------------------
// Fused attention (R2 design): O = (sum e^s v) / (1 + sum e^s); cvec saved.
__global__ __launch_bounds__(256) void attn_fused(
    const __bf16* __restrict__ q, const __bf16* __restrict__ kk,
    const __bf16* __restrict__ vt, float* __restrict__ cvec,
    __bf16* __restrict__ aout)
{
    __shared__ __bf16 qs[64][72];
    __shared__ __bf16 ks[64][72];
    __shared__ __bf16 vs[64][72];
    __shared__ __bf16 es[64][72];
    const int tid = threadIdx.x, wave = tid >> 6, lane = tid & 63;
    const int lq = lane >> 4, lc = lane & 15;
    const int o = (blockIdx.z * 16 + blockIdx.y) * 64 + blockIdx.x;
    const int w = swz8(o, 2048);
    const int l0 = (w & 63) * 64, h = (w >> 6) & 15, n = w >> 10;
    const int wr = wave * 16;
#pragma unroll
    for (int i = 0; i < 2; ++i) {
        const int cc = tid + 256 * i, row = cc >> 3, kc = (cc & 7) * 8;
        *(uint4*)&qs[row][kc] =
            *(const uint4*)(q + ((size_t)((l0 + row) * 2 + n)) * 1024 + h * 64 + kc);
    }
    const f32x4 fz = {0.f, 0.f, 0.f, 0.f};
    f32x4 oacc[4];
#pragma unroll
    for (int dj = 0; dj < 4; ++dj) oacc[dj] = fz;
    float den[4] = {0.f, 0.f, 0.f, 0.f};

    for (int st = 0; st < 16; ++st) {
        __syncthreads();
#pragma unroll
        for (int i = 0; i < 2; ++i) {
            const int cc = tid + 256 * i, row = cc >> 3, kc = (cc & 7) * 8;
            *(uint4*)&ks[row][kc] =
                *(const uint4*)(kk + ((size_t)((st * 64 + row) * 2 + n)) * 1024 + h * 64 + kc);
            *(uint4*)&vs[row][kc] =
                *(const uint4*)(vt + ((size_t)((n * 16 + h) * 64 + row)) * 1024 + st * 64 + kc);
        }
        __syncthreads();
        const bf16x8 a0 = *(const bf16x8*)&qs[wr + lc][lq * 8];
        const bf16x8 a1 = *(const bf16x8*)&qs[wr + lc][32 + lq * 8];
#pragma unroll
        for (int sj = 0; sj < 4; ++sj) {
            f32x4 acc = fz;
            const bf16x8 b0 = *(const bf16x8*)&ks[sj * 16 + lc][lq * 8];
            const bf16x8 b1 = *(const bf16x8*)&ks[sj * 16 + lc][32 + lq * 8];
            acc = mfma16(a0, b0, acc);
            acc = mfma16(a1, b1, acc);
#pragma unroll
            for (int r = 0; r < 4; ++r) {
                const float e = __expf(acc[r]);
                den[r] += e;
                es[wr + lq * 4 + r][sj * 16 + lc] = (__bf16)e;
            }
        }
        const bf16x8 w0 = *(const bf16x8*)&es[wr + lc][lq * 8];
        const bf16x8 w1 = *(const bf16x8*)&es[wr + lc][32 + lq * 8];
#pragma unroll
        for (int dj = 0; dj < 4; ++dj) {
            const bf16x8 v0 = *(const bf16x8*)&vs[dj * 16 + lc][lq * 8];
            const bf16x8 v1 = *(const bf16x8*)&vs[dj * 16 + lc][32 + lq * 8];
            oacc[dj] = mfma16(w0, v0, oacc[dj]);
            oacc[dj] = mfma16(w1, v1, oacc[dj]);
        }
    }
#pragma unroll
    for (int m = 1; m < 16; m <<= 1)
#pragma unroll
        for (int r = 0; r < 4; ++r) den[r] += __shfl_xor(den[r], m);
    float c_r[4];
#pragma unroll
    for (int r = 0; r < 4; ++r) c_r[r] = 1.f / (den[r] + 1.f);
    if (lc == 0) {
#pragma unroll
        for (int r = 0; r < 4; ++r)
            cvec[((size_t)(n * 16 + h)) * 4096 + (l0 + wr + lq * 4 + r)] = c_r[r];
    }
#pragma unroll
    for (int dj = 0; dj < 4; ++dj)
#pragma unroll
        for (int r = 0; r < 4; ++r) {
            const int l = l0 + wr + lq * 4 + r;
            aout[((size_t)l * 2 + n) * 1024 + h * 64 + dj * 16 + lc] =
                (__bf16)(oacc[dj][r] * c_r[r]);
        }
}

// ---------------------------------------------------------------------------
// attn_map[n][l][s] = mean_h sigmoid(w); sigmoid via Taylor poly on (0,1).
__global__ __launch_bounds__(256) void attn_map_k(
    const __bf16* __restrict__ q, const __bf16* __restrict__ kk,
    const float* __restrict__ cvec, float* __restrict__ amap)
{
    __shared__ __bf16 qs[64][72];
    __shared__ __bf16 ks[64][72];
    const int tid = threadIdx.x, wave = tid >> 6, lane = tid & 63;
    const int lq = lane >> 4, lc = lane & 15;
    const int o = (blockIdx.z * 16 + blockIdx.y) * 64 + blockIdx.x;
    const int w = swz8(o, 2048);
    const int l0 = (w & 63) * 64, st = (w >> 6) & 15, n = w >> 10;
    const int wr = wave * 16;
    float sig[4][4];
#pragma unroll
    for (int sj = 0; sj < 4; ++sj)
#pragma unroll
        for (int r = 0; r < 4; ++r) sig[sj][r] = 0.f;

    for (int h = 0; h < 16; ++h) {
        __syncthreads();
#pragma unroll
        for (int i = 0; i < 2; ++i) {
            const int cc = tid + 256 * i, row = cc >> 3, kc = (cc & 7) * 8;
            *(uint4*)&qs[row][kc] =
                *(const uint4*)(q + ((size_t)((l0 + row) * 2 + n)) * 1024 + h * 64 + kc);
            *(uint4*)&ks[row][kc] =
                *(const uint4*)(kk + ((size_t)((st * 64 + row) * 2 + n)) * 1024 + h * 64 + kc);
        }
        __syncthreads();
        float c_r[4];
#pragma unroll
        for (int r = 0; r < 4; ++r)
            c_r[r] = cvec[((size_t)(n * 16 + h)) * 4096 + (l0 + wr + lq * 4 + r)];
        const bf16x8 a0 = *(const bf16x8*)&qs[wr + lc][lq * 8];
        const bf16x8 a1 = *(const bf16x8*)&qs[wr + lc][32 + lq * 8];
#pragma unroll
        for (int sj = 0; sj < 4; ++sj) {
            const f32x4 fz = {0.f, 0.f, 0.f, 0.f};
            f32x4 acc = fz;
            const bf16x8 b0 = *(const bf16x8*)&ks[sj * 16 + lc][lq * 8];
            const bf16x8 b1 = *(const bf16x8*)&ks[sj * 16 + lc][32 + lq * 8];
            acc = mfma16(a0, b0, acc);
            acc = mfma16(a1, b1, acc);
#pragma unroll
            for (int r = 0; r < 4; ++r) {
                const float ww = __expf(acc[r]) * c_r[r];   // w in (0,1)
                const float w2 = ww * ww;
                sig[sj][r] += 0.5f + ww * (0.25f - w2 * (1.f / 48.f - w2 * (1.f / 480.f)));
            }
        }
    }
#pragma unroll
    for (int sj = 0; sj < 4; ++sj)
#pragma unroll
        for (int r = 0; r < 4; ++r) {
            const int l = l0 + wr + lq * 4 + r;
            const int s = st * 64 + sj * 16 + lc;
            amap[((size_t)n * 4096 + l) * 1024 + s] = sig[sj][r] * (1.f / 16.f);
        }
}

// ---------------------------------------------------------------------------
// y = LN(base + add) * g + b; base is f32 (basef) or bf16 (baseb).
__global__ __launch_bounds__(256) void ln_k(
    const float* __restrict__ basef, const __bf16* __restrict__ baseb,
    const __bf16* __restrict__ add,
    const float* __restrict__ g, const float* __restrict__ bb,
    float* __restrict__ out_f32, __bf16* __restrict__ out_bf)
{
    __shared__ float red[8];
    const int row = blockIdx.x, tid = threadIdx.x;
    const int col = tid * 4;
    const size_t off = (size_t)row * 1024 + col;
    float v[4];
    if (basef) {
        float4 t = *(const float4*)(basef + off);
        v[0] = t.x; v[1] = t.y; v[2] = t.z; v[3] = t.w;
    } else {
        union { uint2 u; __bf16 h[4]; } tb;
        tb.u = *(const uint2*)(baseb + off);
#pragma unroll
        for (int j = 0; j < 4; ++j) v[j] = (float)tb.h[j];
    }
    {
        union { uint2 u; __bf16 h[4]; } ub;
        ub.u = *(const uint2*)(add + off);
#pragma unroll
        for (int j = 0; j < 4; ++j) v[j] += (float)ub.h[j];
    }
    float s = v[0] + v[1] + v[2] + v[3];
    float q = v[0] * v[0] + v[1] * v[1] + v[2] * v[2] + v[3] * v[3];
#pragma unroll
    for (int m = 1; m < 64; m <<= 1) { s += __shfl_xor(s, m); q += __shfl_xor(q, m); }
    const int wave = tid >> 6, lane = tid & 63;
    if (lane == 0) { red[wave] = s; red[4 + wave] = q; }
    __syncthreads();
    s = red[0] + red[1] + red[2] + red[3];
    q = red[4] + red[5] + red[6] + red[7];
    const float mu = s * (1.f / 1024.f);
    const float var = q * (1.f / 1024.f) - mu * mu;
    const float rs = rsqrtf(var + 1e-5f);
    const float4 gv = *(const float4*)(g + col);
    const float4 bv = *(const float4*)(bb + col);
    float y[4];
    y[0] = (v[0] - mu) * rs * gv.x + bv.x;
    y[1] = (v[1] - mu) * rs * gv.y + bv.y;
    y[2] = (v[2] - mu) * rs * gv.z + bv.z;
    y[3] = (v[3] - mu) * rs * gv.w + bv.w;
    if (out_f32) {
        float4 o; o.x = y[0]; o.y = y[1]; o.z = y[2]; o.w = y[3];
        *(float4*)(out_f32 + off) = o;
    }
    if (out_bf) {
        union { uint2 u; __bf16 h[4]; } ob;
#pragma unroll
        for (int j = 0; j < 4; ++j) ob.h[j] = (__bf16)y[j];
        *(uint2*)(out_bf + off) = ob.u;
    }
}

// ---------------------------------------------------------------------------
extern "C" void kernel_launch(void* const* d_in, const int* in_sizes, int n_in,
                              void* d_out, int out_size, void* d_ws, size_t ws_size,
                              hipStream_t stream) {
    const float* key_in    = (const float*)d_in[0];
    const float* value_in  = (const float*)d_in[1];
    const float* query     = (const float*)d_in[2];
    const float* in_proj_w = (const float*)d_in[3];
    const float* in_proj_b = (const float*)d_in[4];
    const float* out_w     = (const float*)d_in[5];
    const float* out_b     = (const float*)d_in[6];
    const float* ln1_g     = (const float*)d_in[7];
    const float* ln1_b     = (const float*)d_in[8];
    const float* ln2_g     = (const float*)d_in[9];
    const float* ln2_b     = (const float*)d_in[10];
    const float* ff1_w     = (const float*)d_in[11];
    const float* ff1_b     = (const float*)d_in[12];
    const float* ff2_w     = (const float*)d_in[13];
    const float* ff2_b     = (const float*)d_in[14];
    float* outp = (float*)d_out;

    __bf16* ws = (__bf16*)d_ws;
    const size_t M1 = 1048576;
    __bf16* WQKV = ws;               // 6 M1 (both layers)
    __bf16* WOUT = ws + 6 * M1;      // 2
    __bf16* WF1  = ws + 8 * M1;      // 8
    __bf16* WF2  = ws + 16 * M1;     // 8
    __bf16* KIN  = ws + 24 * M1;     // 2
    __bf16* VIN  = ws + 26 * M1;     // 2
    __bf16* TGT  = ws + 28 * M1;     // 8
    __bf16* PROJ = ws + 36 * M1;     // 8 (q-proj out; out-proj out)
    __bf16* KB   = ws + 44 * M1;     // 2
    __bf16* VB   = ws + 46 * M1;     // 2
    __bf16* VT   = ws + 48 * M1;     // 2
    __bf16* AOUT = ws + 50 * M1;     // 8 (attn out; ff2 out)
    __bf16* XB   = ws + 58 * M1;     // 8 (ln1 out, bf16)
    __bf16* H1   = ws + 66 * M1;     // 32
    float*  CVEC = (float*)(ws + 98 * M1);   // 131072 f32

    // upfront casts: inputs + ALL weights (both layers)
    cast_k<<<8192, 256, 0, stream>>>(query, TGT, 2097152);
    cast_k<<<2048, 256, 0, stream>>>(key_in, KIN, 524288);
    cast_k<<<2048, 256, 0, stream>>>(value_in, VIN, 524288);
    cast_k<<<6144, 256, 0, stream>>>(in_proj_w, WQKV, 1572864);
    cast_k<<<2048, 256, 0, stream>>>(out_w, WOUT, 524288);
    cast_k<<<8192, 256, 0, stream>>>(ff1_w, WF1, 2097152);
    cast_k<<<8192, 256, 0, stream>>>(ff2_w, WF2, 2097152);

    for (int i = 0; i < 2; ++i) {
        __bf16* WQKVi = WQKV + (size_t)i * 3 * M1;
        __bf16* WOUTi = WOUT + (size_t)i * M1;
        __bf16* WF1i  = WF1 + (size_t)i * 4 * M1;
        __bf16* WF2i  = WF2 + (size_t)i * 4 * M1;

        // fused q/k/v projections (one dispatch, 1536 blocks)
        gemm_qkv<<<1536, 256, 0, stream>>>(TGT, KIN, VIN, WQKVi,
                                           in_proj_b + i * 3072, PROJ, KB, VB);
        transpose_v<<<dim3(16, 16, 2), 256, 0, stream>>>(VB, VT);

        attn_fused<<<dim3(64, 16, 2), 256, 0, stream>>>(PROJ, KB, VT, CVEC, AOUT);
        if (i == 1)
            attn_map_k<<<dim3(64, 16, 2), 256, 0, stream>>>(PROJ, KB, CVEC,
                                                            outp + 8388608);

        // out projection: pipelined 256x128 tiles (256 blocks = 1 CU round)
        gemm_pipe<<<256, 512, 0, stream>>>(AOUT, WOUTi, out_b + i * 1024,
                                           PROJ, 32, 1024, 1024, 1.f, 0);
        // LN1: base = query (f32, layer 0) or TGT (bf16)
        ln_k<<<8192, 256, 0, stream>>>(i == 0 ? query : nullptr,
                                       i == 0 ? nullptr : TGT,
                                       PROJ, ln1_g + i * 1024, ln1_b + i * 1024,
                                       nullptr, XB);
        // FFN (pipelined)
        gemm_pipe<<<1024, 512, 0, stream>>>(XB, WF1i, ff1_b + i * 4096,
                                            H1, 32, 4096, 1024, 1.f, 1);
        gemm_pipe<<<256, 512, 0, stream>>>(H1, WF2i, ff2_b + i * 1024,
                                           AOUT, 32, 1024, 4096, 1.f, 0);
        // LN2: base = XB (bf16); final layer also writes f32 tgt to d_out
        ln_k<<<8192, 256, 0, stream>>>(nullptr, XB, AOUT,
                                       ln2_g + i * 1024, ln2_b + i * 1024,
                                       i == 1 ? outp : nullptr, TGT);
    }
}

// Round 3
// 983.637 us; speedup vs baseline: 1.2474x; 1.2474x over previous
//
#include <hip/hip_runtime.h>
#include <hip/hip_bf16.h>

// ---------------------------------------------------------------------------
// PadTransformer R7: R5 base (gemm64/gemm_qkv/attn/LN unchanged) + m201-style
// 8-phase 256x256 pipelined GEMM (gemm8p) for ff1 ONLY.
// gemm8p: 512 thr = 8 waves (2M x 4N), per-wave 128x64 C. BK=64.
// LDS = 8 half-tile slots (128rows x 64K = 16 KiB each) = 128 KiB.
// Per K-tile: 4 phases, each {ds_read subtile || stage half-tiles || 16 MFMA
// between raw s_barriers}; stages target tile t+2; vmcnt(8) once per K-tile.
// Stage order (B at phase2, A at phase3) derived so slot overwrites are
// always >=1 barrier after last read and >=4 phases before first read.
// ---------------------------------------------------------------------------

typedef __bf16 bf16x8 __attribute__((ext_vector_type(8)));
typedef float  f32x4  __attribute__((ext_vector_type(4)));

__device__ __forceinline__ f32x4 mfma16(bf16x8 a, bf16x8 b, f32x4 c) {
    return __builtin_amdgcn_mfma_f32_16x16x32_bf16(a, b, c, 0, 0, 0);
}

__device__ __forceinline__ void load_lds16(const __bf16* g, __bf16* l) {
    __builtin_amdgcn_global_load_lds(
        (const __attribute__((address_space(1))) void*)g,
        (__attribute__((address_space(3))) void*)l, 16, 0, 0);
}

// bijective XCD swizzle; valid when nwg % 8 == 0 (true for every launch here)
__device__ __forceinline__ int swz8(int o, int nwg) {
    return (o & 7) * (nwg >> 3) + (o >> 3);
}

// ---------------------------------------------------------------------------
__global__ __launch_bounds__(256) void cast_k(const float* __restrict__ in,
                                              __bf16* __restrict__ out, int n4) {
    int i = blockIdx.x * 256 + threadIdx.x;
    if (i >= n4) return;
    float4 f = ((const float4*)in)[i];
    union { uint2 u; __bf16 h[4]; } ob;
    ob.h[0] = (__bf16)f.x; ob.h[1] = (__bf16)f.y;
    ob.h[2] = (__bf16)f.z; ob.h[3] = (__bf16)f.w;
    ((uint2*)out)[i] = ob.u;
}

// ---------------------------------------------------------------------------
// 8-phase pipelined 256x256 GEMM (ff1). C = A[M][K] * B[N][K]^T + bias.
__global__ __launch_bounds__(512, 2) void gemm8p(
    const __bf16* __restrict__ A, const __bf16* __restrict__ B,
    const float* __restrict__ bias, __bf16* __restrict__ C,
    int Mt, int N, int K, float scale, int relu)
{
    // 8 half-tile slots: [parity*4 + {0:A-top,1:A-bot,2:B-left,3:B-right}]
    __shared__ __bf16 L[8][8192];      // 128 KiB
    const int tid = threadIdx.x;
    const int wid = tid >> 6, lane = tid & 63;
    const int lq = lane >> 4, lc = lane & 15;
    const int wm = wid >> 2;           // row half (0/1): rows [wm*128, +128)
    const int wn = (wid & 3) * 64;     // col base: 0,64,128,192
    const int bh = wn >> 7;            // B half id
    const int lb = wn & 127;           // local col within B half (0 or 64)
    const int sw = lc & 7;
    const int w = swz8(blockIdx.x, gridDim.x);
    const int bm = (w % Mt) * 256, bn = (w / Mt) * 256;
    const int NT = K >> 6;

    // stage one half-tile (128 rows x 64 K) = 2 x global_load_lds per thread.
    // R3 swizzle on the GLOBAL source, linear LDS dest (both-sides rule).
    auto stageA = [&](int kt, int h) {
#pragma unroll
        for (int p = 0; p < 2; ++p) {
            const int cc = p * 512 + tid;
            const int row = cc >> 3, gk = ((cc & 7) ^ (row & 7)) * 8;
            load_lds16(A + (size_t)(bm + h * 128 + row) * K + (kt * 64 + gk),
                       &L[(kt & 1) * 4 + h][(size_t)cc * 8]);
        }
    };
    auto stageB = [&](int kt, int h) {
#pragma unroll
        for (int p = 0; p < 2; ++p) {
            const int cc = p * 512 + tid;
            const int row = cc >> 3, gk = ((cc & 7) ^ (row & 7)) * 8;
            load_lds16(B + (size_t)(bn + h * 128 + row) * K + (kt * 64 + gk),
                       &L[(kt & 1) * 4 + 2 + h][(size_t)cc * 8]);
        }
    };

    // prologue: stage K-tiles 0 and 1 (16 loads); wait tile 0 landed (8 left)
    stageA(0, 0); stageA(0, 1); stageB(0, 0); stageB(0, 1);
    stageA(1, 0); stageA(1, 1); stageB(1, 0); stageB(1, 1);
    asm volatile("s_waitcnt vmcnt(8)" ::: "memory");
    __builtin_amdgcn_s_barrier();
    __builtin_amdgcn_sched_barrier(0);

    const f32x4 fz = {0.f, 0.f, 0.f, 0.f};
    f32x4 acc[2][4][4];                 // [rowhalf][i][ch*2+j]
#pragma unroll
    for (int rh = 0; rh < 2; ++rh)
#pragma unroll
        for (int i = 0; i < 4; ++i)
#pragma unroll
            for (int jj = 0; jj < 4; ++jj) acc[rh][i][jj] = fz;

    for (int t = 0; t < NT; ++t) {
        const __bf16* __restrict__ Ah = &L[(t & 1) * 4 + wm][0];
        const __bf16* __restrict__ Bh = &L[(t & 1) * 4 + 2 + bh][0];
        const int pf = (t + 2 < NT);
        bf16x8 a[2][4], b0[2][2], b1[2][2];

        // ---- phase 0: read A rows 0-63 + B cols lb+0..31; MFMA quad (0,0)
#pragma unroll
        for (int kk = 0; kk < 2; ++kk) {
            const int sl = ((kk * 4 + lq) ^ sw) * 8;
#pragma unroll
            for (int i = 0; i < 4; ++i)
                a[kk][i] = *(const bf16x8*)&Ah[(i * 16 + lc) * 64 + sl];
#pragma unroll
            for (int j = 0; j < 2; ++j)
                b0[kk][j] = *(const bf16x8*)&Bh[(lb + j * 16 + lc) * 64 + sl];
        }
        __builtin_amdgcn_s_barrier();
        asm volatile("s_waitcnt lgkmcnt(0)" ::: "memory");
        __builtin_amdgcn_sched_barrier(0);
        __builtin_amdgcn_s_setprio(1);
#pragma unroll
        for (int kk = 0; kk < 2; ++kk)
#pragma unroll
            for (int i = 0; i < 4; ++i)
#pragma unroll
                for (int j = 0; j < 2; ++j)
                    acc[0][i][j] = mfma16(a[kk][i], b0[kk][j], acc[0][i][j]);
        __builtin_amdgcn_s_setprio(0);
        __builtin_amdgcn_s_barrier();
        __builtin_amdgcn_sched_barrier(0);

        // ---- phase 1: read B cols lb+32..63; MFMA quad (0,1)
#pragma unroll
        for (int kk = 0; kk < 2; ++kk) {
            const int sl = ((kk * 4 + lq) ^ sw) * 8;
#pragma unroll
            for (int j = 0; j < 2; ++j)
                b1[kk][j] = *(const bf16x8*)&Bh[(lb + 32 + j * 16 + lc) * 64 + sl];
        }
        __builtin_amdgcn_s_barrier();
        asm volatile("s_waitcnt lgkmcnt(0)" ::: "memory");
        __builtin_amdgcn_sched_barrier(0);
        __builtin_amdgcn_s_setprio(1);
#pragma unroll
        for (int kk = 0; kk < 2; ++kk)
#pragma unroll
            for (int i = 0; i < 4; ++i)
#pragma unroll
                for (int j = 0; j < 2; ++j)
                    acc[0][i][2 + j] = mfma16(a[kk][i], b1[kk][j], acc[0][i][2 + j]);
        __builtin_amdgcn_s_setprio(0);
        __builtin_amdgcn_s_barrier();
        __builtin_amdgcn_sched_barrier(0);

        // ---- phase 2: read A rows 64-127; stage B(t+2); MFMA quad (1,0)
#pragma unroll
        for (int kk = 0; kk < 2; ++kk) {
            const int sl = ((kk * 4 + lq) ^ sw) * 8;
#pragma unroll
            for (int i = 0; i < 4; ++i)
                a[kk][i] = *(const bf16x8*)&Ah[(64 + i * 16 + lc) * 64 + sl];
        }
        if (pf) { stageB(t + 2, 0); stageB(t + 2, 1); }
        __builtin_amdgcn_s_barrier();
        asm volatile("s_waitcnt lgkmcnt(0)" ::: "memory");
        __builtin_amdgcn_sched_barrier(0);
        __builtin_amdgcn_s_setprio(1);
#pragma unroll
        for (int kk = 0; kk < 2; ++kk)
#pragma unroll
            for (int i = 0; i < 4; ++i)
#pragma unroll
                for (int j = 0; j < 2; ++j)
                    acc[1][i][j] = mfma16(a[kk][i], b0[kk][j], acc[1][i][j]);
        __builtin_amdgcn_s_setprio(0);
        __builtin_amdgcn_s_barrier();
        __builtin_amdgcn_sched_barrier(0);

        // ---- phase 3: stage A(t+2); MFMA quad (1,1); per-tile vmcnt
        if (pf) { stageA(t + 2, 0); stageA(t + 2, 1); }
        __builtin_amdgcn_s_barrier();
        __builtin_amdgcn_sched_barrier(0);
        __builtin_amdgcn_s_setprio(1);
#pragma unroll
        for (int kk = 0; kk < 2; ++kk)
#pragma unroll
            for (int i = 0; i < 4; ++i)
#pragma unroll
                for (int j = 0; j < 2; ++j)
                    acc[1][i][2 + j] = mfma16(a[kk][i], b1[kk][j], acc[1][i][2 + j]);
        __builtin_amdgcn_s_setprio(0);
        // ensure tile t+1 fully landed before its phase-0 reads; keep tile
        // t+2's 8 loads in flight (counted, never a mid-loop drain).
        if (pf) asm volatile("s_waitcnt vmcnt(8)" ::: "memory");
        else    asm volatile("s_waitcnt vmcnt(0)" ::: "memory");
        __builtin_amdgcn_s_barrier();
        __builtin_amdgcn_sched_barrier(0);
    }

    // epilogue: bias + scale + relu, bf16 store (same FP order as R5)
#pragma unroll
    for (int ch = 0; ch < 2; ++ch)
#pragma unroll
        for (int j = 0; j < 2; ++j) {
            const int col = bn + wn + ch * 32 + j * 16 + lc;
            const float bv = bias[col];
#pragma unroll
            for (int rh = 0; rh < 2; ++rh)
#pragma unroll
                for (int i = 0; i < 4; ++i)
#pragma unroll
                    for (int r = 0; r < 4; ++r) {
                        float v = (acc[rh][i][ch * 2 + j][r] + bv) * scale;
                        if (relu) v = fmaxf(v, 0.f);
                        const int row = bm + wm * 128 + rh * 64 + i * 16 + lq * 4 + r;
                        C[(size_t)row * N + col] = (__bf16)v;
                    }
        }
}

// ---------------------------------------------------------------------------
// Legacy 2-phase core (qkv / ff2 / out-proj): C[128 x BN] tile, BK=64.
template <int BN>
__device__ __forceinline__ void gemm_core(
    const __bf16* __restrict__ A, const __bf16* __restrict__ B,
    const float* __restrict__ bias, __bf16* __restrict__ C,
    int M, int N, int K, float scale, int relu, int bm, int bn,
    __bf16* As, __bf16* Bs)
{
    const int tid = threadIdx.x;
    const int wave = tid >> 6, lane = tid & 63;
    const int lq = lane >> 4, lc = lane & 15;
    const int WN = BN / 2;
    const int JT = WN / 16;
    const int wm = (wave >> 1) * 64, wn = (wave & 1) * WN;

    const f32x4 fz = {0.f, 0.f, 0.f, 0.f};
    f32x4 acc[4][4];
#pragma unroll
    for (int i = 0; i < 4; ++i)
#pragma unroll
        for (int j = 0; j < JT; ++j) acc[i][j] = fz;

    const int sw = lc & 7;

    for (int k0 = 0; k0 < K; k0 += 64) {
        __syncthreads();
#pragma unroll
        for (int i = 0; i < 4; ++i) {
            const int c = tid + 256 * i;
            const int row = c >> 3, gk = ((c & 7) ^ (row & 7)) * 8;
            load_lds16(A + (size_t)(bm + row) * K + (k0 + gk),
                       As + (size_t)c * 8);
        }
#pragma unroll
        for (int i = 0; i < BN / 32; ++i) {
            const int c = tid + 256 * i;
            const int row = c >> 3, gk = ((c & 7) ^ (row & 7)) * 8;
            load_lds16(B + (size_t)(bn + row) * K + (k0 + gk),
                       Bs + (size_t)c * 8);
        }
        __syncthreads();
#pragma unroll
        for (int kk = 0; kk < 2; ++kk) {
            bf16x8 af[4], bw[4];
            const int slot = ((kk * 4 + lq) ^ sw) * 8;
#pragma unroll
            for (int i = 0; i < 4; ++i)
                af[i] = *(const bf16x8*)&As[(wm + i * 16 + lc) * 64 + slot];
#pragma unroll
            for (int j = 0; j < JT; ++j)
                bw[j] = *(const bf16x8*)&Bs[(wn + j * 16 + lc) * 64 + slot];
#pragma unroll
            for (int i = 0; i < 4; ++i)
#pragma unroll
                for (int j = 0; j < JT; ++j)
                    acc[i][j] = mfma16(af[i], bw[j], acc[i][j]);
        }
    }

#pragma unroll
    for (int j = 0; j < JT; ++j) {
        const int col = bn + wn + j * 16 + lc;
        const float bv = bias[col];
#pragma unroll
        for (int i = 0; i < 4; ++i) {
#pragma unroll
            for (int r = 0; r < 4; ++r) {
                float v = (acc[i][j][r] + bv) * scale;
                if (relu) v = fmaxf(v, 0.f);
                const int row = bm + wm + i * 16 + lq * 4 + r;
                C[(size_t)row * N + col] = (__bf16)v;
            }
        }
    }
}

__global__ __launch_bounds__(256) void gemm64(
    const __bf16* __restrict__ A, const __bf16* __restrict__ B,
    const float* __restrict__ bias, __bf16* __restrict__ C,
    int M, int N, int K, float scale, int relu)
{
    __shared__ __bf16 As[128 * 64];
    __shared__ __bf16 Bs[64 * 64];
    const int nwg = gridDim.x * gridDim.y;
    const int o = blockIdx.y * gridDim.x + blockIdx.x;
    const int w = swz8(o, nwg);
    const int bx = w % gridDim.x, by = w / gridDim.x;
    gemm_core<64>(A, B, bias, C, M, N, K, scale, relu,
                  by * 128, bx * 64, As, Bs);
}

// Fused q/k/v projection: flat grid 1536 blocks, BN=64.
__global__ __launch_bounds__(256) void gemm_qkv(
    const __bf16* __restrict__ TGT, const __bf16* __restrict__ KIN,
    const __bf16* __restrict__ VIN, const __bf16* __restrict__ W,
    const float* __restrict__ bias, __bf16* __restrict__ PROJ,
    __bf16* __restrict__ KB, __bf16* __restrict__ VB)
{
    __shared__ __bf16 As[128 * 64];
    __shared__ __bf16 Bs[64 * 64];
    const int bid = swz8(blockIdx.x, 1536);   // XCD-contiguous tile runs
    const __bf16* A; __bf16* Cout; int M, t, seg; float scale;
    if (bid < 1024)      { seg = 0; t = bid;        A = TGT; Cout = PROJ; M = 8192; scale = 0.125f; }
    else if (bid < 1280) { seg = 1; t = bid - 1024; A = KIN; Cout = KB;   M = 2048; scale = 1.f; }
    else                 { seg = 2; t = bid - 1280; A = VIN; Cout = VB;   M = 2048; scale = 1.f; }
    gemm_core<64>(A, W + (size_t)seg * 1048576, bias + seg * 1024, Cout,
                  M, 1024, 1024, scale, 0, (t >> 4) * 128, (t & 15) * 64, As, Bs);
}

// ---------------------------------------------------------------------------
// transpose V per (n,h): vt[(n*16+h)*64 + d][s] = v[(s*2+n)*1024 + h*64 + d]
__global__ __launch_bounds__(256) void transpose_v(const __bf16* __restrict__ v,
                                                   __bf16* __restrict__ vt) {
    __shared__ __bf16 t[64][72];
    const int tid = threadIdx.x;
    const int s0 = blockIdx.x * 64, h = blockIdx.y, n = blockIdx.z;
#pragma unroll
    for (int i = 0; i < 2; ++i) {
        const int cc = tid + 256 * i, row = cc >> 3, kc = (cc & 7) * 8;
        *(uint4*)&t[row][kc] =
            *(const uint4*)(v + ((size_t)((s0 + row) * 2 + n)) * 1024 + h * 64 + kc);
    }
    __syncthreads();
#pragma unroll
    for (int i = 0; i < 2; ++i) {
        const int cc = tid + 256 * i, d = cc >> 3, jc = (cc & 7) * 8;
        __attribute__((aligned(16))) __bf16 tmp[8];
#pragma unroll
        for (int u = 0; u < 8; ++u) tmp[u] = t[jc + u][d];
        *(uint4*)(vt + ((size_t)((n * 16 + h) * 64 + d)) * 1024 + s0 + jc) = *(uint4*)tmp;
    }
}

// ---------------------------------------------------------------------------
// Fused attention (R2 design): O = (sum e^s v) / (1 + sum e^s); cvec saved.
__global__ __launch_bounds__(256) void attn_fused(
    const __bf16* __restrict__ q, const __bf16* __restrict__ kk,
    const __bf16* __restrict__ vt, float* __restrict__ cvec,
    __bf16* __restrict__ aout)
{
    __shared__ __bf16 qs[64][72];
    __shared__ __bf16 ks[64][72];
    __shared__ __bf16 vs[64][72];
    __shared__ __bf16 es[64][72];
    const int tid = threadIdx.x, wave = tid >> 6, lane = tid & 63;
    const int lq = lane >> 4, lc = lane & 15;
    const int o = (blockIdx.z * 16 + blockIdx.y) * 64 + blockIdx.x;
    const int w = swz8(o, 2048);
    const int l0 = (w & 63) * 64, h = (w >> 6) & 15, n = w >> 10;
    const int wr = wave * 16;
#pragma unroll
    for (int i = 0; i < 2; ++i) {
        const int cc = tid + 256 * i, row = cc >> 3, kc = (cc & 7) * 8;
        *(uint4*)&qs[row][kc] =
            *(const uint4*)(q + ((size_t)((l0 + row) * 2 + n)) * 1024 + h * 64 + kc);
    }
    const f32x4 fz = {0.f, 0.f, 0.f, 0.f};
    f32x4 oacc[4];
#pragma unroll
    for (int dj = 0; dj < 4; ++dj) oacc[dj] = fz;
    float den[4] = {0.f, 0.f, 0.f, 0.f};

    for (int st = 0; st < 16; ++st) {
        __syncthreads();
#pragma unroll
        for (int i = 0; i < 2; ++i) {
            const int cc = tid + 256 * i, row = cc >> 3, kc = (cc & 7) * 8;
            *(uint4*)&ks[row][kc] =
                *(const uint4*)(kk + ((size_t)((st * 64 + row) * 2 + n)) * 1024 + h * 64 + kc);
            *(uint4*)&vs[row][kc] =
                *(const uint4*)(vt + ((size_t)((n * 16 + h) * 64 + row)) * 1024 + st * 64 + kc);
        }
        __syncthreads();
        const bf16x8 a0 = *(const bf16x8*)&qs[wr + lc][lq * 8];
        const bf16x8 a1 = *(const bf16x8*)&qs[wr + lc][32 + lq * 8];
#pragma unroll
        for (int sj = 0; sj < 4; ++sj) {
            f32x4 acc = fz;
            const bf16x8 b0 = *(const bf16x8*)&ks[sj * 16 + lc][lq * 8];
            const bf16x8 b1 = *(const bf16x8*)&ks[sj * 16 + lc][32 + lq * 8];
            acc = mfma16(a0, b0, acc);
            acc = mfma16(a1, b1, acc);
#pragma unroll
            for (int r = 0; r < 4; ++r) {
                const float e = __expf(acc[r]);
                den[r] += e;
                es[wr + lq * 4 + r][sj * 16 + lc] = (__bf16)e;
            }
        }
        const bf16x8 w0 = *(const bf16x8*)&es[wr + lc][lq * 8];
        const bf16x8 w1 = *(const bf16x8*)&es[wr + lc][32 + lq * 8];
#pragma unroll
        for (int dj = 0; dj < 4; ++dj) {
            const bf16x8 v0 = *(const bf16x8*)&vs[dj * 16 + lc][lq * 8];
            const bf16x8 v1 = *(const bf16x8*)&vs[dj * 16 + lc][32 + lq * 8];
            oacc[dj] = mfma16(w0, v0, oacc[dj]);
            oacc[dj] = mfma16(w1, v1, oacc[dj]);
        }
    }
#pragma unroll
    for (int m = 1; m < 16; m <<= 1)
#pragma unroll
        for (int r = 0; r < 4; ++r) den[r] += __shfl_xor(den[r], m);
    float c_r[4];
#pragma unroll
    for (int r = 0; r < 4; ++r) c_r[r] = 1.f / (den[r] + 1.f);
    if (lc == 0) {
#pragma unroll
        for (int r = 0; r < 4; ++r)
            cvec[((size_t)(n * 16 + h)) * 4096 + (l0 + wr + lq * 4 + r)] = c_r[r];
    }
#pragma unroll
    for (int dj = 0; dj < 4; ++dj)
#pragma unroll
        for (int r = 0; r < 4; ++r) {
            const int l = l0 + wr + lq * 4 + r;
            aout[((size_t)l * 2 + n) * 1024 + h * 64 + dj * 16 + lc] =
                (__bf16)(oacc[dj][r] * c_r[r]);
        }
}

// ---------------------------------------------------------------------------
// attn_map[n][l][s] = mean_h sigmoid(w); sigmoid via Taylor poly on (0,1).
__global__ __launch_bounds__(256) void attn_map_k(
    const __bf16* __restrict__ q, const __bf16* __restrict__ kk,
    const float* __restrict__ cvec, float* __restrict__ amap)
{
    __shared__ __bf16 qs[64][72];
    __shared__ __bf16 ks[64][72];
    const int tid = threadIdx.x, wave = tid >> 6, lane = tid & 63;
    const int lq = lane >> 4, lc = lane & 15;
    const int o = (blockIdx.z * 16 + blockIdx.y) * 64 + blockIdx.x;
    const int w = swz8(o, 2048);
    const int l0 = (w & 63) * 64, st = (w >> 6) & 15, n = w >> 10;
    const int wr = wave * 16;
    float sig[4][4];
#pragma unroll
    for (int sj = 0; sj < 4; ++sj)
#pragma unroll
        for (int r = 0; r < 4; ++r) sig[sj][r] = 0.f;

    for (int h = 0; h < 16; ++h) {
        __syncthreads();
#pragma unroll
        for (int i = 0; i < 2; ++i) {
            const int cc = tid + 256 * i, row = cc >> 3, kc = (cc & 7) * 8;
            *(uint4*)&qs[row][kc] =
                *(const uint4*)(q + ((size_t)((l0 + row) * 2 + n)) * 1024 + h * 64 + kc);
            *(uint4*)&ks[row][kc] =
                *(const uint4*)(kk + ((size_t)((st * 64 + row) * 2 + n)) * 1024 + h * 64 + kc);
        }
        __syncthreads();
        float c_r[4];
#pragma unroll
        for (int r = 0; r < 4; ++r)
            c_r[r] = cvec[((size_t)(n * 16 + h)) * 4096 + (l0 + wr + lq * 4 + r)];
        const bf16x8 a0 = *(const bf16x8*)&qs[wr + lc][lq * 8];
        const bf16x8 a1 = *(const bf16x8*)&qs[wr + lc][32 + lq * 8];
#pragma unroll
        for (int sj = 0; sj < 4; ++sj) {
            const f32x4 fz = {0.f, 0.f, 0.f, 0.f};
            f32x4 acc = fz;
            const bf16x8 b0 = *(const bf16x8*)&ks[sj * 16 + lc][lq * 8];
            const bf16x8 b1 = *(const bf16x8*)&ks[sj * 16 + lc][32 + lq * 8];
            acc = mfma16(a0, b0, acc);
            acc = mfma16(a1, b1, acc);
#pragma unroll
            for (int r = 0; r < 4; ++r) {
                const float ww = __expf(acc[r]) * c_r[r];   // w in (0,1)
                const float w2 = ww * ww;
                sig[sj][r] += 0.5f + ww * (0.25f - w2 * (1.f / 48.f - w2 * (1.f / 480.f)));
            }
        }
    }
#pragma unroll
    for (int sj = 0; sj < 4; ++sj)
#pragma unroll
        for (int r = 0; r < 4; ++r) {
            const int l = l0 + wr + lq * 4 + r;
            const int s = st * 64 + sj * 16 + lc;
            amap[((size_t)n * 4096 + l) * 1024 + s] = sig[sj][r] * (1.f / 16.f);
        }
}

// ---------------------------------------------------------------------------
// y = LN(base + add) * g + b; base is f32 (basef) or bf16 (baseb).
__global__ __launch_bounds__(256) void ln_k(
    const float* __restrict__ basef, const __bf16* __restrict__ baseb,
    const __bf16* __restrict__ add,
    const float* __restrict__ g, const float* __restrict__ bb,
    float* __restrict__ out_f32, __bf16* __restrict__ out_bf)
{
    __shared__ float red[8];
    const int row = blockIdx.x, tid = threadIdx.x;
    const int col = tid * 4;
    const size_t off = (size_t)row * 1024 + col;
    float v[4];
    if (basef) {
        float4 t = *(const float4*)(basef + off);
        v[0] = t.x; v[1] = t.y; v[2] = t.z; v[3] = t.w;
    } else {
        union { uint2 u; __bf16 h[4]; } tb;
        tb.u = *(const uint2*)(baseb + off);
#pragma unroll
        for (int j = 0; j < 4; ++j) v[j] = (float)tb.h[j];
    }
    {
        union { uint2 u; __bf16 h[4]; } ub;
        ub.u = *(const uint2*)(add + off);
#pragma unroll
        for (int j = 0; j < 4; ++j) v[j] += (float)ub.h[j];
    }
    float s = v[0] + v[1] + v[2] + v[3];
    float q = v[0] * v[0] + v[1] * v[1] + v[2] * v[2] + v[3] * v[3];
#pragma unroll
    for (int m = 1; m < 64; m <<= 1) { s += __shfl_xor(s, m); q += __shfl_xor(q, m); }
    const int wave = tid >> 6, lane = tid & 63;
    if (lane == 0) { red[wave] = s; red[4 + wave] = q; }
    __syncthreads();
    s = red[0] + red[1] + red[2] + red[3];
    q = red[4] + red[5] + red[6] + red[7];
    const float mu = s * (1.f / 1024.f);
    const float var = q * (1.f / 1024.f) - mu * mu;
    const float rs = rsqrtf(var + 1e-5f);
    const float4 gv = *(const float4*)(g + col);
    const float4 bv = *(const float4*)(bb + col);
    float y[4];
    y[0] = (v[0] - mu) * rs * gv.x + bv.x;
    y[1] = (v[1] - mu) * rs * gv.y + bv.y;
    y[2] = (v[2] - mu) * rs * gv.z + bv.z;
    y[3] = (v[3] - mu) * rs * gv.w + bv.w;
    if (out_f32) {
        float4 o; o.x = y[0]; o.y = y[1]; o.z = y[2]; o.w = y[3];
        *(float4*)(out_f32 + off) = o;
    }
    if (out_bf) {
        union { uint2 u; __bf16 h[4]; } ob;
#pragma unroll
        for (int j = 0; j < 4; ++j) ob.h[j] = (__bf16)y[j];
        *(uint2*)(out_bf + off) = ob.u;
    }
}

// ---------------------------------------------------------------------------
extern "C" void kernel_launch(void* const* d_in, const int* in_sizes, int n_in,
                              void* d_out, int out_size, void* d_ws, size_t ws_size,
                              hipStream_t stream) {
    const float* key_in    = (const float*)d_in[0];
    const float* value_in  = (const float*)d_in[1];
    const float* query     = (const float*)d_in[2];
    const float* in_proj_w = (const float*)d_in[3];
    const float* in_proj_b = (const float*)d_in[4];
    const float* out_w     = (const float*)d_in[5];
    const float* out_b     = (const float*)d_in[6];
    const float* ln1_g     = (const float*)d_in[7];
    const float* ln1_b     = (const float*)d_in[8];
    const float* ln2_g     = (const float*)d_in[9];
    const float* ln2_b     = (const float*)d_in[10];
    const float* ff1_w     = (const float*)d_in[11];
    const float* ff1_b     = (const float*)d_in[12];
    const float* ff2_w     = (const float*)d_in[13];
    const float* ff2_b     = (const float*)d_in[14];
    float* outp = (float*)d_out;

    __bf16* ws = (__bf16*)d_ws;
    const size_t M1 = 1048576;
    __bf16* WQKV = ws;               // 6 M1 (both layers)
    __bf16* WOUT = ws + 6 * M1;      // 2
    __bf16* WF1  = ws + 8 * M1;      // 8
    __bf16* WF2  = ws + 16 * M1;     // 8
    __bf16* KIN  = ws + 24 * M1;     // 2
    __bf16* VIN  = ws + 26 * M1;     // 2
    __bf16* TGT  = ws + 28 * M1;     // 8
    __bf16* PROJ = ws + 36 * M1;     // 8 (q-proj out; out-proj out)
    __bf16* KB   = ws + 44 * M1;     // 2
    __bf16* VB   = ws + 46 * M1;     // 2
    __bf16* VT   = ws + 48 * M1;     // 2
    __bf16* AOUT = ws + 50 * M1;     // 8 (attn out; ff2 out)
    __bf16* XB   = ws + 58 * M1;     // 8 (ln1 out, bf16)
    __bf16* H1   = ws + 66 * M1;     // 32
    float*  CVEC = (float*)(ws + 98 * M1);   // 131072 f32

    // upfront casts: inputs + ALL weights (both layers)
    cast_k<<<8192, 256, 0, stream>>>(query, TGT, 2097152);
    cast_k<<<2048, 256, 0, stream>>>(key_in, KIN, 524288);
    cast_k<<<2048, 256, 0, stream>>>(value_in, VIN, 524288);
    cast_k<<<6144, 256, 0, stream>>>(in_proj_w, WQKV, 1572864);
    cast_k<<<2048, 256, 0, stream>>>(out_w, WOUT, 524288);
    cast_k<<<8192, 256, 0, stream>>>(ff1_w, WF1, 2097152);
    cast_k<<<8192, 256, 0, stream>>>(ff2_w, WF2, 2097152);

    for (int i = 0; i < 2; ++i) {
        __bf16* WQKVi = WQKV + (size_t)i * 3 * M1;
        __bf16* WOUTi = WOUT + (size_t)i * M1;
        __bf16* WF1i  = WF1 + (size_t)i * 4 * M1;
        __bf16* WF2i  = WF2 + (size_t)i * 4 * M1;

        // fused q/k/v projections (one dispatch, 1536 blocks)
        gemm_qkv<<<1536, 256, 0, stream>>>(TGT, KIN, VIN, WQKVi,
                                           in_proj_b + i * 3072, PROJ, KB, VB);
        transpose_v<<<dim3(16, 16, 2), 256, 0, stream>>>(VB, VT);

        attn_fused<<<dim3(64, 16, 2), 256, 0, stream>>>(PROJ, KB, VT, CVEC, AOUT);
        if (i == 1)
            attn_map_k<<<dim3(64, 16, 2), 256, 0, stream>>>(PROJ, KB, CVEC,
                                                            outp + 8388608);

        // out projection (BN=64 -> 1024 blocks)
        gemm64<<<dim3(16, 64), 256, 0, stream>>>(AOUT, WOUTi, out_b + i * 1024,
                                                 PROJ, 8192, 1024, 1024, 1.f, 0);
        // LN1: base = query (f32, layer 0) or TGT (bf16)
        ln_k<<<8192, 256, 0, stream>>>(i == 0 ? query : nullptr,
                                       i == 0 ? nullptr : TGT,
                                       PROJ, ln1_g + i * 1024, ln1_b + i * 1024,
                                       nullptr, XB);
        // FFN: ff1 via 8-phase 256x256 pipeline (512 blocks = 2 CU rounds)
        gemm8p<<<512, 512, 0, stream>>>(XB, WF1i, ff1_b + i * 4096,
                                        H1, 32, 4096, 1024, 1.f, 1);
        gemm64<<<dim3(16, 64), 256, 0, stream>>>(H1, WF2i, ff2_b + i * 1024,
                                                 AOUT, 8192, 1024, 4096, 1.f, 0);
        // LN2: base = XB (bf16); final layer also writes f32 tgt to d_out
        ln_k<<<8192, 256, 0, stream>>>(nullptr, XB, AOUT,
                                       ln2_g + i * 1024, ln2_b + i * 1024,
                                       i == 1 ? outp : nullptr, TGT);
    }
}

// Round 4
// 936.436 us; speedup vs baseline: 1.3103x; 1.0504x over previous
//
#include <hip/hip_runtime.h>
#include <hip/hip_bf16.h>

// ---------------------------------------------------------------------------
// PadTransformer R8: R7 + row-major epilogue store ordering. gemm8p's old
// epilogue wrote each 128B C-line in four 32B quarters separated by 128-row
// bursts; with 128KB C-tile/block x 32 blocks/XCD the partial lines thrashed
// L2 -> RMW (WRITE 161MB vs 64MB output). Now each row's full line is
// written in 4 consecutive stores. Same fix in attn_fused/attn_map stores.
// ---------------------------------------------------------------------------

typedef __bf16 bf16x8 __attribute__((ext_vector_type(8)));
typedef float  f32x4  __attribute__((ext_vector_type(4)));

__device__ __forceinline__ f32x4 mfma16(bf16x8 a, bf16x8 b, f32x4 c) {
    return __builtin_amdgcn_mfma_f32_16x16x32_bf16(a, b, c, 0, 0, 0);
}

__device__ __forceinline__ void load_lds16(const __bf16* g, __bf16* l) {
    __builtin_amdgcn_global_load_lds(
        (const __attribute__((address_space(1))) void*)g,
        (__attribute__((address_space(3))) void*)l, 16, 0, 0);
}

// bijective XCD swizzle; valid when nwg % 8 == 0 (true for every launch here)
__device__ __forceinline__ int swz8(int o, int nwg) {
    return (o & 7) * (nwg >> 3) + (o >> 3);
}

// ---------------------------------------------------------------------------
__global__ __launch_bounds__(256) void cast_k(const float* __restrict__ in,
                                              __bf16* __restrict__ out, int n4) {
    int i = blockIdx.x * 256 + threadIdx.x;
    if (i >= n4) return;
    float4 f = ((const float4*)in)[i];
    union { uint2 u; __bf16 h[4]; } ob;
    ob.h[0] = (__bf16)f.x; ob.h[1] = (__bf16)f.y;
    ob.h[2] = (__bf16)f.z; ob.h[3] = (__bf16)f.w;
    ((uint2*)out)[i] = ob.u;
}

// ---------------------------------------------------------------------------
// 8-phase pipelined 256x256 GEMM (ff1). C = A[M][K] * B[N][K]^T + bias.
__global__ __launch_bounds__(512, 2) void gemm8p(
    const __bf16* __restrict__ A, const __bf16* __restrict__ B,
    const float* __restrict__ bias, __bf16* __restrict__ C,
    int Mt, int N, int K, float scale, int relu)
{
    // 8 half-tile slots: [parity*4 + {0:A-top,1:A-bot,2:B-left,3:B-right}]
    __shared__ __bf16 L[8][8192];      // 128 KiB
    const int tid = threadIdx.x;
    const int wid = tid >> 6, lane = tid & 63;
    const int lq = lane >> 4, lc = lane & 15;
    const int wm = wid >> 2;           // row half (0/1): rows [wm*128, +128)
    const int wn = (wid & 3) * 64;     // col base: 0,64,128,192
    const int bh = wn >> 7;            // B half id
    const int lb = wn & 127;           // local col within B half (0 or 64)
    const int sw = lc & 7;
    const int w = swz8(blockIdx.x, gridDim.x);
    const int bm = (w % Mt) * 256, bn = (w / Mt) * 256;
    const int NT = K >> 6;

    // stage one half-tile (128 rows x 64 K) = 2 x global_load_lds per thread.
    // R3 swizzle on the GLOBAL source, linear LDS dest (both-sides rule).
    auto stageA = [&](int kt, int h) {
#pragma unroll
        for (int p = 0; p < 2; ++p) {
            const int cc = p * 512 + tid;
            const int row = cc >> 3, gk = ((cc & 7) ^ (row & 7)) * 8;
            load_lds16(A + (size_t)(bm + h * 128 + row) * K + (kt * 64 + gk),
                       &L[(kt & 1) * 4 + h][(size_t)cc * 8]);
        }
    };
    auto stageB = [&](int kt, int h) {
#pragma unroll
        for (int p = 0; p < 2; ++p) {
            const int cc = p * 512 + tid;
            const int row = cc >> 3, gk = ((cc & 7) ^ (row & 7)) * 8;
            load_lds16(B + (size_t)(bn + h * 128 + row) * K + (kt * 64 + gk),
                       &L[(kt & 1) * 4 + 2 + h][(size_t)cc * 8]);
        }
    };

    // prologue: stage K-tiles 0 and 1 (16 loads); wait tile 0 landed (8 left)
    stageA(0, 0); stageA(0, 1); stageB(0, 0); stageB(0, 1);
    stageA(1, 0); stageA(1, 1); stageB(1, 0); stageB(1, 1);
    asm volatile("s_waitcnt vmcnt(8)" ::: "memory");
    __builtin_amdgcn_s_barrier();
    __builtin_amdgcn_sched_barrier(0);

    const f32x4 fz = {0.f, 0.f, 0.f, 0.f};
    f32x4 acc[2][4][4];                 // [rowhalf][i][ch*2+j]
#pragma unroll
    for (int rh = 0; rh < 2; ++rh)
#pragma unroll
        for (int i = 0; i < 4; ++i)
#pragma unroll
            for (int jj = 0; jj < 4; ++jj) acc[rh][i][jj] = fz;

    for (int t = 0; t < NT; ++t) {
        const __bf16* __restrict__ Ah = &L[(t & 1) * 4 + wm][0];
        const __bf16* __restrict__ Bh = &L[(t & 1) * 4 + 2 + bh][0];
        const int pf = (t + 2 < NT);
        bf16x8 a[2][4], b0[2][2], b1[2][2];

        // ---- phase 0: read A rows 0-63 + B cols lb+0..31; MFMA quad (0,0)
#pragma unroll
        for (int kk = 0; kk < 2; ++kk) {
            const int sl = ((kk * 4 + lq) ^ sw) * 8;
#pragma unroll
            for (int i = 0; i < 4; ++i)
                a[kk][i] = *(const bf16x8*)&Ah[(i * 16 + lc) * 64 + sl];
#pragma unroll
            for (int j = 0; j < 2; ++j)
                b0[kk][j] = *(const bf16x8*)&Bh[(lb + j * 16 + lc) * 64 + sl];
        }
        __builtin_amdgcn_s_barrier();
        asm volatile("s_waitcnt lgkmcnt(0)" ::: "memory");
        __builtin_amdgcn_sched_barrier(0);
        __builtin_amdgcn_s_setprio(1);
#pragma unroll
        for (int kk = 0; kk < 2; ++kk)
#pragma unroll
            for (int i = 0; i < 4; ++i)
#pragma unroll
                for (int j = 0; j < 2; ++j)
                    acc[0][i][j] = mfma16(a[kk][i], b0[kk][j], acc[0][i][j]);
        __builtin_amdgcn_s_setprio(0);
        __builtin_amdgcn_s_barrier();
        __builtin_amdgcn_sched_barrier(0);

        // ---- phase 1: read B cols lb+32..63; MFMA quad (0,1)
#pragma unroll
        for (int kk = 0; kk < 2; ++kk) {
            const int sl = ((kk * 4 + lq) ^ sw) * 8;
#pragma unroll
            for (int j = 0; j < 2; ++j)
                b1[kk][j] = *(const bf16x8*)&Bh[(lb + 32 + j * 16 + lc) * 64 + sl];
        }
        __builtin_amdgcn_s_barrier();
        asm volatile("s_waitcnt lgkmcnt(0)" ::: "memory");
        __builtin_amdgcn_sched_barrier(0);
        __builtin_amdgcn_s_setprio(1);
#pragma unroll
        for (int kk = 0; kk < 2; ++kk)
#pragma unroll
            for (int i = 0; i < 4; ++i)
#pragma unroll
                for (int j = 0; j < 2; ++j)
                    acc[0][i][2 + j] = mfma16(a[kk][i], b1[kk][j], acc[0][i][2 + j]);
        __builtin_amdgcn_s_setprio(0);
        __builtin_amdgcn_s_barrier();
        __builtin_amdgcn_sched_barrier(0);

        // ---- phase 2: read A rows 64-127; stage B(t+2); MFMA quad (1,0)
#pragma unroll
        for (int kk = 0; kk < 2; ++kk) {
            const int sl = ((kk * 4 + lq) ^ sw) * 8;
#pragma unroll
            for (int i = 0; i < 4; ++i)
                a[kk][i] = *(const bf16x8*)&Ah[(64 + i * 16 + lc) * 64 + sl];
        }
        if (pf) { stageB(t + 2, 0); stageB(t + 2, 1); }
        __builtin_amdgcn_s_barrier();
        asm volatile("s_waitcnt lgkmcnt(0)" ::: "memory");
        __builtin_amdgcn_sched_barrier(0);
        __builtin_amdgcn_s_setprio(1);
#pragma unroll
        for (int kk = 0; kk < 2; ++kk)
#pragma unroll
            for (int i = 0; i < 4; ++i)
#pragma unroll
                for (int j = 0; j < 2; ++j)
                    acc[1][i][j] = mfma16(a[kk][i], b0[kk][j], acc[1][i][j]);
        __builtin_amdgcn_s_setprio(0);
        __builtin_amdgcn_s_barrier();
        __builtin_amdgcn_sched_barrier(0);

        // ---- phase 3: stage A(t+2); MFMA quad (1,1); per-tile vmcnt
        if (pf) { stageA(t + 2, 0); stageA(t + 2, 1); }
        __builtin_amdgcn_s_barrier();
        __builtin_amdgcn_sched_barrier(0);
        __builtin_amdgcn_s_setprio(1);
#pragma unroll
        for (int kk = 0; kk < 2; ++kk)
#pragma unroll
            for (int i = 0; i < 4; ++i)
#pragma unroll
                for (int j = 0; j < 2; ++j)
                    acc[1][i][2 + j] = mfma16(a[kk][i], b1[kk][j], acc[1][i][2 + j]);
        __builtin_amdgcn_s_setprio(0);
        // ensure tile t+1 fully landed before its phase-0 reads; keep tile
        // t+2's 8 loads in flight (counted, never a mid-loop drain).
        if (pf) asm volatile("s_waitcnt vmcnt(8)" ::: "memory");
        else    asm volatile("s_waitcnt vmcnt(0)" ::: "memory");
        __builtin_amdgcn_s_barrier();
        __builtin_amdgcn_sched_barrier(0);
    }

    // epilogue: ROW-MAJOR order — each row's full 128B line (4 quarters)
    // written in 4 consecutive stores so L2 never holds partial lines long.
    // Same per-element arithmetic/order as R7 (absmax unchanged).
    float bv[4];
#pragma unroll
    for (int q = 0; q < 4; ++q) bv[q] = bias[bn + wn + q * 16 + lc];
#pragma unroll
    for (int rh = 0; rh < 2; ++rh)
#pragma unroll
        for (int i = 0; i < 4; ++i)
#pragma unroll
            for (int r = 0; r < 4; ++r) {
                const int row = bm + wm * 128 + rh * 64 + i * 16 + lq * 4 + r;
                const size_t base = (size_t)row * N + bn + wn + lc;
#pragma unroll
                for (int ch = 0; ch < 2; ++ch)
#pragma unroll
                    for (int j = 0; j < 2; ++j) {
                        float v = (acc[rh][i][ch * 2 + j][r] + bv[ch * 2 + j]) * scale;
                        if (relu) v = fmaxf(v, 0.f);
                        C[base + ch * 32 + j * 16] = (__bf16)v;
                    }
            }
}

// ---------------------------------------------------------------------------
// Legacy 2-phase core (qkv / ff2 / out-proj): C[128 x BN] tile, BK=64.
template <int BN>
__device__ __forceinline__ void gemm_core(
    const __bf16* __restrict__ A, const __bf16* __restrict__ B,
    const float* __restrict__ bias, __bf16* __restrict__ C,
    int M, int N, int K, float scale, int relu, int bm, int bn,
    __bf16* As, __bf16* Bs)
{
    const int tid = threadIdx.x;
    const int wave = tid >> 6, lane = tid & 63;
    const int lq = lane >> 4, lc = lane & 15;
    const int WN = BN / 2;
    const int JT = WN / 16;
    const int wm = (wave >> 1) * 64, wn = (wave & 1) * WN;

    const f32x4 fz = {0.f, 0.f, 0.f, 0.f};
    f32x4 acc[4][4];
#pragma unroll
    for (int i = 0; i < 4; ++i)
#pragma unroll
        for (int j = 0; j < JT; ++j) acc[i][j] = fz;

    const int sw = lc & 7;

    for (int k0 = 0; k0 < K; k0 += 64) {
        __syncthreads();
#pragma unroll
        for (int i = 0; i < 4; ++i) {
            const int c = tid + 256 * i;
            const int row = c >> 3, gk = ((c & 7) ^ (row & 7)) * 8;
            load_lds16(A + (size_t)(bm + row) * K + (k0 + gk),
                       As + (size_t)c * 8);
        }
#pragma unroll
        for (int i = 0; i < BN / 32; ++i) {
            const int c = tid + 256 * i;
            const int row = c >> 3, gk = ((c & 7) ^ (row & 7)) * 8;
            load_lds16(B + (size_t)(bn + row) * K + (k0 + gk),
                       Bs + (size_t)c * 8);
        }
        __syncthreads();
#pragma unroll
        for (int kk = 0; kk < 2; ++kk) {
            bf16x8 af[4], bw[4];
            const int slot = ((kk * 4 + lq) ^ sw) * 8;
#pragma unroll
            for (int i = 0; i < 4; ++i)
                af[i] = *(const bf16x8*)&As[(wm + i * 16 + lc) * 64 + slot];
#pragma unroll
            for (int j = 0; j < JT; ++j)
                bw[j] = *(const bf16x8*)&Bs[(wn + j * 16 + lc) * 64 + slot];
#pragma unroll
            for (int i = 0; i < 4; ++i)
#pragma unroll
                for (int j = 0; j < JT; ++j)
                    acc[i][j] = mfma16(af[i], bw[j], acc[i][j]);
        }
    }

#pragma unroll
    for (int j = 0; j < JT; ++j) {
        const int col = bn + wn + j * 16 + lc;
        const float bv = bias[col];
#pragma unroll
        for (int i = 0; i < 4; ++i) {
#pragma unroll
            for (int r = 0; r < 4; ++r) {
                float v = (acc[i][j][r] + bv) * scale;
                if (relu) v = fmaxf(v, 0.f);
                const int row = bm + wm + i * 16 + lq * 4 + r;
                C[(size_t)row * N + col] = (__bf16)v;
            }
        }
    }
}

__global__ __launch_bounds__(256) void gemm64(
    const __bf16* __restrict__ A, const __bf16* __restrict__ B,
    const float* __restrict__ bias, __bf16* __restrict__ C,
    int M, int N, int K, float scale, int relu)
{
    __shared__ __bf16 As[128 * 64];
    __shared__ __bf16 Bs[64 * 64];
    const int nwg = gridDim.x * gridDim.y;
    const int o = blockIdx.y * gridDim.x + blockIdx.x;
    const int w = swz8(o, nwg);
    const int bx = w % gridDim.x, by = w / gridDim.x;
    gemm_core<64>(A, B, bias, C, M, N, K, scale, relu,
                  by * 128, bx * 64, As, Bs);
}

// Fused q/k/v projection: flat grid 1536 blocks, BN=64.
__global__ __launch_bounds__(256) void gemm_qkv(
    const __bf16* __restrict__ TGT, const __bf16* __restrict__ KIN,
    const __bf16* __restrict__ VIN, const __bf16* __restrict__ W,
    const float* __restrict__ bias, __bf16* __restrict__ PROJ,
    __bf16* __restrict__ KB, __bf16* __restrict__ VB)
{
    __shared__ __bf16 As[128 * 64];
    __shared__ __bf16 Bs[64 * 64];
    const int bid = swz8(blockIdx.x, 1536);   // XCD-contiguous tile runs
    const __bf16* A; __bf16* Cout; int M, t, seg; float scale;
    if (bid < 1024)      { seg = 0; t = bid;        A = TGT; Cout = PROJ; M = 8192; scale = 0.125f; }
    else if (bid < 1280) { seg = 1; t = bid - 1024; A = KIN; Cout = KB;   M = 2048; scale = 1.f; }
    else                 { seg = 2; t = bid - 1280; A = VIN; Cout = VB;   M = 2048; scale = 1.f; }
    gemm_core<64>(A, W + (size_t)seg * 1048576, bias + seg * 1024, Cout,
                  M, 1024, 1024, scale, 0, (t >> 4) * 128, (t & 15) * 64, As, Bs);
}

// ---------------------------------------------------------------------------
// transpose V per (n,h): vt[(n*16+h)*64 + d][s] = v[(s*2+n)*1024 + h*64 + d]
__global__ __launch_bounds__(256) void transpose_v(const __bf16* __restrict__ v,
                                                   __bf16* __restrict__ vt) {
    __shared__ __bf16 t[64][72];
    const int tid = threadIdx.x;
    const int s0 = blockIdx.x * 64, h = blockIdx.y, n = blockIdx.z;
#pragma unroll
    for (int i = 0; i < 2; ++i) {
        const int cc = tid + 256 * i, row = cc >> 3, kc = (cc & 7) * 8;
        *(uint4*)&t[row][kc] =
            *(const uint4*)(v + ((size_t)((s0 + row) * 2 + n)) * 1024 + h * 64 + kc);
    }
    __syncthreads();
#pragma unroll
    for (int i = 0; i < 2; ++i) {
        const int cc = tid + 256 * i, d = cc >> 3, jc = (cc & 7) * 8;
        __attribute__((aligned(16))) __bf16 tmp[8];
#pragma unroll
        for (int u = 0; u < 8; ++u) tmp[u] = t[jc + u][d];
        *(uint4*)(vt + ((size_t)((n * 16 + h) * 64 + d)) * 1024 + s0 + jc) = *(uint4*)tmp;
    }
}

// ---------------------------------------------------------------------------
// Fused attention (R2 design): O = (sum e^s v) / (1 + sum e^s); cvec saved.
__global__ __launch_bounds__(256) void attn_fused(
    const __bf16* __restrict__ q, const __bf16* __restrict__ kk,
    const __bf16* __restrict__ vt, float* __restrict__ cvec,
    __bf16* __restrict__ aout)
{
    __shared__ __bf16 qs[64][72];
    __shared__ __bf16 ks[64][72];
    __shared__ __bf16 vs[64][72];
    __shared__ __bf16 es[64][72];
    const int tid = threadIdx.x, wave = tid >> 6, lane = tid & 63;
    const int lq = lane >> 4, lc = lane & 15;
    const int o = (blockIdx.z * 16 + blockIdx.y) * 64 + blockIdx.x;
    const int w = swz8(o, 2048);
    const int l0 = (w & 63) * 64, h = (w >> 6) & 15, n = w >> 10;
    const int wr = wave * 16;
#pragma unroll
    for (int i = 0; i < 2; ++i) {
        const int cc = tid + 256 * i, row = cc >> 3, kc = (cc & 7) * 8;
        *(uint4*)&qs[row][kc] =
            *(const uint4*)(q + ((size_t)((l0 + row) * 2 + n)) * 1024 + h * 64 + kc);
    }
    const f32x4 fz = {0.f, 0.f, 0.f, 0.f};
    f32x4 oacc[4];
#pragma unroll
    for (int dj = 0; dj < 4; ++dj) oacc[dj] = fz;
    float den[4] = {0.f, 0.f, 0.f, 0.f};

    for (int st = 0; st < 16; ++st) {
        __syncthreads();
#pragma unroll
        for (int i = 0; i < 2; ++i) {
            const int cc = tid + 256 * i, row = cc >> 3, kc = (cc & 7) * 8;
            *(uint4*)&ks[row][kc] =
                *(const uint4*)(kk + ((size_t)((st * 64 + row) * 2 + n)) * 1024 + h * 64 + kc);
            *(uint4*)&vs[row][kc] =
                *(const uint4*)(vt + ((size_t)((n * 16 + h) * 64 + row)) * 1024 + st * 64 + kc);
        }
        __syncthreads();
        const bf16x8 a0 = *(const bf16x8*)&qs[wr + lc][lq * 8];
        const bf16x8 a1 = *(const bf16x8*)&qs[wr + lc][32 + lq * 8];
#pragma unroll
        for (int sj = 0; sj < 4; ++sj) {
            f32x4 acc = fz;
            const bf16x8 b0 = *(const bf16x8*)&ks[sj * 16 + lc][lq * 8];
            const bf16x8 b1 = *(const bf16x8*)&ks[sj * 16 + lc][32 + lq * 8];
            acc = mfma16(a0, b0, acc);
            acc = mfma16(a1, b1, acc);
#pragma unroll
            for (int r = 0; r < 4; ++r) {
                const float e = __expf(acc[r]);
                den[r] += e;
                es[wr + lq * 4 + r][sj * 16 + lc] = (__bf16)e;
            }
        }
        const bf16x8 w0 = *(const bf16x8*)&es[wr + lc][lq * 8];
        const bf16x8 w1 = *(const bf16x8*)&es[wr + lc][32 + lq * 8];
#pragma unroll
        for (int dj = 0; dj < 4; ++dj) {
            const bf16x8 v0 = *(const bf16x8*)&vs[dj * 16 + lc][lq * 8];
            const bf16x8 v1 = *(const bf16x8*)&vs[dj * 16 + lc][32 + lq * 8];
            oacc[dj] = mfma16(w0, v0, oacc[dj]);
            oacc[dj] = mfma16(w1, v1, oacc[dj]);
        }
    }
#pragma unroll
    for (int m = 1; m < 16; m <<= 1)
#pragma unroll
        for (int r = 0; r < 4; ++r) den[r] += __shfl_xor(den[r], m);
    float c_r[4];
#pragma unroll
    for (int r = 0; r < 4; ++r) c_r[r] = 1.f / (den[r] + 1.f);
    if (lc == 0) {
#pragma unroll
        for (int r = 0; r < 4; ++r)
            cvec[((size_t)(n * 16 + h)) * 4096 + (l0 + wr + lq * 4 + r)] = c_r[r];
    }
    // row-major store: each row's 128B head-slice in 4 consecutive stores
#pragma unroll
    for (int r = 0; r < 4; ++r) {
        const int l = l0 + wr + lq * 4 + r;
        const size_t base = ((size_t)l * 2 + n) * 1024 + h * 64 + lc;
#pragma unroll
        for (int dj = 0; dj < 4; ++dj)
            aout[base + dj * 16] = (__bf16)(oacc[dj][r] * c_r[r]);
    }
}

// ---------------------------------------------------------------------------
// attn_map[n][l][s] = mean_h sigmoid(w); sigmoid via Taylor poly on (0,1).
__global__ __launch_bounds__(256) void attn_map_k(
    const __bf16* __restrict__ q, const __bf16* __restrict__ kk,
    const float* __restrict__ cvec, float* __restrict__ amap)
{
    __shared__ __bf16 qs[64][72];
    __shared__ __bf16 ks[64][72];
    const int tid = threadIdx.x, wave = tid >> 6, lane = tid & 63;
    const int lq = lane >> 4, lc = lane & 15;
    const int o = (blockIdx.z * 16 + blockIdx.y) * 64 + blockIdx.x;
    const int w = swz8(o, 2048);
    const int l0 = (w & 63) * 64, st = (w >> 6) & 15, n = w >> 10;
    const int wr = wave * 16;
    float sig[4][4];
#pragma unroll
    for (int sj = 0; sj < 4; ++sj)
#pragma unroll
        for (int r = 0; r < 4; ++r) sig[sj][r] = 0.f;

    for (int h = 0; h < 16; ++h) {
        __syncthreads();
#pragma unroll
        for (int i = 0; i < 2; ++i) {
            const int cc = tid + 256 * i, row = cc >> 3, kc = (cc & 7) * 8;
            *(uint4*)&qs[row][kc] =
                *(const uint4*)(q + ((size_t)((l0 + row) * 2 + n)) * 1024 + h * 64 + kc);
            *(uint4*)&ks[row][kc] =
                *(const uint4*)(kk + ((size_t)((st * 64 + row) * 2 + n)) * 1024 + h * 64 + kc);
        }
        __syncthreads();
        float c_r[4];
#pragma unroll
        for (int r = 0; r < 4; ++r)
            c_r[r] = cvec[((size_t)(n * 16 + h)) * 4096 + (l0 + wr + lq * 4 + r)];
        const bf16x8 a0 = *(const bf16x8*)&qs[wr + lc][lq * 8];
        const bf16x8 a1 = *(const bf16x8*)&qs[wr + lc][32 + lq * 8];
#pragma unroll
        for (int sj = 0; sj < 4; ++sj) {
            const f32x4 fz = {0.f, 0.f, 0.f, 0.f};
            f32x4 acc = fz;
            const bf16x8 b0 = *(const bf16x8*)&ks[sj * 16 + lc][lq * 8];
            const bf16x8 b1 = *(const bf16x8*)&ks[sj * 16 + lc][32 + lq * 8];
            acc = mfma16(a0, b0, acc);
            acc = mfma16(a1, b1, acc);
#pragma unroll
            for (int r = 0; r < 4; ++r) {
                const float ww = __expf(acc[r]) * c_r[r];   // w in (0,1)
                const float w2 = ww * ww;
                sig[sj][r] += 0.5f + ww * (0.25f - w2 * (1.f / 48.f - w2 * (1.f / 480.f)));
            }
        }
    }
    // row-major store: each row's 256B s-slice in 4 consecutive stores
#pragma unroll
    for (int r = 0; r < 4; ++r) {
        const int l = l0 + wr + lq * 4 + r;
        const size_t base = ((size_t)n * 4096 + l) * 1024 + st * 64 + lc;
#pragma unroll
        for (int sj = 0; sj < 4; ++sj)
            amap[base + sj * 16] = sig[sj][r] * (1.f / 16.f);
    }
}

// ---------------------------------------------------------------------------
// y = LN(base + add) * g + b; base is f32 (basef) or bf16 (baseb).
__global__ __launch_bounds__(256) void ln_k(
    const float* __restrict__ basef, const __bf16* __restrict__ baseb,
    const __bf16* __restrict__ add,
    const float* __restrict__ g, const float* __restrict__ bb,
    float* __restrict__ out_f32, __bf16* __restrict__ out_bf)
{
    __shared__ float red[8];
    const int row = blockIdx.x, tid = threadIdx.x;
    const int col = tid * 4;
    const size_t off = (size_t)row * 1024 + col;
    float v[4];
    if (basef) {
        float4 t = *(const float4*)(basef + off);
        v[0] = t.x; v[1] = t.y; v[2] = t.z; v[3] = t.w;
    } else {
        union { uint2 u; __bf16 h[4]; } tb;
        tb.u = *(const uint2*)(baseb + off);
#pragma unroll
        for (int j = 0; j < 4; ++j) v[j] = (float)tb.h[j];
    }
    {
        union { uint2 u; __bf16 h[4]; } ub;
        ub.u = *(const uint2*)(add + off);
#pragma unroll
        for (int j = 0; j < 4; ++j) v[j] += (float)ub.h[j];
    }
    float s = v[0] + v[1] + v[2] + v[3];
    float q = v[0] * v[0] + v[1] * v[1] + v[2] * v[2] + v[3] * v[3];
#pragma unroll
    for (int m = 1; m < 64; m <<= 1) { s += __shfl_xor(s, m); q += __shfl_xor(q, m); }
    const int wave = tid >> 6, lane = tid & 63;
    if (lane == 0) { red[wave] = s; red[4 + wave] = q; }
    __syncthreads();
    s = red[0] + red[1] + red[2] + red[3];
    q = red[4] + red[5] + red[6] + red[7];
    const float mu = s * (1.f / 1024.f);
    const float var = q * (1.f / 1024.f) - mu * mu;
    const float rs = rsqrtf(var + 1e-5f);
    const float4 gv = *(const float4*)(g + col);
    const float4 bv = *(const float4*)(bb + col);
    float y[4];
    y[0] = (v[0] - mu) * rs * gv.x + bv.x;
    y[1] = (v[1] - mu) * rs * gv.y + bv.y;
    y[2] = (v[2] - mu) * rs * gv.z + bv.z;
    y[3] = (v[3] - mu) * rs * gv.w + bv.w;
    if (out_f32) {
        float4 o; o.x = y[0]; o.y = y[1]; o.z = y[2]; o.w = y[3];
        *(float4*)(out_f32 + off) = o;
    }
    if (out_bf) {
        union { uint2 u; __bf16 h[4]; } ob;
#pragma unroll
        for (int j = 0; j < 4; ++j) ob.h[j] = (__bf16)y[j];
        *(uint2*)(out_bf + off) = ob.u;
    }
}

// ---------------------------------------------------------------------------
extern "C" void kernel_launch(void* const* d_in, const int* in_sizes, int n_in,
                              void* d_out, int out_size, void* d_ws, size_t ws_size,
                              hipStream_t stream) {
    const float* key_in    = (const float*)d_in[0];
    const float* value_in  = (const float*)d_in[1];
    const float* query     = (const float*)d_in[2];
    const float* in_proj_w = (const float*)d_in[3];
    const float* in_proj_b = (const float*)d_in[4];
    const float* out_w     = (const float*)d_in[5];
    const float* out_b     = (const float*)d_in[6];
    const float* ln1_g     = (const float*)d_in[7];
    const float* ln1_b     = (const float*)d_in[8];
    const float* ln2_g     = (const float*)d_in[9];
    const float* ln2_b     = (const float*)d_in[10];
    const float* ff1_w     = (const float*)d_in[11];
    const float* ff1_b     = (const float*)d_in[12];
    const float* ff2_w     = (const float*)d_in[13];
    const float* ff2_b     = (const float*)d_in[14];
    float* outp = (float*)d_out;

    __bf16* ws = (__bf16*)d_ws;
    const size_t M1 = 1048576;
    __bf16* WQKV = ws;               // 6 M1 (both layers)
    __bf16* WOUT = ws + 6 * M1;      // 2
    __bf16* WF1  = ws + 8 * M1;      // 8
    __bf16* WF2  = ws + 16 * M1;     // 8
    __bf16* KIN  = ws + 24 * M1;     // 2
    __bf16* VIN  = ws + 26 * M1;     // 2
    __bf16* TGT  = ws + 28 * M1;     // 8
    __bf16* PROJ = ws + 36 * M1;     // 8 (q-proj out; out-proj out)
    __bf16* KB   = ws + 44 * M1;     // 2
    __bf16* VB   = ws + 46 * M1;     // 2
    __bf16* VT   = ws + 48 * M1;     // 2
    __bf16* AOUT = ws + 50 * M1;     // 8 (attn out; ff2 out)
    __bf16* XB   = ws + 58 * M1;     // 8 (ln1 out, bf16)
    __bf16* H1   = ws + 66 * M1;     // 32
    float*  CVEC = (float*)(ws + 98 * M1);   // 131072 f32

    // upfront casts: inputs + ALL weights (both layers)
    cast_k<<<8192, 256, 0, stream>>>(query, TGT, 2097152);
    cast_k<<<2048, 256, 0, stream>>>(key_in, KIN, 524288);
    cast_k<<<2048, 256, 0, stream>>>(value_in, VIN, 524288);
    cast_k<<<6144, 256, 0, stream>>>(in_proj_w, WQKV, 1572864);
    cast_k<<<2048, 256, 0, stream>>>(out_w, WOUT, 524288);
    cast_k<<<8192, 256, 0, stream>>>(ff1_w, WF1, 2097152);
    cast_k<<<8192, 256, 0, stream>>>(ff2_w, WF2, 2097152);

    for (int i = 0; i < 2; ++i) {
        __bf16* WQKVi = WQKV + (size_t)i * 3 * M1;
        __bf16* WOUTi = WOUT + (size_t)i * M1;
        __bf16* WF1i  = WF1 + (size_t)i * 4 * M1;
        __bf16* WF2i  = WF2 + (size_t)i * 4 * M1;

        // fused q/k/v projections (one dispatch, 1536 blocks)
        gemm_qkv<<<1536, 256, 0, stream>>>(TGT, KIN, VIN, WQKVi,
                                           in_proj_b + i * 3072, PROJ, KB, VB);
        transpose_v<<<dim3(16, 16, 2), 256, 0, stream>>>(VB, VT);

        attn_fused<<<dim3(64, 16, 2), 256, 0, stream>>>(PROJ, KB, VT, CVEC, AOUT);
        if (i == 1)
            attn_map_k<<<dim3(64, 16, 2), 256, 0, stream>>>(PROJ, KB, CVEC,
                                                            outp + 8388608);

        // out projection (BN=64 -> 1024 blocks)
        gemm64<<<dim3(16, 64), 256, 0, stream>>>(AOUT, WOUTi, out_b + i * 1024,
                                                 PROJ, 8192, 1024, 1024, 1.f, 0);
        // LN1: base = query (f32, layer 0) or TGT (bf16)
        ln_k<<<8192, 256, 0, stream>>>(i == 0 ? query : nullptr,
                                       i == 0 ? nullptr : TGT,
                                       PROJ, ln1_g + i * 1024, ln1_b + i * 1024,
                                       nullptr, XB);
        // FFN: ff1 via 8-phase 256x256 pipeline (512 blocks = 2 CU rounds)
        gemm8p<<<512, 512, 0, stream>>>(XB, WF1i, ff1_b + i * 4096,
                                        H1, 32, 4096, 1024, 1.f, 1);
        gemm64<<<dim3(16, 64), 256, 0, stream>>>(H1, WF2i, ff2_b + i * 1024,
                                                 AOUT, 8192, 1024, 4096, 1.f, 0);
        // LN2: base = XB (bf16); final layer also writes f32 tgt to d_out
        ln_k<<<8192, 256, 0, stream>>>(nullptr, XB, AOUT,
                                       ln2_g + i * 1024, ln2_b + i * 1024,
                                       i == 1 ? outp : nullptr, TGT);
    }
}

// Round 5
// 914.822 us; speedup vs baseline: 1.3413x; 1.0236x over previous
//
#include <hip/hip_runtime.h>
#include <hip/hip_bf16.h>

// ---------------------------------------------------------------------------
// PadTransformer R9: R8 + pipelined 256x128 GEMM (gemm8pN) for ff2/out-proj
// (the two N=1024 GEMMs, 256 blocks = 1 full CU round). Same phase discipline
// as gemm8p: ds_read cluster -> barrier -> lgkmcnt(0) -> MFMA cluster, stages
// issued only after all reads of the overwritten slot are barrier-complete,
// counted vmcnt(6) once per K-tile. Row-major epilogues everywhere (R8 fix).
// ---------------------------------------------------------------------------

typedef __bf16 bf16x8 __attribute__((ext_vector_type(8)));
typedef float  f32x4  __attribute__((ext_vector_type(4)));

__device__ __forceinline__ f32x4 mfma16(bf16x8 a, bf16x8 b, f32x4 c) {
    return __builtin_amdgcn_mfma_f32_16x16x32_bf16(a, b, c, 0, 0, 0);
}

__device__ __forceinline__ void load_lds16(const __bf16* g, __bf16* l) {
    __builtin_amdgcn_global_load_lds(
        (const __attribute__((address_space(1))) void*)g,
        (__attribute__((address_space(3))) void*)l, 16, 0, 0);
}

// bijective XCD swizzle; valid when nwg % 8 == 0 (true for every launch here)
__device__ __forceinline__ int swz8(int o, int nwg) {
    return (o & 7) * (nwg >> 3) + (o >> 3);
}

// ---------------------------------------------------------------------------
__global__ __launch_bounds__(256) void cast_k(const float* __restrict__ in,
                                              __bf16* __restrict__ out, int n4) {
    int i = blockIdx.x * 256 + threadIdx.x;
    if (i >= n4) return;
    float4 f = ((const float4*)in)[i];
    union { uint2 u; __bf16 h[4]; } ob;
    ob.h[0] = (__bf16)f.x; ob.h[1] = (__bf16)f.y;
    ob.h[2] = (__bf16)f.z; ob.h[3] = (__bf16)f.w;
    ((uint2*)out)[i] = ob.u;
}

// ---------------------------------------------------------------------------
// 8-phase pipelined 256x256 GEMM (ff1). C = A[M][K] * B[N][K]^T + bias.
__global__ __launch_bounds__(512, 2) void gemm8p(
    const __bf16* __restrict__ A, const __bf16* __restrict__ B,
    const float* __restrict__ bias, __bf16* __restrict__ C,
    int Mt, int N, int K, float scale, int relu)
{
    // 8 half-tile slots: [parity*4 + {0:A-top,1:A-bot,2:B-left,3:B-right}]
    __shared__ __bf16 L[8][8192];      // 128 KiB
    const int tid = threadIdx.x;
    const int wid = tid >> 6, lane = tid & 63;
    const int lq = lane >> 4, lc = lane & 15;
    const int wm = wid >> 2;           // row half (0/1): rows [wm*128, +128)
    const int wn = (wid & 3) * 64;     // col base: 0,64,128,192
    const int bh = wn >> 7;            // B half id
    const int lb = wn & 127;           // local col within B half (0 or 64)
    const int sw = lc & 7;
    const int w = swz8(blockIdx.x, gridDim.x);
    const int bm = (w % Mt) * 256, bn = (w / Mt) * 256;
    const int NT = K >> 6;

    auto stageA = [&](int kt, int h) {
#pragma unroll
        for (int p = 0; p < 2; ++p) {
            const int cc = p * 512 + tid;
            const int row = cc >> 3, gk = ((cc & 7) ^ (row & 7)) * 8;
            load_lds16(A + (size_t)(bm + h * 128 + row) * K + (kt * 64 + gk),
                       &L[(kt & 1) * 4 + h][(size_t)cc * 8]);
        }
    };
    auto stageB = [&](int kt, int h) {
#pragma unroll
        for (int p = 0; p < 2; ++p) {
            const int cc = p * 512 + tid;
            const int row = cc >> 3, gk = ((cc & 7) ^ (row & 7)) * 8;
            load_lds16(B + (size_t)(bn + h * 128 + row) * K + (kt * 64 + gk),
                       &L[(kt & 1) * 4 + 2 + h][(size_t)cc * 8]);
        }
    };

    // prologue: stage K-tiles 0 and 1 (16 loads); wait tile 0 landed (8 left)
    stageA(0, 0); stageA(0, 1); stageB(0, 0); stageB(0, 1);
    stageA(1, 0); stageA(1, 1); stageB(1, 0); stageB(1, 1);
    asm volatile("s_waitcnt vmcnt(8)" ::: "memory");
    __builtin_amdgcn_s_barrier();
    __builtin_amdgcn_sched_barrier(0);

    const f32x4 fz = {0.f, 0.f, 0.f, 0.f};
    f32x4 acc[2][4][4];                 // [rowhalf][i][ch*2+j]
#pragma unroll
    for (int rh = 0; rh < 2; ++rh)
#pragma unroll
        for (int i = 0; i < 4; ++i)
#pragma unroll
            for (int jj = 0; jj < 4; ++jj) acc[rh][i][jj] = fz;

    for (int t = 0; t < NT; ++t) {
        const __bf16* __restrict__ Ah = &L[(t & 1) * 4 + wm][0];
        const __bf16* __restrict__ Bh = &L[(t & 1) * 4 + 2 + bh][0];
        const int pf = (t + 2 < NT);
        bf16x8 a[2][4], b0[2][2], b1[2][2];

        // ---- phase 0: read A rows 0-63 + B cols lb+0..31; MFMA quad (0,0)
#pragma unroll
        for (int kk = 0; kk < 2; ++kk) {
            const int sl = ((kk * 4 + lq) ^ sw) * 8;
#pragma unroll
            for (int i = 0; i < 4; ++i)
                a[kk][i] = *(const bf16x8*)&Ah[(i * 16 + lc) * 64 + sl];
#pragma unroll
            for (int j = 0; j < 2; ++j)
                b0[kk][j] = *(const bf16x8*)&Bh[(lb + j * 16 + lc) * 64 + sl];
        }
        __builtin_amdgcn_s_barrier();
        asm volatile("s_waitcnt lgkmcnt(0)" ::: "memory");
        __builtin_amdgcn_sched_barrier(0);
        __builtin_amdgcn_s_setprio(1);
#pragma unroll
        for (int kk = 0; kk < 2; ++kk)
#pragma unroll
            for (int i = 0; i < 4; ++i)
#pragma unroll
                for (int j = 0; j < 2; ++j)
                    acc[0][i][j] = mfma16(a[kk][i], b0[kk][j], acc[0][i][j]);
        __builtin_amdgcn_s_setprio(0);
        __builtin_amdgcn_s_barrier();
        __builtin_amdgcn_sched_barrier(0);

        // ---- phase 1: read B cols lb+32..63; MFMA quad (0,1)
#pragma unroll
        for (int kk = 0; kk < 2; ++kk) {
            const int sl = ((kk * 4 + lq) ^ sw) * 8;
#pragma unroll
            for (int j = 0; j < 2; ++j)
                b1[kk][j] = *(const bf16x8*)&Bh[(lb + 32 + j * 16 + lc) * 64 + sl];
        }
        __builtin_amdgcn_s_barrier();
        asm volatile("s_waitcnt lgkmcnt(0)" ::: "memory");
        __builtin_amdgcn_sched_barrier(0);
        __builtin_amdgcn_s_setprio(1);
#pragma unroll
        for (int kk = 0; kk < 2; ++kk)
#pragma unroll
            for (int i = 0; i < 4; ++i)
#pragma unroll
                for (int j = 0; j < 2; ++j)
                    acc[0][i][2 + j] = mfma16(a[kk][i], b1[kk][j], acc[0][i][2 + j]);
        __builtin_amdgcn_s_setprio(0);
        __builtin_amdgcn_s_barrier();
        __builtin_amdgcn_sched_barrier(0);

        // ---- phase 2: read A rows 64-127; stage B(t+2); MFMA quad (1,0)
#pragma unroll
        for (int kk = 0; kk < 2; ++kk) {
            const int sl = ((kk * 4 + lq) ^ sw) * 8;
#pragma unroll
            for (int i = 0; i < 4; ++i)
                a[kk][i] = *(const bf16x8*)&Ah[(64 + i * 16 + lc) * 64 + sl];
        }
        if (pf) { stageB(t + 2, 0); stageB(t + 2, 1); }
        __builtin_amdgcn_s_barrier();
        asm volatile("s_waitcnt lgkmcnt(0)" ::: "memory");
        __builtin_amdgcn_sched_barrier(0);
        __builtin_amdgcn_s_setprio(1);
#pragma unroll
        for (int kk = 0; kk < 2; ++kk)
#pragma unroll
            for (int i = 0; i < 4; ++i)
#pragma unroll
                for (int j = 0; j < 2; ++j)
                    acc[1][i][j] = mfma16(a[kk][i], b0[kk][j], acc[1][i][j]);
        __builtin_amdgcn_s_setprio(0);
        __builtin_amdgcn_s_barrier();
        __builtin_amdgcn_sched_barrier(0);

        // ---- phase 3: stage A(t+2); MFMA quad (1,1); per-tile vmcnt
        if (pf) { stageA(t + 2, 0); stageA(t + 2, 1); }
        __builtin_amdgcn_s_barrier();
        __builtin_amdgcn_sched_barrier(0);
        __builtin_amdgcn_s_setprio(1);
#pragma unroll
        for (int kk = 0; kk < 2; ++kk)
#pragma unroll
            for (int i = 0; i < 4; ++i)
#pragma unroll
                for (int j = 0; j < 2; ++j)
                    acc[1][i][2 + j] = mfma16(a[kk][i], b1[kk][j], acc[1][i][2 + j]);
        __builtin_amdgcn_s_setprio(0);
        if (pf) asm volatile("s_waitcnt vmcnt(8)" ::: "memory");
        else    asm volatile("s_waitcnt vmcnt(0)" ::: "memory");
        __builtin_amdgcn_s_barrier();
        __builtin_amdgcn_sched_barrier(0);
    }

    // epilogue: ROW-MAJOR order (R8): full 128B line per row, consecutive.
    float bv[4];
#pragma unroll
    for (int q = 0; q < 4; ++q) bv[q] = bias[bn + wn + q * 16 + lc];
#pragma unroll
    for (int rh = 0; rh < 2; ++rh)
#pragma unroll
        for (int i = 0; i < 4; ++i)
#pragma unroll
            for (int r = 0; r < 4; ++r) {
                const int row = bm + wm * 128 + rh * 64 + i * 16 + lq * 4 + r;
                const size_t base = (size_t)row * N + bn + wn + lc;
#pragma unroll
                for (int ch = 0; ch < 2; ++ch)
#pragma unroll
                    for (int j = 0; j < 2; ++j) {
                        float v = (acc[rh][i][ch * 2 + j][r] + bv[ch * 2 + j]) * scale;
                        if (relu) v = fmaxf(v, 0.f);
                        C[base + ch * 32 + j * 16] = (__bf16)v;
                    }
            }
}

// ---------------------------------------------------------------------------
// Pipelined 256x128 GEMM (ff2 / out-proj, N=1024 -> 256 blocks).
// 8 waves, per-wave 128x32. LDS 6 slots x 16 KiB (A-top/A-bot/B x 2 parity).
// Phase 0: all 20 ds_reads -> barrier -> lgkmcnt(0) -> 16 MFMA (row-half 0).
// Phase 1: issue 6 global_load_lds for t+2 -> 16 MFMA (row-half 1) -> vmcnt(6).
__global__ __launch_bounds__(512, 2) void gemm8pN(
    const __bf16* __restrict__ A, const __bf16* __restrict__ B,
    const float* __restrict__ bias, __bf16* __restrict__ C,
    int Mt, int N, int K, float scale, int relu)
{
    __shared__ __bf16 L[6][8192];      // 96 KiB: [par*3 + {0:A-top,1:A-bot,2:B}]
    const int tid = threadIdx.x;
    const int wid = tid >> 6, lane = tid & 63;
    const int lq = lane >> 4, lc = lane & 15;
    const int wha = wid >> 2;          // A half (0/1): rows [wha*128, +128)
    const int wn = (wid & 3) * 32;     // col base within 128-wide tile
    const int sw = lc & 7;
    const int w = swz8(blockIdx.x, gridDim.x);
    const int bm = (w % Mt) * 256, bn = (w / Mt) * 128;
    const int NT = K >> 6;

    auto stageA = [&](int kt, int h) {
#pragma unroll
        for (int p = 0; p < 2; ++p) {
            const int cc = p * 512 + tid;
            const int row = cc >> 3, gk = ((cc & 7) ^ (row & 7)) * 8;
            load_lds16(A + (size_t)(bm + h * 128 + row) * K + (kt * 64 + gk),
                       &L[(kt & 1) * 3 + h][(size_t)cc * 8]);
        }
    };
    auto stageB = [&](int kt) {
#pragma unroll
        for (int p = 0; p < 2; ++p) {
            const int cc = p * 512 + tid;
            const int row = cc >> 3, gk = ((cc & 7) ^ (row & 7)) * 8;
            load_lds16(B + (size_t)(bn + row) * K + (kt * 64 + gk),
                       &L[(kt & 1) * 3 + 2][(size_t)cc * 8]);
        }
    };

    // prologue: stage K-tiles 0 and 1 (12 loads); wait tile 0 landed (6 left)
    stageA(0, 0); stageA(0, 1); stageB(0);
    stageA(1, 0); stageA(1, 1); stageB(1);
    asm volatile("s_waitcnt vmcnt(6)" ::: "memory");
    __builtin_amdgcn_s_barrier();
    __builtin_amdgcn_sched_barrier(0);

    const f32x4 fz = {0.f, 0.f, 0.f, 0.f};
    f32x4 acc[2][4][2];                 // [rowhalf][i][j]
#pragma unroll
    for (int rh = 0; rh < 2; ++rh)
#pragma unroll
        for (int i = 0; i < 4; ++i)
#pragma unroll
            for (int j = 0; j < 2; ++j) acc[rh][i][j] = fz;

    for (int t = 0; t < NT; ++t) {
        const __bf16* __restrict__ Ah = &L[(t & 1) * 3 + wha][0];
        const __bf16* __restrict__ Bb = &L[(t & 1) * 3 + 2][0];
        const int pf = (t + 2 < NT);
        bf16x8 a0[2][4], a1[2][4], b[2][2];

        // ---- phase 0: read ALL tile-t fragments (20 b128); MFMA row-half 0
#pragma unroll
        for (int kk = 0; kk < 2; ++kk) {
            const int sl = ((kk * 4 + lq) ^ sw) * 8;
#pragma unroll
            for (int i = 0; i < 4; ++i) {
                a0[kk][i] = *(const bf16x8*)&Ah[(i * 16 + lc) * 64 + sl];
                a1[kk][i] = *(const bf16x8*)&Ah[(64 + i * 16 + lc) * 64 + sl];
            }
#pragma unroll
            for (int j = 0; j < 2; ++j)
                b[kk][j] = *(const bf16x8*)&Bb[(wn + j * 16 + lc) * 64 + sl];
        }
        __builtin_amdgcn_s_barrier();
        asm volatile("s_waitcnt lgkmcnt(0)" ::: "memory");
        __builtin_amdgcn_sched_barrier(0);
        __builtin_amdgcn_s_setprio(1);
#pragma unroll
        for (int kk = 0; kk < 2; ++kk)
#pragma unroll
            for (int i = 0; i < 4; ++i)
#pragma unroll
                for (int j = 0; j < 2; ++j)
                    acc[0][i][j] = mfma16(a0[kk][i], b[kk][j], acc[0][i][j]);
        __builtin_amdgcn_s_setprio(0);
        __builtin_amdgcn_s_barrier();
        __builtin_amdgcn_sched_barrier(0);

        // ---- phase 1: stage tile t+2 (all reads of parity done); MFMA rh 1
        if (pf) { stageB(t + 2); stageA(t + 2, 0); stageA(t + 2, 1); }
        __builtin_amdgcn_s_setprio(1);
#pragma unroll
        for (int kk = 0; kk < 2; ++kk)
#pragma unroll
            for (int i = 0; i < 4; ++i)
#pragma unroll
                for (int j = 0; j < 2; ++j)
                    acc[1][i][j] = mfma16(a1[kk][i], b[kk][j], acc[1][i][j]);
        __builtin_amdgcn_s_setprio(0);
        if (pf) asm volatile("s_waitcnt vmcnt(6)" ::: "memory");
        else    asm volatile("s_waitcnt vmcnt(0)" ::: "memory");
        __builtin_amdgcn_s_barrier();
        __builtin_amdgcn_sched_barrier(0);
    }

    // epilogue: row-major, both 16-col chunks per row back-to-back
    float bv[2];
    bv[0] = bias[bn + wn + lc];
    bv[1] = bias[bn + wn + 16 + lc];
#pragma unroll
    for (int rh = 0; rh < 2; ++rh)
#pragma unroll
        for (int i = 0; i < 4; ++i)
#pragma unroll
            for (int r = 0; r < 4; ++r) {
                const int row = bm + wha * 128 + rh * 64 + i * 16 + lq * 4 + r;
                const size_t base = (size_t)row * N + bn + wn + lc;
#pragma unroll
                for (int j = 0; j < 2; ++j) {
                    float v = (acc[rh][i][j][r] + bv[j]) * scale;
                    if (relu) v = fmaxf(v, 0.f);
                    C[base + j * 16] = (__bf16)v;
                }
            }
}

// ---------------------------------------------------------------------------
// Legacy 2-phase core (qkv): C[128 x BN] tile, BK=64, R3 swizzle.
template <int BN>
__device__ __forceinline__ void gemm_core(
    const __bf16* __restrict__ A, const __bf16* __restrict__ B,
    const float* __restrict__ bias, __bf16* __restrict__ C,
    int M, int N, int K, float scale, int relu, int bm, int bn,
    __bf16* As, __bf16* Bs)
{
    const int tid = threadIdx.x;
    const int wave = tid >> 6, lane = tid & 63;
    const int lq = lane >> 4, lc = lane & 15;
    const int WN = BN / 2;
    const int JT = WN / 16;
    const int wm = (wave >> 1) * 64, wn = (wave & 1) * WN;

    const f32x4 fz = {0.f, 0.f, 0.f, 0.f};
    f32x4 acc[4][4];
#pragma unroll
    for (int i = 0; i < 4; ++i)
#pragma unroll
        for (int j = 0; j < JT; ++j) acc[i][j] = fz;

    const int sw = lc & 7;

    for (int k0 = 0; k0 < K; k0 += 64) {
        __syncthreads();
#pragma unroll
        for (int i = 0; i < 4; ++i) {
            const int c = tid + 256 * i;
            const int row = c >> 3, gk = ((c & 7) ^ (row & 7)) * 8;
            load_lds16(A + (size_t)(bm + row) * K + (k0 + gk),
                       As + (size_t)c * 8);
        }
#pragma unroll
        for (int i = 0; i < BN / 32; ++i) {
            const int c = tid + 256 * i;
            const int row = c >> 3, gk = ((c & 7) ^ (row & 7)) * 8;
            load_lds16(B + (size_t)(bn + row) * K + (k0 + gk),
                       Bs + (size_t)c * 8);
        }
        __syncthreads();
#pragma unroll
        for (int kk = 0; kk < 2; ++kk) {
            bf16x8 af[4], bw[4];
            const int slot = ((kk * 4 + lq) ^ sw) * 8;
#pragma unroll
            for (int i = 0; i < 4; ++i)
                af[i] = *(const bf16x8*)&As[(wm + i * 16 + lc) * 64 + slot];
#pragma unroll
            for (int j = 0; j < JT; ++j)
                bw[j] = *(const bf16x8*)&Bs[(wn + j * 16 + lc) * 64 + slot];
#pragma unroll
            for (int i = 0; i < 4; ++i)
#pragma unroll
                for (int j = 0; j < JT; ++j)
                    acc[i][j] = mfma16(af[i], bw[j], acc[i][j]);
        }
    }

#pragma unroll
    for (int j = 0; j < JT; ++j) {
        const int col = bn + wn + j * 16 + lc;
        const float bv = bias[col];
#pragma unroll
        for (int i = 0; i < 4; ++i) {
#pragma unroll
            for (int r = 0; r < 4; ++r) {
                float v = (acc[i][j][r] + bv) * scale;
                if (relu) v = fmaxf(v, 0.f);
                const int row = bm + wm + i * 16 + lq * 4 + r;
                C[(size_t)row * N + col] = (__bf16)v;
            }
        }
    }
}

// Fused q/k/v projection: flat grid 1536 blocks, BN=64.
__global__ __launch_bounds__(256) void gemm_qkv(
    const __bf16* __restrict__ TGT, const __bf16* __restrict__ KIN,
    const __bf16* __restrict__ VIN, const __bf16* __restrict__ W,
    const float* __restrict__ bias, __bf16* __restrict__ PROJ,
    __bf16* __restrict__ KB, __bf16* __restrict__ VB)
{
    __shared__ __bf16 As[128 * 64];
    __shared__ __bf16 Bs[64 * 64];
    const int bid = swz8(blockIdx.x, 1536);   // XCD-contiguous tile runs
    const __bf16* A; __bf16* Cout; int M, t, seg; float scale;
    if (bid < 1024)      { seg = 0; t = bid;        A = TGT; Cout = PROJ; M = 8192; scale = 0.125f; }
    else if (bid < 1280) { seg = 1; t = bid - 1024; A = KIN; Cout = KB;   M = 2048; scale = 1.f; }
    else                 { seg = 2; t = bid - 1280; A = VIN; Cout = VB;   M = 2048; scale = 1.f; }
    gemm_core<64>(A, W + (size_t)seg * 1048576, bias + seg * 1024, Cout,
                  M, 1024, 1024, scale, 0, (t >> 4) * 128, (t & 15) * 64, As, Bs);
}

// ---------------------------------------------------------------------------
// transpose V per (n,h): vt[(n*16+h)*64 + d][s] = v[(s*2+n)*1024 + h*64 + d]
__global__ __launch_bounds__(256) void transpose_v(const __bf16* __restrict__ v,
                                                   __bf16* __restrict__ vt) {
    __shared__ __bf16 t[64][72];
    const int tid = threadIdx.x;
    const int s0 = blockIdx.x * 64, h = blockIdx.y, n = blockIdx.z;
#pragma unroll
    for (int i = 0; i < 2; ++i) {
        const int cc = tid + 256 * i, row = cc >> 3, kc = (cc & 7) * 8;
        *(uint4*)&t[row][kc] =
            *(const uint4*)(v + ((size_t)((s0 + row) * 2 + n)) * 1024 + h * 64 + kc);
    }
    __syncthreads();
#pragma unroll
    for (int i = 0; i < 2; ++i) {
        const int cc = tid + 256 * i, d = cc >> 3, jc = (cc & 7) * 8;
        __attribute__((aligned(16))) __bf16 tmp[8];
#pragma unroll
        for (int u = 0; u < 8; ++u) tmp[u] = t[jc + u][d];
        *(uint4*)(vt + ((size_t)((n * 16 + h) * 64 + d)) * 1024 + s0 + jc) = *(uint4*)tmp;
    }
}

// ---------------------------------------------------------------------------
// Fused attention (R2 design): O = (sum e^s v) / (1 + sum e^s); cvec saved.
__global__ __launch_bounds__(256) void attn_fused(
    const __bf16* __restrict__ q, const __bf16* __restrict__ kk,
    const __bf16* __restrict__ vt, float* __restrict__ cvec,
    __bf16* __restrict__ aout)
{
    __shared__ __bf16 qs[64][72];
    __shared__ __bf16 ks[64][72];
    __shared__ __bf16 vs[64][72];
    __shared__ __bf16 es[64][72];
    const int tid = threadIdx.x, wave = tid >> 6, lane = tid & 63;
    const int lq = lane >> 4, lc = lane & 15;
    const int o = (blockIdx.z * 16 + blockIdx.y) * 64 + blockIdx.x;
    const int w = swz8(o, 2048);
    const int l0 = (w & 63) * 64, h = (w >> 6) & 15, n = w >> 10;
    const int wr = wave * 16;
#pragma unroll
    for (int i = 0; i < 2; ++i) {
        const int cc = tid + 256 * i, row = cc >> 3, kc = (cc & 7) * 8;
        *(uint4*)&qs[row][kc] =
            *(const uint4*)(q + ((size_t)((l0 + row) * 2 + n)) * 1024 + h * 64 + kc);
    }
    const f32x4 fz = {0.f, 0.f, 0.f, 0.f};
    f32x4 oacc[4];
#pragma unroll
    for (int dj = 0; dj < 4; ++dj) oacc[dj] = fz;
    float den[4] = {0.f, 0.f, 0.f, 0.f};

    for (int st = 0; st < 16; ++st) {
        __syncthreads();
#pragma unroll
        for (int i = 0; i < 2; ++i) {
            const int cc = tid + 256 * i, row = cc >> 3, kc = (cc & 7) * 8;
            *(uint4*)&ks[row][kc] =
                *(const uint4*)(kk + ((size_t)((st * 64 + row) * 2 + n)) * 1024 + h * 64 + kc);
            *(uint4*)&vs[row][kc] =
                *(const uint4*)(vt + ((size_t)((n * 16 + h) * 64 + row)) * 1024 + st * 64 + kc);
        }
        __syncthreads();
        const bf16x8 a0 = *(const bf16x8*)&qs[wr + lc][lq * 8];
        const bf16x8 a1 = *(const bf16x8*)&qs[wr + lc][32 + lq * 8];
#pragma unroll
        for (int sj = 0; sj < 4; ++sj) {
            f32x4 acc = fz;
            const bf16x8 b0 = *(const bf16x8*)&ks[sj * 16 + lc][lq * 8];
            const bf16x8 b1 = *(const bf16x8*)&ks[sj * 16 + lc][32 + lq * 8];
            acc = mfma16(a0, b0, acc);
            acc = mfma16(a1, b1, acc);
#pragma unroll
            for (int r = 0; r < 4; ++r) {
                const float e = __expf(acc[r]);
                den[r] += e;
                es[wr + lq * 4 + r][sj * 16 + lc] = (__bf16)e;
            }
        }
        const bf16x8 w0 = *(const bf16x8*)&es[wr + lc][lq * 8];
        const bf16x8 w1 = *(const bf16x8*)&es[wr + lc][32 + lq * 8];
#pragma unroll
        for (int dj = 0; dj < 4; ++dj) {
            const bf16x8 v0 = *(const bf16x8*)&vs[dj * 16 + lc][lq * 8];
            const bf16x8 v1 = *(const bf16x8*)&vs[dj * 16 + lc][32 + lq * 8];
            oacc[dj] = mfma16(w0, v0, oacc[dj]);
            oacc[dj] = mfma16(w1, v1, oacc[dj]);
        }
    }
#pragma unroll
    for (int m = 1; m < 16; m <<= 1)
#pragma unroll
        for (int r = 0; r < 4; ++r) den[r] += __shfl_xor(den[r], m);
    float c_r[4];
#pragma unroll
    for (int r = 0; r < 4; ++r) c_r[r] = 1.f / (den[r] + 1.f);
    if (lc == 0) {
#pragma unroll
        for (int r = 0; r < 4; ++r)
            cvec[((size_t)(n * 16 + h)) * 4096 + (l0 + wr + lq * 4 + r)] = c_r[r];
    }
    // row-major store: each row's 128B head-slice in 4 consecutive stores
#pragma unroll
    for (int r = 0; r < 4; ++r) {
        const int l = l0 + wr + lq * 4 + r;
        const size_t base = ((size_t)l * 2 + n) * 1024 + h * 64 + lc;
#pragma unroll
        for (int dj = 0; dj < 4; ++dj)
            aout[base + dj * 16] = (__bf16)(oacc[dj][r] * c_r[r]);
    }
}

// ---------------------------------------------------------------------------
// attn_map[n][l][s] = mean_h sigmoid(w); sigmoid via Taylor poly on (0,1).
__global__ __launch_bounds__(256) void attn_map_k(
    const __bf16* __restrict__ q, const __bf16* __restrict__ kk,
    const float* __restrict__ cvec, float* __restrict__ amap)
{
    __shared__ __bf16 qs[64][72];
    __shared__ __bf16 ks[64][72];
    const int tid = threadIdx.x, wave = tid >> 6, lane = tid & 63;
    const int lq = lane >> 4, lc = lane & 15;
    const int o = (blockIdx.z * 16 + blockIdx.y) * 64 + blockIdx.x;
    const int w = swz8(o, 2048);
    const int l0 = (w & 63) * 64, st = (w >> 6) & 15, n = w >> 10;
    const int wr = wave * 16;
    float sig[4][4];
#pragma unroll
    for (int sj = 0; sj < 4; ++sj)
#pragma unroll
        for (int r = 0; r < 4; ++r) sig[sj][r] = 0.f;

    for (int h = 0; h < 16; ++h) {
        __syncthreads();
#pragma unroll
        for (int i = 0; i < 2; ++i) {
            const int cc = tid + 256 * i, row = cc >> 3, kc = (cc & 7) * 8;
            *(uint4*)&qs[row][kc] =
                *(const uint4*)(q + ((size_t)((l0 + row) * 2 + n)) * 1024 + h * 64 + kc);
            *(uint4*)&ks[row][kc] =
                *(const uint4*)(kk + ((size_t)((st * 64 + row) * 2 + n)) * 1024 + h * 64 + kc);
        }
        __syncthreads();
        float c_r[4];
#pragma unroll
        for (int r = 0; r < 4; ++r)
            c_r[r] = cvec[((size_t)(n * 16 + h)) * 4096 + (l0 + wr + lq * 4 + r)];
        const bf16x8 a0 = *(const bf16x8*)&qs[wr + lc][lq * 8];
        const bf16x8 a1 = *(const bf16x8*)&qs[wr + lc][32 + lq * 8];
#pragma unroll
        for (int sj = 0; sj < 4; ++sj) {
            const f32x4 fz = {0.f, 0.f, 0.f, 0.f};
            f32x4 acc = fz;
            const bf16x8 b0 = *(const bf16x8*)&ks[sj * 16 + lc][lq * 8];
            const bf16x8 b1 = *(const bf16x8*)&ks[sj * 16 + lc][32 + lq * 8];
            acc = mfma16(a0, b0, acc);
            acc = mfma16(a1, b1, acc);
#pragma unroll
            for (int r = 0; r < 4; ++r) {
                const float ww = __expf(acc[r]) * c_r[r];   // w in (0,1)
                const float w2 = ww * ww;
                sig[sj][r] += 0.5f + ww * (0.25f - w2 * (1.f / 48.f - w2 * (1.f / 480.f)));
            }
        }
    }
    // row-major store: each row's 256B s-slice in 4 consecutive stores
#pragma unroll
    for (int r = 0; r < 4; ++r) {
        const int l = l0 + wr + lq * 4 + r;
        const size_t base = ((size_t)n * 4096 + l) * 1024 + st * 64 + lc;
#pragma unroll
        for (int sj = 0; sj < 4; ++sj)
            amap[base + sj * 16] = sig[sj][r] * (1.f / 16.f);
    }
}

// ---------------------------------------------------------------------------
// y = LN(base + add) * g + b; base is f32 (basef) or bf16 (baseb).
__global__ __launch_bounds__(256) void ln_k(
    const float* __restrict__ basef, const __bf16* __restrict__ baseb,
    const __bf16* __restrict__ add,
    const float* __restrict__ g, const float* __restrict__ bb,
    float* __restrict__ out_f32, __bf16* __restrict__ out_bf)
{
    __shared__ float red[8];
    const int row = blockIdx.x, tid = threadIdx.x;
    const int col = tid * 4;
    const size_t off = (size_t)row * 1024 + col;
    float v[4];
    if (basef) {
        float4 t = *(const float4*)(basef + off);
        v[0] = t.x; v[1] = t.y; v[2] = t.z; v[3] = t.w;
    } else {
        union { uint2 u; __bf16 h[4]; } tb;
        tb.u = *(const uint2*)(baseb + off);
#pragma unroll
        for (int j = 0; j < 4; ++j) v[j] = (float)tb.h[j];
    }
    {
        union { uint2 u; __bf16 h[4]; } ub;
        ub.u = *(const uint2*)(add + off);
#pragma unroll
        for (int j = 0; j < 4; ++j) v[j] += (float)ub.h[j];
    }
    float s = v[0] + v[1] + v[2] + v[3];
    float q = v[0] * v[0] + v[1] * v[1] + v[2] * v[2] + v[3] * v[3];
#pragma unroll
    for (int m = 1; m < 64; m <<= 1) { s += __shfl_xor(s, m); q += __shfl_xor(q, m); }
    const int wave = tid >> 6, lane = tid & 63;
    if (lane == 0) { red[wave] = s; red[4 + wave] = q; }
    __syncthreads();
    s = red[0] + red[1] + red[2] + red[3];
    q = red[4] + red[5] + red[6] + red[7];
    const float mu = s * (1.f / 1024.f);
    const float var = q * (1.f / 1024.f) - mu * mu;
    const float rs = rsqrtf(var + 1e-5f);
    const float4 gv = *(const float4*)(g + col);
    const float4 bv = *(const float4*)(bb + col);
    float y[4];
    y[0] = (v[0] - mu) * rs * gv.x + bv.x;
    y[1] = (v[1] - mu) * rs * gv.y + bv.y;
    y[2] = (v[2] - mu) * rs * gv.z + bv.z;
    y[3] = (v[3] - mu) * rs * gv.w + bv.w;
    if (out_f32) {
        float4 o; o.x = y[0]; o.y = y[1]; o.z = y[2]; o.w = y[3];
        *(float4*)(out_f32 + off) = o;
    }
    if (out_bf) {
        union { uint2 u; __bf16 h[4]; } ob;
#pragma unroll
        for (int j = 0; j < 4; ++j) ob.h[j] = (__bf16)y[j];
        *(uint2*)(out_bf + off) = ob.u;
    }
}

// ---------------------------------------------------------------------------
extern "C" void kernel_launch(void* const* d_in, const int* in_sizes, int n_in,
                              void* d_out, int out_size, void* d_ws, size_t ws_size,
                              hipStream_t stream) {
    const float* key_in    = (const float*)d_in[0];
    const float* value_in  = (const float*)d_in[1];
    const float* query     = (const float*)d_in[2];
    const float* in_proj_w = (const float*)d_in[3];
    const float* in_proj_b = (const float*)d_in[4];
    const float* out_w     = (const float*)d_in[5];
    const float* out_b     = (const float*)d_in[6];
    const float* ln1_g     = (const float*)d_in[7];
    const float* ln1_b     = (const float*)d_in[8];
    const float* ln2_g     = (const float*)d_in[9];
    const float* ln2_b     = (const float*)d_in[10];
    const float* ff1_w     = (const float*)d_in[11];
    const float* ff1_b     = (const float*)d_in[12];
    const float* ff2_w     = (const float*)d_in[13];
    const float* ff2_b     = (const float*)d_in[14];
    float* outp = (float*)d_out;

    __bf16* ws = (__bf16*)d_ws;
    const size_t M1 = 1048576;
    __bf16* WQKV = ws;               // 6 M1 (both layers)
    __bf16* WOUT = ws + 6 * M1;      // 2
    __bf16* WF1  = ws + 8 * M1;      // 8
    __bf16* WF2  = ws + 16 * M1;     // 8
    __bf16* KIN  = ws + 24 * M1;     // 2
    __bf16* VIN  = ws + 26 * M1;     // 2
    __bf16* TGT  = ws + 28 * M1;     // 8
    __bf16* PROJ = ws + 36 * M1;     // 8 (q-proj out; out-proj out)
    __bf16* KB   = ws + 44 * M1;     // 2
    __bf16* VB   = ws + 46 * M1;     // 2
    __bf16* VT   = ws + 48 * M1;     // 2
    __bf16* AOUT = ws + 50 * M1;     // 8 (attn out; ff2 out)
    __bf16* XB   = ws + 58 * M1;     // 8 (ln1 out, bf16)
    __bf16* H1   = ws + 66 * M1;     // 32
    float*  CVEC = (float*)(ws + 98 * M1);   // 131072 f32

    // upfront casts: inputs + ALL weights (both layers)
    cast_k<<<8192, 256, 0, stream>>>(query, TGT, 2097152);
    cast_k<<<2048, 256, 0, stream>>>(key_in, KIN, 524288);
    cast_k<<<2048, 256, 0, stream>>>(value_in, VIN, 524288);
    cast_k<<<6144, 256, 0, stream>>>(in_proj_w, WQKV, 1572864);
    cast_k<<<2048, 256, 0, stream>>>(out_w, WOUT, 524288);
    cast_k<<<8192, 256, 0, stream>>>(ff1_w, WF1, 2097152);
    cast_k<<<8192, 256, 0, stream>>>(ff2_w, WF2, 2097152);

    for (int i = 0; i < 2; ++i) {
        __bf16* WQKVi = WQKV + (size_t)i * 3 * M1;
        __bf16* WOUTi = WOUT + (size_t)i * M1;
        __bf16* WF1i  = WF1 + (size_t)i * 4 * M1;
        __bf16* WF2i  = WF2 + (size_t)i * 4 * M1;

        // fused q/k/v projections (one dispatch, 1536 blocks)
        gemm_qkv<<<1536, 256, 0, stream>>>(TGT, KIN, VIN, WQKVi,
                                           in_proj_b + i * 3072, PROJ, KB, VB);
        transpose_v<<<dim3(16, 16, 2), 256, 0, stream>>>(VB, VT);

        attn_fused<<<dim3(64, 16, 2), 256, 0, stream>>>(PROJ, KB, VT, CVEC, AOUT);
        if (i == 1)
            attn_map_k<<<dim3(64, 16, 2), 256, 0, stream>>>(PROJ, KB, CVEC,
                                                            outp + 8388608);

        // out projection: pipelined 256x128 (256 blocks = 1 CU round)
        gemm8pN<<<256, 512, 0, stream>>>(AOUT, WOUTi, out_b + i * 1024,
                                         PROJ, 32, 1024, 1024, 1.f, 0);
        // LN1: base = query (f32, layer 0) or TGT (bf16)
        ln_k<<<8192, 256, 0, stream>>>(i == 0 ? query : nullptr,
                                       i == 0 ? nullptr : TGT,
                                       PROJ, ln1_g + i * 1024, ln1_b + i * 1024,
                                       nullptr, XB);
        // FFN: ff1 via 8-phase 256x256 pipeline (512 blocks = 2 CU rounds),
        // ff2 via 256x128 pipeline (256 blocks, K=4096 deep pipeline)
        gemm8p<<<512, 512, 0, stream>>>(XB, WF1i, ff1_b + i * 4096,
                                        H1, 32, 4096, 1024, 1.f, 1);
        gemm8pN<<<256, 512, 0, stream>>>(H1, WF2i, ff2_b + i * 1024,
                                         AOUT, 32, 1024, 4096, 1.f, 0);
        // LN2: base = XB (bf16); final layer also writes f32 tgt to d_out
        ln_k<<<8192, 256, 0, stream>>>(nullptr, XB, AOUT,
                                       ln2_g + i * 1024, ln2_b + i * 1024,
                                       i == 1 ? outp : nullptr, TGT);
    }
}

// Round 7
// 890.990 us; speedup vs baseline: 1.3771x; 1.0267x over previous
//
#include <hip/hip_runtime.h>
#include <hip/hip_bf16.h>

// ---------------------------------------------------------------------------
// PadTransformer R10 (resubmit; previous round failed on container infra,
// not kernel): R9 + corrected tile->XCD traversal order in the pipelined
// GEMMs. R9 decoded row-fastest, so each XCD swept one column panel over
// ALL row strips -> A re-streamed once per column panel (ff2 FETCH 266MB vs
// 72MB compulsory). Now bn is fastest within each XCD's contiguous swizzled
// run: one A row-strip stays L2-resident across all its column panels (the
// traffic pattern R8's gemm64 counters validated). Pure index permutation -
// numerics identical.
// ---------------------------------------------------------------------------

typedef __bf16 bf16x8 __attribute__((ext_vector_type(8)));
typedef float  f32x4  __attribute__((ext_vector_type(4)));

__device__ __forceinline__ f32x4 mfma16(bf16x8 a, bf16x8 b, f32x4 c) {
    return __builtin_amdgcn_mfma_f32_16x16x32_bf16(a, b, c, 0, 0, 0);
}

__device__ __forceinline__ void load_lds16(const __bf16* g, __bf16* l) {
    __builtin_amdgcn_global_load_lds(
        (const __attribute__((address_space(1))) void*)g,
        (__attribute__((address_space(3))) void*)l, 16, 0, 0);
}

// bijective XCD swizzle; valid when nwg % 8 == 0 (true for every launch here)
__device__ __forceinline__ int swz8(int o, int nwg) {
    return (o & 7) * (nwg >> 3) + (o >> 3);
}

// ---------------------------------------------------------------------------
__global__ __launch_bounds__(256) void cast_k(const float* __restrict__ in,
                                              __bf16* __restrict__ out, int n4) {
    int i = blockIdx.x * 256 + threadIdx.x;
    if (i >= n4) return;
    float4 f = ((const float4*)in)[i];
    union { uint2 u; __bf16 h[4]; } ob;
    ob.h[0] = (__bf16)f.x; ob.h[1] = (__bf16)f.y;
    ob.h[2] = (__bf16)f.z; ob.h[3] = (__bf16)f.w;
    ((uint2*)out)[i] = ob.u;
}

// ---------------------------------------------------------------------------
// 8-phase pipelined 256x256 GEMM (ff1). C = A[M][K] * B[N][K]^T + bias.
__global__ __launch_bounds__(512, 2) void gemm8p(
    const __bf16* __restrict__ A, const __bf16* __restrict__ B,
    const float* __restrict__ bias, __bf16* __restrict__ C,
    int N, int K, float scale, int relu)
{
    // 8 half-tile slots: [parity*4 + {0:A-top,1:A-bot,2:B-left,3:B-right}]
    __shared__ __bf16 L[8][8192];      // 128 KiB
    const int tid = threadIdx.x;
    const int wid = tid >> 6, lane = tid & 63;
    const int lq = lane >> 4, lc = lane & 15;
    const int wm = wid >> 2;           // row half (0/1): rows [wm*128, +128)
    const int wn = (wid & 3) * 64;     // col base: 0,64,128,192
    const int bh = wn >> 7;            // B half id
    const int lb = wn & 127;           // local col within B half (0 or 64)
    const int sw = lc & 7;
    const int w = swz8(blockIdx.x, gridDim.x);
    const int nt = N >> 8;             // column panels (fastest within XCD run)
    const int bm = (w / nt) * 256, bn = (w % nt) * 256;
    const int NT = K >> 6;

    auto stageA = [&](int kt, int h) {
#pragma unroll
        for (int p = 0; p < 2; ++p) {
            const int cc = p * 512 + tid;
            const int row = cc >> 3, gk = ((cc & 7) ^ (row & 7)) * 8;
            load_lds16(A + (size_t)(bm + h * 128 + row) * K + (kt * 64 + gk),
                       &L[(kt & 1) * 4 + h][(size_t)cc * 8]);
        }
    };
    auto stageB = [&](int kt, int h) {
#pragma unroll
        for (int p = 0; p < 2; ++p) {
            const int cc = p * 512 + tid;
            const int row = cc >> 3, gk = ((cc & 7) ^ (row & 7)) * 8;
            load_lds16(B + (size_t)(bn + h * 128 + row) * K + (kt * 64 + gk),
                       &L[(kt & 1) * 4 + 2 + h][(size_t)cc * 8]);
        }
    };

    // prologue: stage K-tiles 0 and 1 (16 loads); wait tile 0 landed (8 left)
    stageA(0, 0); stageA(0, 1); stageB(0, 0); stageB(0, 1);
    stageA(1, 0); stageA(1, 1); stageB(1, 0); stageB(1, 1);
    asm volatile("s_waitcnt vmcnt(8)" ::: "memory");
    __builtin_amdgcn_s_barrier();
    __builtin_amdgcn_sched_barrier(0);

    const f32x4 fz = {0.f, 0.f, 0.f, 0.f};
    f32x4 acc[2][4][4];                 // [rowhalf][i][ch*2+j]
#pragma unroll
    for (int rh = 0; rh < 2; ++rh)
#pragma unroll
        for (int i = 0; i < 4; ++i)
#pragma unroll
            for (int jj = 0; jj < 4; ++jj) acc[rh][i][jj] = fz;

    for (int t = 0; t < NT; ++t) {
        const __bf16* __restrict__ Ah = &L[(t & 1) * 4 + wm][0];
        const __bf16* __restrict__ Bh = &L[(t & 1) * 4 + 2 + bh][0];
        const int pf = (t + 2 < NT);
        bf16x8 a[2][4], b0[2][2], b1[2][2];

        // ---- phase 0: read A rows 0-63 + B cols lb+0..31; MFMA quad (0,0)
#pragma unroll
        for (int kk = 0; kk < 2; ++kk) {
            const int sl = ((kk * 4 + lq) ^ sw) * 8;
#pragma unroll
            for (int i = 0; i < 4; ++i)
                a[kk][i] = *(const bf16x8*)&Ah[(i * 16 + lc) * 64 + sl];
#pragma unroll
            for (int j = 0; j < 2; ++j)
                b0[kk][j] = *(const bf16x8*)&Bh[(lb + j * 16 + lc) * 64 + sl];
        }
        __builtin_amdgcn_s_barrier();
        asm volatile("s_waitcnt lgkmcnt(0)" ::: "memory");
        __builtin_amdgcn_sched_barrier(0);
        __builtin_amdgcn_s_setprio(1);
#pragma unroll
        for (int kk = 0; kk < 2; ++kk)
#pragma unroll
            for (int i = 0; i < 4; ++i)
#pragma unroll
                for (int j = 0; j < 2; ++j)
                    acc[0][i][j] = mfma16(a[kk][i], b0[kk][j], acc[0][i][j]);
        __builtin_amdgcn_s_setprio(0);
        __builtin_amdgcn_s_barrier();
        __builtin_amdgcn_sched_barrier(0);

        // ---- phase 1: read B cols lb+32..63; MFMA quad (0,1)
#pragma unroll
        for (int kk = 0; kk < 2; ++kk) {
            const int sl = ((kk * 4 + lq) ^ sw) * 8;
#pragma unroll
            for (int j = 0; j < 2; ++j)
                b1[kk][j] = *(const bf16x8*)&Bh[(lb + 32 + j * 16 + lc) * 64 + sl];
        }
        __builtin_amdgcn_s_barrier();
        asm volatile("s_waitcnt lgkmcnt(0)" ::: "memory");
        __builtin_amdgcn_sched_barrier(0);
        __builtin_amdgcn_s_setprio(1);
#pragma unroll
        for (int kk = 0; kk < 2; ++kk)
#pragma unroll
            for (int i = 0; i < 4; ++i)
#pragma unroll
                for (int j = 0; j < 2; ++j)
                    acc[0][i][2 + j] = mfma16(a[kk][i], b1[kk][j], acc[0][i][2 + j]);
        __builtin_amdgcn_s_setprio(0);
        __builtin_amdgcn_s_barrier();
        __builtin_amdgcn_sched_barrier(0);

        // ---- phase 2: read A rows 64-127; stage B(t+2); MFMA quad (1,0)
#pragma unroll
        for (int kk = 0; kk < 2; ++kk) {
            const int sl = ((kk * 4 + lq) ^ sw) * 8;
#pragma unroll
            for (int i = 0; i < 4; ++i)
                a[kk][i] = *(const bf16x8*)&Ah[(64 + i * 16 + lc) * 64 + sl];
        }
        if (pf) { stageB(t + 2, 0); stageB(t + 2, 1); }
        __builtin_amdgcn_s_barrier();
        asm volatile("s_waitcnt lgkmcnt(0)" ::: "memory");
        __builtin_amdgcn_sched_barrier(0);
        __builtin_amdgcn_s_setprio(1);
#pragma unroll
        for (int kk = 0; kk < 2; ++kk)
#pragma unroll
            for (int i = 0; i < 4; ++i)
#pragma unroll
                for (int j = 0; j < 2; ++j)
                    acc[1][i][j] = mfma16(a[kk][i], b0[kk][j], acc[1][i][j]);
        __builtin_amdgcn_s_setprio(0);
        __builtin_amdgcn_s_barrier();
        __builtin_amdgcn_sched_barrier(0);

        // ---- phase 3: stage A(t+2); MFMA quad (1,1); per-tile vmcnt
        if (pf) { stageA(t + 2, 0); stageA(t + 2, 1); }
        __builtin_amdgcn_s_barrier();
        __builtin_amdgcn_sched_barrier(0);
        __builtin_amdgcn_s_setprio(1);
#pragma unroll
        for (int kk = 0; kk < 2; ++kk)
#pragma unroll
            for (int i = 0; i < 4; ++i)
#pragma unroll
                for (int j = 0; j < 2; ++j)
                    acc[1][i][2 + j] = mfma16(a[kk][i], b1[kk][j], acc[1][i][2 + j]);
        __builtin_amdgcn_s_setprio(0);
        if (pf) asm volatile("s_waitcnt vmcnt(8)" ::: "memory");
        else    asm volatile("s_waitcnt vmcnt(0)" ::: "memory");
        __builtin_amdgcn_s_barrier();
        __builtin_amdgcn_sched_barrier(0);
    }

    // epilogue: ROW-MAJOR order (R8): full 128B line per row, consecutive.
    float bv[4];
#pragma unroll
    for (int q = 0; q < 4; ++q) bv[q] = bias[bn + wn + q * 16 + lc];
#pragma unroll
    for (int rh = 0; rh < 2; ++rh)
#pragma unroll
        for (int i = 0; i < 4; ++i)
#pragma unroll
            for (int r = 0; r < 4; ++r) {
                const int row = bm + wm * 128 + rh * 64 + i * 16 + lq * 4 + r;
                const size_t base = (size_t)row * N + bn + wn + lc;
#pragma unroll
                for (int ch = 0; ch < 2; ++ch)
#pragma unroll
                    for (int j = 0; j < 2; ++j) {
                        float v = (acc[rh][i][ch * 2 + j][r] + bv[ch * 2 + j]) * scale;
                        if (relu) v = fmaxf(v, 0.f);
                        C[base + ch * 32 + j * 16] = (__bf16)v;
                    }
            }
}

// ---------------------------------------------------------------------------
// Pipelined 256x128 GEMM (ff2 / out-proj, N=1024 -> 256 blocks).
// 8 waves, per-wave 128x32. LDS 6 slots x 16 KiB (A-top/A-bot/B x 2 parity).
__global__ __launch_bounds__(512, 2) void gemm8pN(
    const __bf16* __restrict__ A, const __bf16* __restrict__ B,
    const float* __restrict__ bias, __bf16* __restrict__ C,
    int N, int K, float scale, int relu)
{
    __shared__ __bf16 L[6][8192];      // 96 KiB: [par*3 + {0:A-top,1:A-bot,2:B}]
    const int tid = threadIdx.x;
    const int wid = tid >> 6, lane = tid & 63;
    const int lq = lane >> 4, lc = lane & 15;
    const int wha = wid >> 2;          // A half (0/1): rows [wha*128, +128)
    const int wn = (wid & 3) * 32;     // col base within 128-wide tile
    const int sw = lc & 7;
    const int w = swz8(blockIdx.x, gridDim.x);
    const int nt = N >> 7;             // column panels (fastest within XCD run)
    const int bm = (w / nt) * 256, bn = (w % nt) * 128;
    const int NT = K >> 6;

    auto stageA = [&](int kt, int h) {
#pragma unroll
        for (int p = 0; p < 2; ++p) {
            const int cc = p * 512 + tid;
            const int row = cc >> 3, gk = ((cc & 7) ^ (row & 7)) * 8;
            load_lds16(A + (size_t)(bm + h * 128 + row) * K + (kt * 64 + gk),
                       &L[(kt & 1) * 3 + h][(size_t)cc * 8]);
        }
    };
    auto stageB = [&](int kt) {
#pragma unroll
        for (int p = 0; p < 2; ++p) {
            const int cc = p * 512 + tid;
            const int row = cc >> 3, gk = ((cc & 7) ^ (row & 7)) * 8;
            load_lds16(B + (size_t)(bn + row) * K + (kt * 64 + gk),
                       &L[(kt & 1) * 3 + 2][(size_t)cc * 8]);
        }
    };

    // prologue: stage K-tiles 0 and 1 (12 loads); wait tile 0 landed (6 left)
    stageA(0, 0); stageA(0, 1); stageB(0);
    stageA(1, 0); stageA(1, 1); stageB(1);
    asm volatile("s_waitcnt vmcnt(6)" ::: "memory");
    __builtin_amdgcn_s_barrier();
    __builtin_amdgcn_sched_barrier(0);

    const f32x4 fz = {0.f, 0.f, 0.f, 0.f};
    f32x4 acc[2][4][2];                 // [rowhalf][i][j]
#pragma unroll
    for (int rh = 0; rh < 2; ++rh)
#pragma unroll
        for (int i = 0; i < 4; ++i)
#pragma unroll
            for (int j = 0; j < 2; ++j) acc[rh][i][j] = fz;

    for (int t = 0; t < NT; ++t) {
        const __bf16* __restrict__ Ah = &L[(t & 1) * 3 + wha][0];
        const __bf16* __restrict__ Bb = &L[(t & 1) * 3 + 2][0];
        const int pf = (t + 2 < NT);
        bf16x8 a0[2][4], a1[2][4], b[2][2];

        // ---- phase 0: read ALL tile-t fragments (20 b128); MFMA row-half 0
#pragma unroll
        for (int kk = 0; kk < 2; ++kk) {
            const int sl = ((kk * 4 + lq) ^ sw) * 8;
#pragma unroll
            for (int i = 0; i < 4; ++i) {
                a0[kk][i] = *(const bf16x8*)&Ah[(i * 16 + lc) * 64 + sl];
                a1[kk][i] = *(const bf16x8*)&Ah[(64 + i * 16 + lc) * 64 + sl];
            }
#pragma unroll
            for (int j = 0; j < 2; ++j)
                b[kk][j] = *(const bf16x8*)&Bb[(wn + j * 16 + lc) * 64 + sl];
        }
        __builtin_amdgcn_s_barrier();
        asm volatile("s_waitcnt lgkmcnt(0)" ::: "memory");
        __builtin_amdgcn_sched_barrier(0);
        __builtin_amdgcn_s_setprio(1);
#pragma unroll
        for (int kk = 0; kk < 2; ++kk)
#pragma unroll
            for (int i = 0; i < 4; ++i)
#pragma unroll
                for (int j = 0; j < 2; ++j)
                    acc[0][i][j] = mfma16(a0[kk][i], b[kk][j], acc[0][i][j]);
        __builtin_amdgcn_s_setprio(0);
        __builtin_amdgcn_s_barrier();
        __builtin_amdgcn_sched_barrier(0);

        // ---- phase 1: stage tile t+2 (all reads of parity done); MFMA rh 1
        if (pf) { stageB(t + 2); stageA(t + 2, 0); stageA(t + 2, 1); }
        __builtin_amdgcn_s_setprio(1);
#pragma unroll
        for (int kk = 0; kk < 2; ++kk)
#pragma unroll
            for (int i = 0; i < 4; ++i)
#pragma unroll
                for (int j = 0; j < 2; ++j)
                    acc[1][i][j] = mfma16(a1[kk][i], b[kk][j], acc[1][i][j]);
        __builtin_amdgcn_s_setprio(0);
        if (pf) asm volatile("s_waitcnt vmcnt(6)" ::: "memory");
        else    asm volatile("s_waitcnt vmcnt(0)" ::: "memory");
        __builtin_amdgcn_s_barrier();
        __builtin_amdgcn_sched_barrier(0);
    }

    // epilogue: row-major, both 16-col chunks per row back-to-back
    float bv[2];
    bv[0] = bias[bn + wn + lc];
    bv[1] = bias[bn + wn + 16 + lc];
#pragma unroll
    for (int rh = 0; rh < 2; ++rh)
#pragma unroll
        for (int i = 0; i < 4; ++i)
#pragma unroll
            for (int r = 0; r < 4; ++r) {
                const int row = bm + wha * 128 + rh * 64 + i * 16 + lq * 4 + r;
                const size_t base = (size_t)row * N + bn + wn + lc;
#pragma unroll
                for (int j = 0; j < 2; ++j) {
                    float v = (acc[rh][i][j][r] + bv[j]) * scale;
                    if (relu) v = fmaxf(v, 0.f);
                    C[base + j * 16] = (__bf16)v;
                }
            }
}

// ---------------------------------------------------------------------------
// Legacy 2-phase core (qkv): C[128 x BN] tile, BK=64, R3 swizzle.
template <int BN>
__device__ __forceinline__ void gemm_core(
    const __bf16* __restrict__ A, const __bf16* __restrict__ B,
    const float* __restrict__ bias, __bf16* __restrict__ C,
    int M, int N, int K, float scale, int relu, int bm, int bn,
    __bf16* As, __bf16* Bs)
{
    const int tid = threadIdx.x;
    const int wave = tid >> 6, lane = tid & 63;
    const int lq = lane >> 4, lc = lane & 15;
    const int WN = BN / 2;
    const int JT = WN / 16;
    const int wm = (wave >> 1) * 64, wn = (wave & 1) * WN;

    const f32x4 fz = {0.f, 0.f, 0.f, 0.f};
    f32x4 acc[4][4];
#pragma unroll
    for (int i = 0; i < 4; ++i)
#pragma unroll
        for (int j = 0; j < JT; ++j) acc[i][j] = fz;

    const int sw = lc & 7;

    for (int k0 = 0; k0 < K; k0 += 64) {
        __syncthreads();
#pragma unroll
        for (int i = 0; i < 4; ++i) {
            const int c = tid + 256 * i;
            const int row = c >> 3, gk = ((c & 7) ^ (row & 7)) * 8;
            load_lds16(A + (size_t)(bm + row) * K + (k0 + gk),
                       As + (size_t)c * 8);
        }
#pragma unroll
        for (int i = 0; i < BN / 32; ++i) {
            const int c = tid + 256 * i;
            const int row = c >> 3, gk = ((c & 7) ^ (row & 7)) * 8;
            load_lds16(B + (size_t)(bn + row) * K + (k0 + gk),
                       Bs + (size_t)c * 8);
        }
        __syncthreads();
#pragma unroll
        for (int kk = 0; kk < 2; ++kk) {
            bf16x8 af[4], bw[4];
            const int slot = ((kk * 4 + lq) ^ sw) * 8;
#pragma unroll
            for (int i = 0; i < 4; ++i)
                af[i] = *(const bf16x8*)&As[(wm + i * 16 + lc) * 64 + slot];
#pragma unroll
            for (int j = 0; j < JT; ++j)
                bw[j] = *(const bf16x8*)&Bs[(wn + j * 16 + lc) * 64 + slot];
#pragma unroll
            for (int i = 0; i < 4; ++i)
#pragma unroll
                for (int j = 0; j < JT; ++j)
                    acc[i][j] = mfma16(af[i], bw[j], acc[i][j]);
        }
    }

#pragma unroll
    for (int j = 0; j < JT; ++j) {
        const int col = bn + wn + j * 16 + lc;
        const float bv = bias[col];
#pragma unroll
        for (int i = 0; i < 4; ++i) {
#pragma unroll
            for (int r = 0; r < 4; ++r) {
                float v = (acc[i][j][r] + bv) * scale;
                if (relu) v = fmaxf(v, 0.f);
                const int row = bm + wm + i * 16 + lq * 4 + r;
                C[(size_t)row * N + col] = (__bf16)v;
            }
        }
    }
}

// Fused q/k/v projection: flat grid 1536 blocks, BN=64.
__global__ __launch_bounds__(256) void gemm_qkv(
    const __bf16* __restrict__ TGT, const __bf16* __restrict__ KIN,
    const __bf16* __restrict__ VIN, const __bf16* __restrict__ W,
    const float* __restrict__ bias, __bf16* __restrict__ PROJ,
    __bf16* __restrict__ KB, __bf16* __restrict__ VB)
{
    __shared__ __bf16 As[128 * 64];
    __shared__ __bf16 Bs[64 * 64];
    const int bid = swz8(blockIdx.x, 1536);   // XCD-contiguous tile runs
    const __bf16* A; __bf16* Cout; int M, t, seg; float scale;
    if (bid < 1024)      { seg = 0; t = bid;        A = TGT; Cout = PROJ; M = 8192; scale = 0.125f; }
    else if (bid < 1280) { seg = 1; t = bid - 1024; A = KIN; Cout = KB;   M = 2048; scale = 1.f; }
    else                 { seg = 2; t = bid - 1280; A = VIN; Cout = VB;   M = 2048; scale = 1.f; }
    gemm_core<64>(A, W + (size_t)seg * 1048576, bias + seg * 1024, Cout,
                  M, 1024, 1024, scale, 0, (t >> 4) * 128, (t & 15) * 64, As, Bs);
}

// ---------------------------------------------------------------------------
// transpose V per (n,h): vt[(n*16+h)*64 + d][s] = v[(s*2+n)*1024 + h*64 + d]
__global__ __launch_bounds__(256) void transpose_v(const __bf16* __restrict__ v,
                                                   __bf16* __restrict__ vt) {
    __shared__ __bf16 t[64][72];
    const int tid = threadIdx.x;
    const int s0 = blockIdx.x * 64, h = blockIdx.y, n = blockIdx.z;
#pragma unroll
    for (int i = 0; i < 2; ++i) {
        const int cc = tid + 256 * i, row = cc >> 3, kc = (cc & 7) * 8;
        *(uint4*)&t[row][kc] =
            *(const uint4*)(v + ((size_t)((s0 + row) * 2 + n)) * 1024 + h * 64 + kc);
    }
    __syncthreads();
#pragma unroll
    for (int i = 0; i < 2; ++i) {
        const int cc = tid + 256 * i, d = cc >> 3, jc = (cc & 7) * 8;
        __attribute__((aligned(16))) __bf16 tmp[8];
#pragma unroll
        for (int u = 0; u < 8; ++u) tmp[u] = t[jc + u][d];
        *(uint4*)(vt + ((size_t)((n * 16 + h) * 64 + d)) * 1024 + s0 + jc) = *(uint4*)tmp;
    }
}

// ---------------------------------------------------------------------------
// Fused attention (R2 design): O = (sum e^s v) / (1 + sum e^s); cvec saved.
__global__ __launch_bounds__(256) void attn_fused(
    const __bf16* __restrict__ q, const __bf16* __restrict__ kk,
    const __bf16* __restrict__ vt, float* __restrict__ cvec,
    __bf16* __restrict__ aout)
{
    __shared__ __bf16 qs[64][72];
    __shared__ __bf16 ks[64][72];
    __shared__ __bf16 vs[64][72];
    __shared__ __bf16 es[64][72];
    const int tid = threadIdx.x, wave = tid >> 6, lane = tid & 63;
    const int lq = lane >> 4, lc = lane & 15;
    const int o = (blockIdx.z * 16 + blockIdx.y) * 64 + blockIdx.x;
    const int w = swz8(o, 2048);
    const int l0 = (w & 63) * 64, h = (w >> 6) & 15, n = w >> 10;
    const int wr = wave * 16;
#pragma unroll
    for (int i = 0; i < 2; ++i) {
        const int cc = tid + 256 * i, row = cc >> 3, kc = (cc & 7) * 8;
        *(uint4*)&qs[row][kc] =
            *(const uint4*)(q + ((size_t)((l0 + row) * 2 + n)) * 1024 + h * 64 + kc);
    }
    const f32x4 fz = {0.f, 0.f, 0.f, 0.f};
    f32x4 oacc[4];
#pragma unroll
    for (int dj = 0; dj < 4; ++dj) oacc[dj] = fz;
    float den[4] = {0.f, 0.f, 0.f, 0.f};

    for (int st = 0; st < 16; ++st) {
        __syncthreads();
#pragma unroll
        for (int i = 0; i < 2; ++i) {
            const int cc = tid + 256 * i, row = cc >> 3, kc = (cc & 7) * 8;
            *(uint4*)&ks[row][kc] =
                *(const uint4*)(kk + ((size_t)((st * 64 + row) * 2 + n)) * 1024 + h * 64 + kc);
            *(uint4*)&vs[row][kc] =
                *(const uint4*)(vt + ((size_t)((n * 16 + h) * 64 + row)) * 1024 + st * 64 + kc);
        }
        __syncthreads();
        const bf16x8 a0 = *(const bf16x8*)&qs[wr + lc][lq * 8];
        const bf16x8 a1 = *(const bf16x8*)&qs[wr + lc][32 + lq * 8];
#pragma unroll
        for (int sj = 0; sj < 4; ++sj) {
            f32x4 acc = fz;
            const bf16x8 b0 = *(const bf16x8*)&ks[sj * 16 + lc][lq * 8];
            const bf16x8 b1 = *(const bf16x8*)&ks[sj * 16 + lc][32 + lq * 8];
            acc = mfma16(a0, b0, acc);
            acc = mfma16(a1, b1, acc);
#pragma unroll
            for (int r = 0; r < 4; ++r) {
                const float e = __expf(acc[r]);
                den[r] += e;
                es[wr + lq * 4 + r][sj * 16 + lc] = (__bf16)e;
            }
        }
        const bf16x8 w0 = *(const bf16x8*)&es[wr + lc][lq * 8];
        const bf16x8 w1 = *(const bf16x8*)&es[wr + lc][32 + lq * 8];
#pragma unroll
        for (int dj = 0; dj < 4; ++dj) {
            const bf16x8 v0 = *(const bf16x8*)&vs[dj * 16 + lc][lq * 8];
            const bf16x8 v1 = *(const bf16x8*)&vs[dj * 16 + lc][32 + lq * 8];
            oacc[dj] = mfma16(w0, v0, oacc[dj]);
            oacc[dj] = mfma16(w1, v1, oacc[dj]);
        }
    }
#pragma unroll
    for (int m = 1; m < 16; m <<= 1)
#pragma unroll
        for (int r = 0; r < 4; ++r) den[r] += __shfl_xor(den[r], m);
    float c_r[4];
#pragma unroll
    for (int r = 0; r < 4; ++r) c_r[r] = 1.f / (den[r] + 1.f);
    if (lc == 0) {
#pragma unroll
        for (int r = 0; r < 4; ++r)
            cvec[((size_t)(n * 16 + h)) * 4096 + (l0 + wr + lq * 4 + r)] = c_r[r];
    }
    // row-major store: each row's 128B head-slice in 4 consecutive stores
#pragma unroll
    for (int r = 0; r < 4; ++r) {
        const int l = l0 + wr + lq * 4 + r;
        const size_t base = ((size_t)l * 2 + n) * 1024 + h * 64 + lc;
#pragma unroll
        for (int dj = 0; dj < 4; ++dj)
            aout[base + dj * 16] = (__bf16)(oacc[dj][r] * c_r[r]);
    }
}

// ---------------------------------------------------------------------------
// attn_map[n][l][s] = mean_h sigmoid(w); sigmoid via Taylor poly on (0,1).
__global__ __launch_bounds__(256) void attn_map_k(
    const __bf16* __restrict__ q, const __bf16* __restrict__ kk,
    const float* __restrict__ cvec, float* __restrict__ amap)
{
    __shared__ __bf16 qs[64][72];
    __shared__ __bf16 ks[64][72];
    const int tid = threadIdx.x, wave = tid >> 6, lane = tid & 63;
    const int lq = lane >> 4, lc = lane & 15;
    const int o = (blockIdx.z * 16 + blockIdx.y) * 64 + blockIdx.x;
    const int w = swz8(o, 2048);
    const int l0 = (w & 63) * 64, st = (w >> 6) & 15, n = w >> 10;
    const int wr = wave * 16;
    float sig[4][4];
#pragma unroll
    for (int sj = 0; sj < 4; ++sj)
#pragma unroll
        for (int r = 0; r < 4; ++r) sig[sj][r] = 0.f;

    for (int h = 0; h < 16; ++h) {
        __syncthreads();
#pragma unroll
        for (int i = 0; i < 2; ++i) {
            const int cc = tid + 256 * i, row = cc >> 3, kc = (cc & 7) * 8;
            *(uint4*)&qs[row][kc] =
                *(const uint4*)(q + ((size_t)((l0 + row) * 2 + n)) * 1024 + h * 64 + kc);
            *(uint4*)&ks[row][kc] =
                *(const uint4*)(kk + ((size_t)((st * 64 + row) * 2 + n)) * 1024 + h * 64 + kc);
        }
        __syncthreads();
        float c_r[4];
#pragma unroll
        for (int r = 0; r < 4; ++r)
            c_r[r] = cvec[((size_t)(n * 16 + h)) * 4096 + (l0 + wr + lq * 4 + r)];
        const bf16x8 a0 = *(const bf16x8*)&qs[wr + lc][lq * 8];
        const bf16x8 a1 = *(const bf16x8*)&qs[wr + lc][32 + lq * 8];
#pragma unroll
        for (int sj = 0; sj < 4; ++sj) {
            const f32x4 fz = {0.f, 0.f, 0.f, 0.f};
            f32x4 acc = fz;
            const bf16x8 b0 = *(const bf16x8*)&ks[sj * 16 + lc][lq * 8];
            const bf16x8 b1 = *(const bf16x8*)&ks[sj * 16 + lc][32 + lq * 8];
            acc = mfma16(a0, b0, acc);
            acc = mfma16(a1, b1, acc);
#pragma unroll
            for (int r = 0; r < 4; ++r) {
                const float ww = __expf(acc[r]) * c_r[r];   // w in (0,1)
                const float w2 = ww * ww;
                sig[sj][r] += 0.5f + ww * (0.25f - w2 * (1.f / 48.f - w2 * (1.f / 480.f)));
            }
        }
    }
    // row-major store: each row's 256B s-slice in 4 consecutive stores
#pragma unroll
    for (int r = 0; r < 4; ++r) {
        const int l = l0 + wr + lq * 4 + r;
        const size_t base = ((size_t)n * 4096 + l) * 1024 + st * 64 + lc;
#pragma unroll
        for (int sj = 0; sj < 4; ++sj)
            amap[base + sj * 16] = sig[sj][r] * (1.f / 16.f);
    }
}

// ---------------------------------------------------------------------------
// y = LN(base + add) * g + b; base is f32 (basef) or bf16 (baseb).
__global__ __launch_bounds__(256) void ln_k(
    const float* __restrict__ basef, const __bf16* __restrict__ baseb,
    const __bf16* __restrict__ add,
    const float* __restrict__ g, const float* __restrict__ bb,
    float* __restrict__ out_f32, __bf16* __restrict__ out_bf)
{
    __shared__ float red[8];
    const int row = blockIdx.x, tid = threadIdx.x;
    const int col = tid * 4;
    const size_t off = (size_t)row * 1024 + col;
    float v[4];
    if (basef) {
        float4 t = *(const float4*)(basef + off);
        v[0] = t.x; v[1] = t.y; v[2] = t.z; v[3] = t.w;
    } else {
        union { uint2 u; __bf16 h[4]; } tb;
        tb.u = *(const uint2*)(baseb + off);
#pragma unroll
        for (int j = 0; j < 4; ++j) v[j] = (float)tb.h[j];
    }
    {
        union { uint2 u; __bf16 h[4]; } ub;
        ub.u = *(const uint2*)(add + off);
#pragma unroll
        for (int j = 0; j < 4; ++j) v[j] += (float)ub.h[j];
    }
    float s = v[0] + v[1] + v[2] + v[3];
    float q = v[0] * v[0] + v[1] * v[1] + v[2] * v[2] + v[3] * v[3];
#pragma unroll
    for (int m = 1; m < 64; m <<= 1) { s += __shfl_xor(s, m); q += __shfl_xor(q, m); }
    const int wave = tid >> 6, lane = tid & 63;
    if (lane == 0) { red[wave] = s; red[4 + wave] = q; }
    __syncthreads();
    s = red[0] + red[1] + red[2] + red[3];
    q = red[4] + red[5] + red[6] + red[7];
    const float mu = s * (1.f / 1024.f);
    const float var = q * (1.f / 1024.f) - mu * mu;
    const float rs = rsqrtf(var + 1e-5f);
    const float4 gv = *(const float4*)(g + col);
    const float4 bv = *(const float4*)(bb + col);
    float y[4];
    y[0] = (v[0] - mu) * rs * gv.x + bv.x;
    y[1] = (v[1] - mu) * rs * gv.y + bv.y;
    y[2] = (v[2] - mu) * rs * gv.z + bv.z;
    y[3] = (v[3] - mu) * rs * gv.w + bv.w;
    if (out_f32) {
        float4 o; o.x = y[0]; o.y = y[1]; o.z = y[2]; o.w = y[3];
        *(float4*)(out_f32 + off) = o;
    }
    if (out_bf) {
        union { uint2 u; __bf16 h[4]; } ob;
#pragma unroll
        for (int j = 0; j < 4; ++j) ob.h[j] = (__bf16)y[j];
        *(uint2*)(out_bf + off) = ob.u;
    }
}

// ---------------------------------------------------------------------------
extern "C" void kernel_launch(void* const* d_in, const int* in_sizes, int n_in,
                              void* d_out, int out_size, void* d_ws, size_t ws_size,
                              hipStream_t stream) {
    const float* key_in    = (const float*)d_in[0];
    const float* value_in  = (const float*)d_in[1];
    const float* query     = (const float*)d_in[2];
    const float* in_proj_w = (const float*)d_in[3];
    const float* in_proj_b = (const float*)d_in[4];
    const float* out_w     = (const float*)d_in[5];
    const float* out_b     = (const float*)d_in[6];
    const float* ln1_g     = (const float*)d_in[7];
    const float* ln1_b     = (const float*)d_in[8];
    const float* ln2_g     = (const float*)d_in[9];
    const float* ln2_b     = (const float*)d_in[10];
    const float* ff1_w     = (const float*)d_in[11];
    const float* ff1_b     = (const float*)d_in[12];
    const float* ff2_w     = (const float*)d_in[13];
    const float* ff2_b     = (const float*)d_in[14];
    float* outp = (float*)d_out;

    __bf16* ws = (__bf16*)d_ws;
    const size_t M1 = 1048576;
    __bf16* WQKV = ws;               // 6 M1 (both layers)
    __bf16* WOUT = ws + 6 * M1;      // 2
    __bf16* WF1  = ws + 8 * M1;      // 8
    __bf16* WF2  = ws + 16 * M1;     // 8
    __bf16* KIN  = ws + 24 * M1;     // 2
    __bf16* VIN  = ws + 26 * M1;     // 2
    __bf16* TGT  = ws + 28 * M1;     // 8
    __bf16* PROJ = ws + 36 * M1;     // 8 (q-proj out; out-proj out)
    __bf16* KB   = ws + 44 * M1;     // 2
    __bf16* VB   = ws + 46 * M1;     // 2
    __bf16* VT   = ws + 48 * M1;     // 2
    __bf16* AOUT = ws + 50 * M1;     // 8 (attn out; ff2 out)
    __bf16* XB   = ws + 58 * M1;     // 8 (ln1 out, bf16)
    __bf16* H1   = ws + 66 * M1;     // 32
    float*  CVEC = (float*)(ws + 98 * M1);   // 131072 f32

    // upfront casts: inputs + ALL weights (both layers)
    cast_k<<<8192, 256, 0, stream>>>(query, TGT, 2097152);
    cast_k<<<2048, 256, 0, stream>>>(key_in, KIN, 524288);
    cast_k<<<2048, 256, 0, stream>>>(value_in, VIN, 524288);
    cast_k<<<6144, 256, 0, stream>>>(in_proj_w, WQKV, 1572864);
    cast_k<<<2048, 256, 0, stream>>>(out_w, WOUT, 524288);
    cast_k<<<8192, 256, 0, stream>>>(ff1_w, WF1, 2097152);
    cast_k<<<8192, 256, 0, stream>>>(ff2_w, WF2, 2097152);

    for (int i = 0; i < 2; ++i) {
        __bf16* WQKVi = WQKV + (size_t)i * 3 * M1;
        __bf16* WOUTi = WOUT + (size_t)i * M1;
        __bf16* WF1i  = WF1 + (size_t)i * 4 * M1;
        __bf16* WF2i  = WF2 + (size_t)i * 4 * M1;

        // fused q/k/v projections (one dispatch, 1536 blocks)
        gemm_qkv<<<1536, 256, 0, stream>>>(TGT, KIN, VIN, WQKVi,
                                           in_proj_b + i * 3072, PROJ, KB, VB);
        transpose_v<<<dim3(16, 16, 2), 256, 0, stream>>>(VB, VT);

        attn_fused<<<dim3(64, 16, 2), 256, 0, stream>>>(PROJ, KB, VT, CVEC, AOUT);
        if (i == 1)
            attn_map_k<<<dim3(64, 16, 2), 256, 0, stream>>>(PROJ, KB, CVEC,
                                                            outp + 8388608);

        // out projection: pipelined 256x128 (256 blocks = 1 CU round)
        gemm8pN<<<256, 512, 0, stream>>>(AOUT, WOUTi, out_b + i * 1024,
                                         PROJ, 1024, 1024, 1.f, 0);
        // LN1: base = query (f32, layer 0) or TGT (bf16)
        ln_k<<<8192, 256, 0, stream>>>(i == 0 ? query : nullptr,
                                       i == 0 ? nullptr : TGT,
                                       PROJ, ln1_g + i * 1024, ln1_b + i * 1024,
                                       nullptr, XB);
        // FFN: ff1 via 8-phase 256x256 pipeline (512 blocks = 2 CU rounds),
        // ff2 via 256x128 pipeline (256 blocks, K=4096 deep pipeline)
        gemm8p<<<512, 512, 0, stream>>>(XB, WF1i, ff1_b + i * 4096,
                                        H1, 4096, 1024, 1.f, 1);
        gemm8pN<<<256, 512, 0, stream>>>(H1, WF2i, ff2_b + i * 1024,
                                         AOUT, 1024, 4096, 1.f, 0);
        // LN2: base = XB (bf16); final layer also writes f32 tgt to d_out
        ln_k<<<8192, 256, 0, stream>>>(nullptr, XB, AOUT,
                                       ln2_g + i * 1024, ln2_b + i * 1024,
                                       i == 1 ? outp : nullptr, TGT);
    }
}

// Round 8
// 884.801 us; speedup vs baseline: 1.3868x; 1.0070x over previous
//
#include <hip/hip_runtime.h>
#include <hip/hip_bf16.h>

// ---------------------------------------------------------------------------
// PadTransformer R11: R10 + gemm8pN wave-grid 2Mx4N -> 4Mx2N (64x64/wave).
// Old layout made all 4 column-waves read the whole 256-row A tile from LDS
// (20 b128/wave/tile, 164KB/CU-tile; LDS-BW-bound at ~79% of its ceiling).
// New: per-wave 64 rows x 64 cols -> 16 b128/wave/tile, 128KB/CU-tile (-22%).
// Per-element K order unchanged (kk0 then kk1) -> bitwise identical output.
// All reads stay in phase 0 (2-parity slot safety preserved).
// ---------------------------------------------------------------------------

typedef __bf16 bf16x8 __attribute__((ext_vector_type(8)));
typedef float  f32x4  __attribute__((ext_vector_type(4)));

__device__ __forceinline__ f32x4 mfma16(bf16x8 a, bf16x8 b, f32x4 c) {
    return __builtin_amdgcn_mfma_f32_16x16x32_bf16(a, b, c, 0, 0, 0);
}

__device__ __forceinline__ void load_lds16(const __bf16* g, __bf16* l) {
    __builtin_amdgcn_global_load_lds(
        (const __attribute__((address_space(1))) void*)g,
        (__attribute__((address_space(3))) void*)l, 16, 0, 0);
}

// bijective XCD swizzle; valid when nwg % 8 == 0 (true for every launch here)
__device__ __forceinline__ int swz8(int o, int nwg) {
    return (o & 7) * (nwg >> 3) + (o >> 3);
}

// ---------------------------------------------------------------------------
__global__ __launch_bounds__(256) void cast_k(const float* __restrict__ in,
                                              __bf16* __restrict__ out, int n4) {
    int i = blockIdx.x * 256 + threadIdx.x;
    if (i >= n4) return;
    float4 f = ((const float4*)in)[i];
    union { uint2 u; __bf16 h[4]; } ob;
    ob.h[0] = (__bf16)f.x; ob.h[1] = (__bf16)f.y;
    ob.h[2] = (__bf16)f.z; ob.h[3] = (__bf16)f.w;
    ((uint2*)out)[i] = ob.u;
}

// ---------------------------------------------------------------------------
// 8-phase pipelined 256x256 GEMM (ff1). C = A[M][K] * B[N][K]^T + bias.
__global__ __launch_bounds__(512, 2) void gemm8p(
    const __bf16* __restrict__ A, const __bf16* __restrict__ B,
    const float* __restrict__ bias, __bf16* __restrict__ C,
    int N, int K, float scale, int relu)
{
    // 8 half-tile slots: [parity*4 + {0:A-top,1:A-bot,2:B-left,3:B-right}]
    __shared__ __bf16 L[8][8192];      // 128 KiB
    const int tid = threadIdx.x;
    const int wid = tid >> 6, lane = tid & 63;
    const int lq = lane >> 4, lc = lane & 15;
    const int wm = wid >> 2;           // row half (0/1): rows [wm*128, +128)
    const int wn = (wid & 3) * 64;     // col base: 0,64,128,192
    const int bh = wn >> 7;            // B half id
    const int lb = wn & 127;           // local col within B half (0 or 64)
    const int sw = lc & 7;
    const int w = swz8(blockIdx.x, gridDim.x);
    const int nt = N >> 8;             // column panels (fastest within XCD run)
    const int bm = (w / nt) * 256, bn = (w % nt) * 256;
    const int NT = K >> 6;

    auto stageA = [&](int kt, int h) {
#pragma unroll
        for (int p = 0; p < 2; ++p) {
            const int cc = p * 512 + tid;
            const int row = cc >> 3, gk = ((cc & 7) ^ (row & 7)) * 8;
            load_lds16(A + (size_t)(bm + h * 128 + row) * K + (kt * 64 + gk),
                       &L[(kt & 1) * 4 + h][(size_t)cc * 8]);
        }
    };
    auto stageB = [&](int kt, int h) {
#pragma unroll
        for (int p = 0; p < 2; ++p) {
            const int cc = p * 512 + tid;
            const int row = cc >> 3, gk = ((cc & 7) ^ (row & 7)) * 8;
            load_lds16(B + (size_t)(bn + h * 128 + row) * K + (kt * 64 + gk),
                       &L[(kt & 1) * 4 + 2 + h][(size_t)cc * 8]);
        }
    };

    // prologue: stage K-tiles 0 and 1 (16 loads); wait tile 0 landed (8 left)
    stageA(0, 0); stageA(0, 1); stageB(0, 0); stageB(0, 1);
    stageA(1, 0); stageA(1, 1); stageB(1, 0); stageB(1, 1);
    asm volatile("s_waitcnt vmcnt(8)" ::: "memory");
    __builtin_amdgcn_s_barrier();
    __builtin_amdgcn_sched_barrier(0);

    const f32x4 fz = {0.f, 0.f, 0.f, 0.f};
    f32x4 acc[2][4][4];                 // [rowhalf][i][ch*2+j]
#pragma unroll
    for (int rh = 0; rh < 2; ++rh)
#pragma unroll
        for (int i = 0; i < 4; ++i)
#pragma unroll
            for (int jj = 0; jj < 4; ++jj) acc[rh][i][jj] = fz;

    for (int t = 0; t < NT; ++t) {
        const __bf16* __restrict__ Ah = &L[(t & 1) * 4 + wm][0];
        const __bf16* __restrict__ Bh = &L[(t & 1) * 4 + 2 + bh][0];
        const int pf = (t + 2 < NT);
        bf16x8 a[2][4], b0[2][2], b1[2][2];

        // ---- phase 0: read A rows 0-63 + B cols lb+0..31; MFMA quad (0,0)
#pragma unroll
        for (int kk = 0; kk < 2; ++kk) {
            const int sl = ((kk * 4 + lq) ^ sw) * 8;
#pragma unroll
            for (int i = 0; i < 4; ++i)
                a[kk][i] = *(const bf16x8*)&Ah[(i * 16 + lc) * 64 + sl];
#pragma unroll
            for (int j = 0; j < 2; ++j)
                b0[kk][j] = *(const bf16x8*)&Bh[(lb + j * 16 + lc) * 64 + sl];
        }
        __builtin_amdgcn_s_barrier();
        asm volatile("s_waitcnt lgkmcnt(0)" ::: "memory");
        __builtin_amdgcn_sched_barrier(0);
        __builtin_amdgcn_s_setprio(1);
#pragma unroll
        for (int kk = 0; kk < 2; ++kk)
#pragma unroll
            for (int i = 0; i < 4; ++i)
#pragma unroll
                for (int j = 0; j < 2; ++j)
                    acc[0][i][j] = mfma16(a[kk][i], b0[kk][j], acc[0][i][j]);
        __builtin_amdgcn_s_setprio(0);
        __builtin_amdgcn_s_barrier();
        __builtin_amdgcn_sched_barrier(0);

        // ---- phase 1: read B cols lb+32..63; MFMA quad (0,1)
#pragma unroll
        for (int kk = 0; kk < 2; ++kk) {
            const int sl = ((kk * 4 + lq) ^ sw) * 8;
#pragma unroll
            for (int j = 0; j < 2; ++j)
                b1[kk][j] = *(const bf16x8*)&Bh[(lb + 32 + j * 16 + lc) * 64 + sl];
        }
        __builtin_amdgcn_s_barrier();
        asm volatile("s_waitcnt lgkmcnt(0)" ::: "memory");
        __builtin_amdgcn_sched_barrier(0);
        __builtin_amdgcn_s_setprio(1);
#pragma unroll
        for (int kk = 0; kk < 2; ++kk)
#pragma unroll
            for (int i = 0; i < 4; ++i)
#pragma unroll
                for (int j = 0; j < 2; ++j)
                    acc[0][i][2 + j] = mfma16(a[kk][i], b1[kk][j], acc[0][i][2 + j]);
        __builtin_amdgcn_s_setprio(0);
        __builtin_amdgcn_s_barrier();
        __builtin_amdgcn_sched_barrier(0);

        // ---- phase 2: read A rows 64-127; stage B(t+2); MFMA quad (1,0)
#pragma unroll
        for (int kk = 0; kk < 2; ++kk) {
            const int sl = ((kk * 4 + lq) ^ sw) * 8;
#pragma unroll
            for (int i = 0; i < 4; ++i)
                a[kk][i] = *(const bf16x8*)&Ah[(64 + i * 16 + lc) * 64 + sl];
        }
        if (pf) { stageB(t + 2, 0); stageB(t + 2, 1); }
        __builtin_amdgcn_s_barrier();
        asm volatile("s_waitcnt lgkmcnt(0)" ::: "memory");
        __builtin_amdgcn_sched_barrier(0);
        __builtin_amdgcn_s_setprio(1);
#pragma unroll
        for (int kk = 0; kk < 2; ++kk)
#pragma unroll
            for (int i = 0; i < 4; ++i)
#pragma unroll
                for (int j = 0; j < 2; ++j)
                    acc[1][i][j] = mfma16(a[kk][i], b0[kk][j], acc[1][i][j]);
        __builtin_amdgcn_s_setprio(0);
        __builtin_amdgcn_s_barrier();
        __builtin_amdgcn_sched_barrier(0);

        // ---- phase 3: stage A(t+2); MFMA quad (1,1); per-tile vmcnt
        if (pf) { stageA(t + 2, 0); stageA(t + 2, 1); }
        __builtin_amdgcn_s_barrier();
        __builtin_amdgcn_sched_barrier(0);
        __builtin_amdgcn_s_setprio(1);
#pragma unroll
        for (int kk = 0; kk < 2; ++kk)
#pragma unroll
            for (int i = 0; i < 4; ++i)
#pragma unroll
                for (int j = 0; j < 2; ++j)
                    acc[1][i][2 + j] = mfma16(a[kk][i], b1[kk][j], acc[1][i][2 + j]);
        __builtin_amdgcn_s_setprio(0);
        if (pf) asm volatile("s_waitcnt vmcnt(8)" ::: "memory");
        else    asm volatile("s_waitcnt vmcnt(0)" ::: "memory");
        __builtin_amdgcn_s_barrier();
        __builtin_amdgcn_sched_barrier(0);
    }

    // epilogue: ROW-MAJOR order (R8): full 128B line per row, consecutive.
    float bv[4];
#pragma unroll
    for (int q = 0; q < 4; ++q) bv[q] = bias[bn + wn + q * 16 + lc];
#pragma unroll
    for (int rh = 0; rh < 2; ++rh)
#pragma unroll
        for (int i = 0; i < 4; ++i)
#pragma unroll
            for (int r = 0; r < 4; ++r) {
                const int row = bm + wm * 128 + rh * 64 + i * 16 + lq * 4 + r;
                const size_t base = (size_t)row * N + bn + wn + lc;
#pragma unroll
                for (int ch = 0; ch < 2; ++ch)
#pragma unroll
                    for (int j = 0; j < 2; ++j) {
                        float v = (acc[rh][i][ch * 2 + j][r] + bv[ch * 2 + j]) * scale;
                        if (relu) v = fmaxf(v, 0.f);
                        C[base + ch * 32 + j * 16] = (__bf16)v;
                    }
            }
}

// ---------------------------------------------------------------------------
// Pipelined 256x128 GEMM (ff2 / out-proj, N=1024 -> 256 blocks).
// 8 waves as 4Mx2N: per-wave 64x64 output (4x4 16x16 frags), 16 b128
// reads/wave/tile (was 20 with 2Mx4N). LDS 6 slots x 16 KiB, 2-parity.
// Phase 0: all 16 ds_reads -> barrier -> lgkm0 -> 16 MFMA (kk=0).
// Phase 1: stage t+2 -> 16 MFMA (kk=1) -> vmcnt(6) -> barrier.
__global__ __launch_bounds__(512, 2) void gemm8pN(
    const __bf16* __restrict__ A, const __bf16* __restrict__ B,
    const float* __restrict__ bias, __bf16* __restrict__ C,
    int N, int K, float scale, int relu)
{
    __shared__ __bf16 L[6][8192];      // 96 KiB: [par*3 + {0:A-top,1:A-bot,2:B}]
    const int tid = threadIdx.x;
    const int wid = tid >> 6, lane = tid & 63;
    const int lq = lane >> 4, lc = lane & 15;
    const int wr = (wid >> 1) * 64;    // wave row base: 0,64,128,192
    const int wc = (wid & 1) * 64;     // wave col base: 0 or 64
    const int ha = wr >> 7;            // A half slot (0/1)
    const int lr = wr & 127;           // row offset within half (0 or 64)
    const int sw = lc & 7;
    const int w = swz8(blockIdx.x, gridDim.x);
    const int nt = N >> 7;             // column panels (fastest within XCD run)
    const int bm = (w / nt) * 256, bn = (w % nt) * 128;
    const int NT = K >> 6;

    auto stageA = [&](int kt, int h) {
#pragma unroll
        for (int p = 0; p < 2; ++p) {
            const int cc = p * 512 + tid;
            const int row = cc >> 3, gk = ((cc & 7) ^ (row & 7)) * 8;
            load_lds16(A + (size_t)(bm + h * 128 + row) * K + (kt * 64 + gk),
                       &L[(kt & 1) * 3 + h][(size_t)cc * 8]);
        }
    };
    auto stageB = [&](int kt) {
#pragma unroll
        for (int p = 0; p < 2; ++p) {
            const int cc = p * 512 + tid;
            const int row = cc >> 3, gk = ((cc & 7) ^ (row & 7)) * 8;
            load_lds16(B + (size_t)(bn + row) * K + (kt * 64 + gk),
                       &L[(kt & 1) * 3 + 2][(size_t)cc * 8]);
        }
    };

    // prologue: stage K-tiles 0 and 1 (12 loads); wait tile 0 landed (6 left)
    stageA(0, 0); stageA(0, 1); stageB(0);
    stageA(1, 0); stageA(1, 1); stageB(1);
    asm volatile("s_waitcnt vmcnt(6)" ::: "memory");
    __builtin_amdgcn_s_barrier();
    __builtin_amdgcn_sched_barrier(0);

    const f32x4 fz = {0.f, 0.f, 0.f, 0.f};
    f32x4 acc[4][4];                    // [i rows][j cols]
#pragma unroll
    for (int i = 0; i < 4; ++i)
#pragma unroll
        for (int j = 0; j < 4; ++j) acc[i][j] = fz;

    for (int t = 0; t < NT; ++t) {
        const __bf16* __restrict__ Ah = &L[(t & 1) * 3 + ha][0];
        const __bf16* __restrict__ Bb = &L[(t & 1) * 3 + 2][0];
        const int pf = (t + 2 < NT);
        bf16x8 a[2][4], b[2][4];

        // ---- phase 0: read ALL tile-t fragments (16 b128); MFMA kk=0
#pragma unroll
        for (int kk = 0; kk < 2; ++kk) {
            const int sl = ((kk * 4 + lq) ^ sw) * 8;
#pragma unroll
            for (int i = 0; i < 4; ++i)
                a[kk][i] = *(const bf16x8*)&Ah[(lr + i * 16 + lc) * 64 + sl];
#pragma unroll
            for (int j = 0; j < 4; ++j)
                b[kk][j] = *(const bf16x8*)&Bb[(wc + j * 16 + lc) * 64 + sl];
        }
        __builtin_amdgcn_s_barrier();
        asm volatile("s_waitcnt lgkmcnt(0)" ::: "memory");
        __builtin_amdgcn_sched_barrier(0);
        __builtin_amdgcn_s_setprio(1);
#pragma unroll
        for (int i = 0; i < 4; ++i)
#pragma unroll
            for (int j = 0; j < 4; ++j)
                acc[i][j] = mfma16(a[0][i], b[0][j], acc[i][j]);
        __builtin_amdgcn_s_setprio(0);
        __builtin_amdgcn_s_barrier();
        __builtin_amdgcn_sched_barrier(0);

        // ---- phase 1: stage tile t+2 (all reads of parity done); MFMA kk=1
        if (pf) { stageB(t + 2); stageA(t + 2, 0); stageA(t + 2, 1); }
        __builtin_amdgcn_s_setprio(1);
#pragma unroll
        for (int i = 0; i < 4; ++i)
#pragma unroll
            for (int j = 0; j < 4; ++j)
                acc[i][j] = mfma16(a[1][i], b[1][j], acc[i][j]);
        __builtin_amdgcn_s_setprio(0);
        if (pf) asm volatile("s_waitcnt vmcnt(6)" ::: "memory");
        else    asm volatile("s_waitcnt vmcnt(0)" ::: "memory");
        __builtin_amdgcn_s_barrier();
        __builtin_amdgcn_sched_barrier(0);
    }

    // epilogue: row-major, full 128B line (4 x 16-col chunks) per row
    float bv[4];
#pragma unroll
    for (int q = 0; q < 4; ++q) bv[q] = bias[bn + wc + q * 16 + lc];
#pragma unroll
    for (int i = 0; i < 4; ++i)
#pragma unroll
        for (int r = 0; r < 4; ++r) {
            const int row = bm + wr + i * 16 + lq * 4 + r;
            const size_t base = (size_t)row * N + bn + wc + lc;
#pragma unroll
            for (int j = 0; j < 4; ++j) {
                float v = (acc[i][j][r] + bv[j]) * scale;
                if (relu) v = fmaxf(v, 0.f);
                C[base + j * 16] = (__bf16)v;
            }
        }
}

// ---------------------------------------------------------------------------
// Legacy 2-phase core (qkv): C[128 x BN] tile, BK=64, R3 swizzle.
template <int BN>
__device__ __forceinline__ void gemm_core(
    const __bf16* __restrict__ A, const __bf16* __restrict__ B,
    const float* __restrict__ bias, __bf16* __restrict__ C,
    int M, int N, int K, float scale, int relu, int bm, int bn,
    __bf16* As, __bf16* Bs)
{
    const int tid = threadIdx.x;
    const int wave = tid >> 6, lane = tid & 63;
    const int lq = lane >> 4, lc = lane & 15;
    const int WN = BN / 2;
    const int JT = WN / 16;
    const int wm = (wave >> 1) * 64, wn = (wave & 1) * WN;

    const f32x4 fz = {0.f, 0.f, 0.f, 0.f};
    f32x4 acc[4][4];
#pragma unroll
    for (int i = 0; i < 4; ++i)
#pragma unroll
        for (int j = 0; j < JT; ++j) acc[i][j] = fz;

    const int sw = lc & 7;

    for (int k0 = 0; k0 < K; k0 += 64) {
        __syncthreads();
#pragma unroll
        for (int i = 0; i < 4; ++i) {
            const int c = tid + 256 * i;
            const int row = c >> 3, gk = ((c & 7) ^ (row & 7)) * 8;
            load_lds16(A + (size_t)(bm + row) * K + (k0 + gk),
                       As + (size_t)c * 8);
        }
#pragma unroll
        for (int i = 0; i < BN / 32; ++i) {
            const int c = tid + 256 * i;
            const int row = c >> 3, gk = ((c & 7) ^ (row & 7)) * 8;
            load_lds16(B + (size_t)(bn + row) * K + (k0 + gk),
                       Bs + (size_t)c * 8);
        }
        __syncthreads();
#pragma unroll
        for (int kk = 0; kk < 2; ++kk) {
            bf16x8 af[4], bw[4];
            const int slot = ((kk * 4 + lq) ^ sw) * 8;
#pragma unroll
            for (int i = 0; i < 4; ++i)
                af[i] = *(const bf16x8*)&As[(wm + i * 16 + lc) * 64 + slot];
#pragma unroll
            for (int j = 0; j < JT; ++j)
                bw[j] = *(const bf16x8*)&Bs[(wn + j * 16 + lc) * 64 + slot];
#pragma unroll
            for (int i = 0; i < 4; ++i)
#pragma unroll
                for (int j = 0; j < JT; ++j)
                    acc[i][j] = mfma16(af[i], bw[j], acc[i][j]);
        }
    }

#pragma unroll
    for (int j = 0; j < JT; ++j) {
        const int col = bn + wn + j * 16 + lc;
        const float bv = bias[col];
#pragma unroll
        for (int i = 0; i < 4; ++i) {
#pragma unroll
            for (int r = 0; r < 4; ++r) {
                float v = (acc[i][j][r] + bv) * scale;
                if (relu) v = fmaxf(v, 0.f);
                const int row = bm + wm + i * 16 + lq * 4 + r;
                C[(size_t)row * N + col] = (__bf16)v;
            }
        }
    }
}

// Fused q/k/v projection: flat grid 1536 blocks, BN=64.
__global__ __launch_bounds__(256) void gemm_qkv(
    const __bf16* __restrict__ TGT, const __bf16* __restrict__ KIN,
    const __bf16* __restrict__ VIN, const __bf16* __restrict__ W,
    const float* __restrict__ bias, __bf16* __restrict__ PROJ,
    __bf16* __restrict__ KB, __bf16* __restrict__ VB)
{
    __shared__ __bf16 As[128 * 64];
    __shared__ __bf16 Bs[64 * 64];
    const int bid = swz8(blockIdx.x, 1536);   // XCD-contiguous tile runs
    const __bf16* A; __bf16* Cout; int M, t, seg; float scale;
    if (bid < 1024)      { seg = 0; t = bid;        A = TGT; Cout = PROJ; M = 8192; scale = 0.125f; }
    else if (bid < 1280) { seg = 1; t = bid - 1024; A = KIN; Cout = KB;   M = 2048; scale = 1.f; }
    else                 { seg = 2; t = bid - 1280; A = VIN; Cout = VB;   M = 2048; scale = 1.f; }
    gemm_core<64>(A, W + (size_t)seg * 1048576, bias + seg * 1024, Cout,
                  M, 1024, 1024, scale, 0, (t >> 4) * 128, (t & 15) * 64, As, Bs);
}

// ---------------------------------------------------------------------------
// transpose V per (n,h): vt[(n*16+h)*64 + d][s] = v[(s*2+n)*1024 + h*64 + d]
__global__ __launch_bounds__(256) void transpose_v(const __bf16* __restrict__ v,
                                                   __bf16* __restrict__ vt) {
    __shared__ __bf16 t[64][72];
    const int tid = threadIdx.x;
    const int s0 = blockIdx.x * 64, h = blockIdx.y, n = blockIdx.z;
#pragma unroll
    for (int i = 0; i < 2; ++i) {
        const int cc = tid + 256 * i, row = cc >> 3, kc = (cc & 7) * 8;
        *(uint4*)&t[row][kc] =
            *(const uint4*)(v + ((size_t)((s0 + row) * 2 + n)) * 1024 + h * 64 + kc);
    }
    __syncthreads();
#pragma unroll
    for (int i = 0; i < 2; ++i) {
        const int cc = tid + 256 * i, d = cc >> 3, jc = (cc & 7) * 8;
        __attribute__((aligned(16))) __bf16 tmp[8];
#pragma unroll
        for (int u = 0; u < 8; ++u) tmp[u] = t[jc + u][d];
        *(uint4*)(vt + ((size_t)((n * 16 + h) * 64 + d)) * 1024 + s0 + jc) = *(uint4*)tmp;
    }
}

// ---------------------------------------------------------------------------
// Fused attention (R2 design): O = (sum e^s v) / (1 + sum e^s); cvec saved.
__global__ __launch_bounds__(256) void attn_fused(
    const __bf16* __restrict__ q, const __bf16* __restrict__ kk,
    const __bf16* __restrict__ vt, float* __restrict__ cvec,
    __bf16* __restrict__ aout)
{
    __shared__ __bf16 qs[64][72];
    __shared__ __bf16 ks[64][72];
    __shared__ __bf16 vs[64][72];
    __shared__ __bf16 es[64][72];
    const int tid = threadIdx.x, wave = tid >> 6, lane = tid & 63;
    const int lq = lane >> 4, lc = lane & 15;
    const int o = (blockIdx.z * 16 + blockIdx.y) * 64 + blockIdx.x;
    const int w = swz8(o, 2048);
    const int l0 = (w & 63) * 64, h = (w >> 6) & 15, n = w >> 10;
    const int wr = wave * 16;
#pragma unroll
    for (int i = 0; i < 2; ++i) {
        const int cc = tid + 256 * i, row = cc >> 3, kc = (cc & 7) * 8;
        *(uint4*)&qs[row][kc] =
            *(const uint4*)(q + ((size_t)((l0 + row) * 2 + n)) * 1024 + h * 64 + kc);
    }
    const f32x4 fz = {0.f, 0.f, 0.f, 0.f};
    f32x4 oacc[4];
#pragma unroll
    for (int dj = 0; dj < 4; ++dj) oacc[dj] = fz;
    float den[4] = {0.f, 0.f, 0.f, 0.f};

    for (int st = 0; st < 16; ++st) {
        __syncthreads();
#pragma unroll
        for (int i = 0; i < 2; ++i) {
            const int cc = tid + 256 * i, row = cc >> 3, kc = (cc & 7) * 8;
            *(uint4*)&ks[row][kc] =
                *(const uint4*)(kk + ((size_t)((st * 64 + row) * 2 + n)) * 1024 + h * 64 + kc);
            *(uint4*)&vs[row][kc] =
                *(const uint4*)(vt + ((size_t)((n * 16 + h) * 64 + row)) * 1024 + st * 64 + kc);
        }
        __syncthreads();
        const bf16x8 a0 = *(const bf16x8*)&qs[wr + lc][lq * 8];
        const bf16x8 a1 = *(const bf16x8*)&qs[wr + lc][32 + lq * 8];
#pragma unroll
        for (int sj = 0; sj < 4; ++sj) {
            f32x4 acc = fz;
            const bf16x8 b0 = *(const bf16x8*)&ks[sj * 16 + lc][lq * 8];
            const bf16x8 b1 = *(const bf16x8*)&ks[sj * 16 + lc][32 + lq * 8];
            acc = mfma16(a0, b0, acc);
            acc = mfma16(a1, b1, acc);
#pragma unroll
            for (int r = 0; r < 4; ++r) {
                const float e = __expf(acc[r]);
                den[r] += e;
                es[wr + lq * 4 + r][sj * 16 + lc] = (__bf16)e;
            }
        }
        const bf16x8 w0 = *(const bf16x8*)&es[wr + lc][lq * 8];
        const bf16x8 w1 = *(const bf16x8*)&es[wr + lc][32 + lq * 8];
#pragma unroll
        for (int dj = 0; dj < 4; ++dj) {
            const bf16x8 v0 = *(const bf16x8*)&vs[dj * 16 + lc][lq * 8];
            const bf16x8 v1 = *(const bf16x8*)&vs[dj * 16 + lc][32 + lq * 8];
            oacc[dj] = mfma16(w0, v0, oacc[dj]);
            oacc[dj] = mfma16(w1, v1, oacc[dj]);
        }
    }
#pragma unroll
    for (int m = 1; m < 16; m <<= 1)
#pragma unroll
        for (int r = 0; r < 4; ++r) den[r] += __shfl_xor(den[r], m);
    float c_r[4];
#pragma unroll
    for (int r = 0; r < 4; ++r) c_r[r] = 1.f / (den[r] + 1.f);
    if (lc == 0) {
#pragma unroll
        for (int r = 0; r < 4; ++r)
            cvec[((size_t)(n * 16 + h)) * 4096 + (l0 + wr + lq * 4 + r)] = c_r[r];
    }
    // row-major store: each row's 128B head-slice in 4 consecutive stores
#pragma unroll
    for (int r = 0; r < 4; ++r) {
        const int l = l0 + wr + lq * 4 + r;
        const size_t base = ((size_t)l * 2 + n) * 1024 + h * 64 + lc;
#pragma unroll
        for (int dj = 0; dj < 4; ++dj)
            aout[base + dj * 16] = (__bf16)(oacc[dj][r] * c_r[r]);
    }
}

// ---------------------------------------------------------------------------
// attn_map[n][l][s] = mean_h sigmoid(w); sigmoid via Taylor poly on (0,1).
__global__ __launch_bounds__(256) void attn_map_k(
    const __bf16* __restrict__ q, const __bf16* __restrict__ kk,
    const float* __restrict__ cvec, float* __restrict__ amap)
{
    __shared__ __bf16 qs[64][72];
    __shared__ __bf16 ks[64][72];
    const int tid = threadIdx.x, wave = tid >> 6, lane = tid & 63;
    const int lq = lane >> 4, lc = lane & 15;
    const int o = (blockIdx.z * 16 + blockIdx.y) * 64 + blockIdx.x;
    const int w = swz8(o, 2048);
    const int l0 = (w & 63) * 64, st = (w >> 6) & 15, n = w >> 10;
    const int wr = wave * 16;
    float sig[4][4];
#pragma unroll
    for (int sj = 0; sj < 4; ++sj)
#pragma unroll
        for (int r = 0; r < 4; ++r) sig[sj][r] = 0.f;

    for (int h = 0; h < 16; ++h) {
        __syncthreads();
#pragma unroll
        for (int i = 0; i < 2; ++i) {
            const int cc = tid + 256 * i, row = cc >> 3, kc = (cc & 7) * 8;
            *(uint4*)&qs[row][kc] =
                *(const uint4*)(q + ((size_t)((l0 + row) * 2 + n)) * 1024 + h * 64 + kc);
            *(uint4*)&ks[row][kc] =
                *(const uint4*)(kk + ((size_t)((st * 64 + row) * 2 + n)) * 1024 + h * 64 + kc);
        }
        __syncthreads();
        float c_r[4];
#pragma unroll
        for (int r = 0; r < 4; ++r)
            c_r[r] = cvec[((size_t)(n * 16 + h)) * 4096 + (l0 + wr + lq * 4 + r)];
        const bf16x8 a0 = *(const bf16x8*)&qs[wr + lc][lq * 8];
        const bf16x8 a1 = *(const bf16x8*)&qs[wr + lc][32 + lq * 8];
#pragma unroll
        for (int sj = 0; sj < 4; ++sj) {
            const f32x4 fz = {0.f, 0.f, 0.f, 0.f};
            f32x4 acc = fz;
            const bf16x8 b0 = *(const bf16x8*)&ks[sj * 16 + lc][lq * 8];
            const bf16x8 b1 = *(const bf16x8*)&ks[sj * 16 + lc][32 + lq * 8];
            acc = mfma16(a0, b0, acc);
            acc = mfma16(a1, b1, acc);
#pragma unroll
            for (int r = 0; r < 4; ++r) {
                const float ww = __expf(acc[r]) * c_r[r];   // w in (0,1)
                const float w2 = ww * ww;
                sig[sj][r] += 0.5f + ww * (0.25f - w2 * (1.f / 48.f - w2 * (1.f / 480.f)));
            }
        }
    }
    // row-major store: each row's 256B s-slice in 4 consecutive stores
#pragma unroll
    for (int r = 0; r < 4; ++r) {
        const int l = l0 + wr + lq * 4 + r;
        const size_t base = ((size_t)n * 4096 + l) * 1024 + st * 64 + lc;
#pragma unroll
        for (int sj = 0; sj < 4; ++sj)
            amap[base + sj * 16] = sig[sj][r] * (1.f / 16.f);
    }
}

// ---------------------------------------------------------------------------
// y = LN(base + add) * g + b; base is f32 (basef) or bf16 (baseb).
__global__ __launch_bounds__(256) void ln_k(
    const float* __restrict__ basef, const __bf16* __restrict__ baseb,
    const __bf16* __restrict__ add,
    const float* __restrict__ g, const float* __restrict__ bb,
    float* __restrict__ out_f32, __bf16* __restrict__ out_bf)
{
    __shared__ float red[8];
    const int row = blockIdx.x, tid = threadIdx.x;
    const int col = tid * 4;
    const size_t off = (size_t)row * 1024 + col;
    float v[4];
    if (basef) {
        float4 t = *(const float4*)(basef + off);
        v[0] = t.x; v[1] = t.y; v[2] = t.z; v[3] = t.w;
    } else {
        union { uint2 u; __bf16 h[4]; } tb;
        tb.u = *(const uint2*)(baseb + off);
#pragma unroll
        for (int j = 0; j < 4; ++j) v[j] = (float)tb.h[j];
    }
    {
        union { uint2 u; __bf16 h[4]; } ub;
        ub.u = *(const uint2*)(add + off);
#pragma unroll
        for (int j = 0; j < 4; ++j) v[j] += (float)ub.h[j];
    }
    float s = v[0] + v[1] + v[2] + v[3];
    float q = v[0] * v[0] + v[1] * v[1] + v[2] * v[2] + v[3] * v[3];
#pragma unroll
    for (int m = 1; m < 64; m <<= 1) { s += __shfl_xor(s, m); q += __shfl_xor(q, m); }
    const int wave = tid >> 6, lane = tid & 63;
    if (lane == 0) { red[wave] = s; red[4 + wave] = q; }
    __syncthreads();
    s = red[0] + red[1] + red[2] + red[3];
    q = red[4] + red[5] + red[6] + red[7];
    const float mu = s * (1.f / 1024.f);
    const float var = q * (1.f / 1024.f) - mu * mu;
    const float rs = rsqrtf(var + 1e-5f);
    const float4 gv = *(const float4*)(g + col);
    const float4 bv = *(const float4*)(bb + col);
    float y[4];
    y[0] = (v[0] - mu) * rs * gv.x + bv.x;
    y[1] = (v[1] - mu) * rs * gv.y + bv.y;
    y[2] = (v[2] - mu) * rs * gv.z + bv.z;
    y[3] = (v[3] - mu) * rs * gv.w + bv.w;
    if (out_f32) {
        float4 o; o.x = y[0]; o.y = y[1]; o.z = y[2]; o.w = y[3];
        *(float4*)(out_f32 + off) = o;
    }
    if (out_bf) {
        union { uint2 u; __bf16 h[4]; } ob;
#pragma unroll
        for (int j = 0; j < 4; ++j) ob.h[j] = (__bf16)y[j];
        *(uint2*)(out_bf + off) = ob.u;
    }
}

// ---------------------------------------------------------------------------
extern "C" void kernel_launch(void* const* d_in, const int* in_sizes, int n_in,
                              void* d_out, int out_size, void* d_ws, size_t ws_size,
                              hipStream_t stream) {
    const float* key_in    = (const float*)d_in[0];
    const float* value_in  = (const float*)d_in[1];
    const float* query     = (const float*)d_in[2];
    const float* in_proj_w = (const float*)d_in[3];
    const float* in_proj_b = (const float*)d_in[4];
    const float* out_w     = (const float*)d_in[5];
    const float* out_b     = (const float*)d_in[6];
    const float* ln1_g     = (const float*)d_in[7];
    const float* ln1_b     = (const float*)d_in[8];
    const float* ln2_g     = (const float*)d_in[9];
    const float* ln2_b     = (const float*)d_in[10];
    const float* ff1_w     = (const float*)d_in[11];
    const float* ff1_b     = (const float*)d_in[12];
    const float* ff2_w     = (const float*)d_in[13];
    const float* ff2_b     = (const float*)d_in[14];
    float* outp = (float*)d_out;

    __bf16* ws = (__bf16*)d_ws;
    const size_t M1 = 1048576;
    __bf16* WQKV = ws;               // 6 M1 (both layers)
    __bf16* WOUT = ws + 6 * M1;      // 2
    __bf16* WF1  = ws + 8 * M1;      // 8
    __bf16* WF2  = ws + 16 * M1;     // 8
    __bf16* KIN  = ws + 24 * M1;     // 2
    __bf16* VIN  = ws + 26 * M1;     // 2
    __bf16* TGT  = ws + 28 * M1;     // 8
    __bf16* PROJ = ws + 36 * M1;     // 8 (q-proj out; out-proj out)
    __bf16* KB   = ws + 44 * M1;     // 2
    __bf16* VB   = ws + 46 * M1;     // 2
    __bf16* VT   = ws + 48 * M1;     // 2
    __bf16* AOUT = ws + 50 * M1;     // 8 (attn out; ff2 out)
    __bf16* XB   = ws + 58 * M1;     // 8 (ln1 out, bf16)
    __bf16* H1   = ws + 66 * M1;     // 32
    float*  CVEC = (float*)(ws + 98 * M1);   // 131072 f32

    // upfront casts: inputs + ALL weights (both layers)
    cast_k<<<8192, 256, 0, stream>>>(query, TGT, 2097152);
    cast_k<<<2048, 256, 0, stream>>>(key_in, KIN, 524288);
    cast_k<<<2048, 256, 0, stream>>>(value_in, VIN, 524288);
    cast_k<<<6144, 256, 0, stream>>>(in_proj_w, WQKV, 1572864);
    cast_k<<<2048, 256, 0, stream>>>(out_w, WOUT, 524288);
    cast_k<<<8192, 256, 0, stream>>>(ff1_w, WF1, 2097152);
    cast_k<<<8192, 256, 0, stream>>>(ff2_w, WF2, 2097152);

    for (int i = 0; i < 2; ++i) {
        __bf16* WQKVi = WQKV + (size_t)i * 3 * M1;
        __bf16* WOUTi = WOUT + (size_t)i * M1;
        __bf16* WF1i  = WF1 + (size_t)i * 4 * M1;
        __bf16* WF2i  = WF2 + (size_t)i * 4 * M1;

        // fused q/k/v projections (one dispatch, 1536 blocks)
        gemm_qkv<<<1536, 256, 0, stream>>>(TGT, KIN, VIN, WQKVi,
                                           in_proj_b + i * 3072, PROJ, KB, VB);
        transpose_v<<<dim3(16, 16, 2), 256, 0, stream>>>(VB, VT);

        attn_fused<<<dim3(64, 16, 2), 256, 0, stream>>>(PROJ, KB, VT, CVEC, AOUT);
        if (i == 1)
            attn_map_k<<<dim3(64, 16, 2), 256, 0, stream>>>(PROJ, KB, CVEC,
                                                            outp + 8388608);

        // out projection: pipelined 256x128 (256 blocks = 1 CU round)
        gemm8pN<<<256, 512, 0, stream>>>(AOUT, WOUTi, out_b + i * 1024,
                                         PROJ, 1024, 1024, 1.f, 0);
        // LN1: base = query (f32, layer 0) or TGT (bf16)
        ln_k<<<8192, 256, 0, stream>>>(i == 0 ? query : nullptr,
                                       i == 0 ? nullptr : TGT,
                                       PROJ, ln1_g + i * 1024, ln1_b + i * 1024,
                                       nullptr, XB);
        // FFN: ff1 via 8-phase 256x256 pipeline (512 blocks = 2 CU rounds),
        // ff2 via 256x128 pipeline (256 blocks, K=4096 deep pipeline)
        gemm8p<<<512, 512, 0, stream>>>(XB, WF1i, ff1_b + i * 4096,
                                        H1, 4096, 1024, 1.f, 1);
        gemm8pN<<<256, 512, 0, stream>>>(H1, WF2i, ff2_b + i * 1024,
                                         AOUT, 1024, 4096, 1.f, 0);
        // LN2: base = XB (bf16); final layer also writes f32 tgt to d_out
        ln_k<<<8192, 256, 0, stream>>>(nullptr, XB, AOUT,
                                       ln2_g + i * 1024, ln2_b + i * 1024,
                                       i == 1 ? outp : nullptr, TGT);
    }
}

// Round 9
// 854.813 us; speedup vs baseline: 1.4354x; 1.0351x over previous
//
#include <hip/hip_runtime.h>
#include <hip/hip_bf16.h>

// ---------------------------------------------------------------------------
// PadTransformer R12: R11 + attention kernels rebuilt on the GEMM staging
// recipe. attn_fused had 1.05e7 LDS bank-conflict cycles/dispatch (~20%),
// traced to scalar es writes in the [64][72] layout (rows 8 apart alias all
// banks; 144B stride), plus loop-invariant Q re-read from LDS each st and
// VALU-heavy reg-roundtrip staging. Now: Q fragments hoisted to registers
// (direct global read), K/V in [64][64] XOR-swizzled LDS staged via
// global_load_lds (zero-conflict gemm pattern), es in [64][64] with
// XOR-swizzled chunk writes/reads. LDS 36.8->24KB (6 blocks/CU).
// Same per-element FP order -> absmax unchanged. GEMMs unchanged from R11.
// ---------------------------------------------------------------------------

typedef __bf16 bf16x8 __attribute__((ext_vector_type(8)));
typedef float  f32x4  __attribute__((ext_vector_type(4)));

__device__ __forceinline__ f32x4 mfma16(bf16x8 a, bf16x8 b, f32x4 c) {
    return __builtin_amdgcn_mfma_f32_16x16x32_bf16(a, b, c, 0, 0, 0);
}

__device__ __forceinline__ void load_lds16(const __bf16* g, __bf16* l) {
    __builtin_amdgcn_global_load_lds(
        (const __attribute__((address_space(1))) void*)g,
        (__attribute__((address_space(3))) void*)l, 16, 0, 0);
}

// bijective XCD swizzle; valid when nwg % 8 == 0 (true for every launch here)
__device__ __forceinline__ int swz8(int o, int nwg) {
    return (o & 7) * (nwg >> 3) + (o >> 3);
}

// ---------------------------------------------------------------------------
__global__ __launch_bounds__(256) void cast_k(const float* __restrict__ in,
                                              __bf16* __restrict__ out, int n4) {
    int i = blockIdx.x * 256 + threadIdx.x;
    if (i >= n4) return;
    float4 f = ((const float4*)in)[i];
    union { uint2 u; __bf16 h[4]; } ob;
    ob.h[0] = (__bf16)f.x; ob.h[1] = (__bf16)f.y;
    ob.h[2] = (__bf16)f.z; ob.h[3] = (__bf16)f.w;
    ((uint2*)out)[i] = ob.u;
}

// ---------------------------------------------------------------------------
// 8-phase pipelined 256x256 GEMM (ff1). C = A[M][K] * B[N][K]^T + bias.
__global__ __launch_bounds__(512, 2) void gemm8p(
    const __bf16* __restrict__ A, const __bf16* __restrict__ B,
    const float* __restrict__ bias, __bf16* __restrict__ C,
    int N, int K, float scale, int relu)
{
    // 8 half-tile slots: [parity*4 + {0:A-top,1:A-bot,2:B-left,3:B-right}]
    __shared__ __bf16 L[8][8192];      // 128 KiB
    const int tid = threadIdx.x;
    const int wid = tid >> 6, lane = tid & 63;
    const int lq = lane >> 4, lc = lane & 15;
    const int wm = wid >> 2;           // row half (0/1): rows [wm*128, +128)
    const int wn = (wid & 3) * 64;     // col base: 0,64,128,192
    const int bh = wn >> 7;            // B half id
    const int lb = wn & 127;           // local col within B half (0 or 64)
    const int sw = lc & 7;
    const int w = swz8(blockIdx.x, gridDim.x);
    const int nt = N >> 8;             // column panels (fastest within XCD run)
    const int bm = (w / nt) * 256, bn = (w % nt) * 256;
    const int NT = K >> 6;

    auto stageA = [&](int kt, int h) {
#pragma unroll
        for (int p = 0; p < 2; ++p) {
            const int cc = p * 512 + tid;
            const int row = cc >> 3, gk = ((cc & 7) ^ (row & 7)) * 8;
            load_lds16(A + (size_t)(bm + h * 128 + row) * K + (kt * 64 + gk),
                       &L[(kt & 1) * 4 + h][(size_t)cc * 8]);
        }
    };
    auto stageB = [&](int kt, int h) {
#pragma unroll
        for (int p = 0; p < 2; ++p) {
            const int cc = p * 512 + tid;
            const int row = cc >> 3, gk = ((cc & 7) ^ (row & 7)) * 8;
            load_lds16(B + (size_t)(bn + h * 128 + row) * K + (kt * 64 + gk),
                       &L[(kt & 1) * 4 + 2 + h][(size_t)cc * 8]);
        }
    };

    // prologue: stage K-tiles 0 and 1 (16 loads); wait tile 0 landed (8 left)
    stageA(0, 0); stageA(0, 1); stageB(0, 0); stageB(0, 1);
    stageA(1, 0); stageA(1, 1); stageB(1, 0); stageB(1, 1);
    asm volatile("s_waitcnt vmcnt(8)" ::: "memory");
    __builtin_amdgcn_s_barrier();
    __builtin_amdgcn_sched_barrier(0);

    const f32x4 fz = {0.f, 0.f, 0.f, 0.f};
    f32x4 acc[2][4][4];                 // [rowhalf][i][ch*2+j]
#pragma unroll
    for (int rh = 0; rh < 2; ++rh)
#pragma unroll
        for (int i = 0; i < 4; ++i)
#pragma unroll
            for (int jj = 0; jj < 4; ++jj) acc[rh][i][jj] = fz;

    for (int t = 0; t < NT; ++t) {
        const __bf16* __restrict__ Ah = &L[(t & 1) * 4 + wm][0];
        const __bf16* __restrict__ Bh = &L[(t & 1) * 4 + 2 + bh][0];
        const int pf = (t + 2 < NT);
        bf16x8 a[2][4], b0[2][2], b1[2][2];

        // ---- phase 0: read A rows 0-63 + B cols lb+0..31; MFMA quad (0,0)
#pragma unroll
        for (int kk = 0; kk < 2; ++kk) {
            const int sl = ((kk * 4 + lq) ^ sw) * 8;
#pragma unroll
            for (int i = 0; i < 4; ++i)
                a[kk][i] = *(const bf16x8*)&Ah[(i * 16 + lc) * 64 + sl];
#pragma unroll
            for (int j = 0; j < 2; ++j)
                b0[kk][j] = *(const bf16x8*)&Bh[(lb + j * 16 + lc) * 64 + sl];
        }
        __builtin_amdgcn_s_barrier();
        asm volatile("s_waitcnt lgkmcnt(0)" ::: "memory");
        __builtin_amdgcn_sched_barrier(0);
        __builtin_amdgcn_s_setprio(1);
#pragma unroll
        for (int kk = 0; kk < 2; ++kk)
#pragma unroll
            for (int i = 0; i < 4; ++i)
#pragma unroll
                for (int j = 0; j < 2; ++j)
                    acc[0][i][j] = mfma16(a[kk][i], b0[kk][j], acc[0][i][j]);
        __builtin_amdgcn_s_setprio(0);
        __builtin_amdgcn_s_barrier();
        __builtin_amdgcn_sched_barrier(0);

        // ---- phase 1: read B cols lb+32..63; MFMA quad (0,1)
#pragma unroll
        for (int kk = 0; kk < 2; ++kk) {
            const int sl = ((kk * 4 + lq) ^ sw) * 8;
#pragma unroll
            for (int j = 0; j < 2; ++j)
                b1[kk][j] = *(const bf16x8*)&Bh[(lb + 32 + j * 16 + lc) * 64 + sl];
        }
        __builtin_amdgcn_s_barrier();
        asm volatile("s_waitcnt lgkmcnt(0)" ::: "memory");
        __builtin_amdgcn_sched_barrier(0);
        __builtin_amdgcn_s_setprio(1);
#pragma unroll
        for (int kk = 0; kk < 2; ++kk)
#pragma unroll
            for (int i = 0; i < 4; ++i)
#pragma unroll
                for (int j = 0; j < 2; ++j)
                    acc[0][i][2 + j] = mfma16(a[kk][i], b1[kk][j], acc[0][i][2 + j]);
        __builtin_amdgcn_s_setprio(0);
        __builtin_amdgcn_s_barrier();
        __builtin_amdgcn_sched_barrier(0);

        // ---- phase 2: read A rows 64-127; stage B(t+2); MFMA quad (1,0)
#pragma unroll
        for (int kk = 0; kk < 2; ++kk) {
            const int sl = ((kk * 4 + lq) ^ sw) * 8;
#pragma unroll
            for (int i = 0; i < 4; ++i)
                a[kk][i] = *(const bf16x8*)&Ah[(64 + i * 16 + lc) * 64 + sl];
        }
        if (pf) { stageB(t + 2, 0); stageB(t + 2, 1); }
        __builtin_amdgcn_s_barrier();
        asm volatile("s_waitcnt lgkmcnt(0)" ::: "memory");
        __builtin_amdgcn_sched_barrier(0);
        __builtin_amdgcn_s_setprio(1);
#pragma unroll
        for (int kk = 0; kk < 2; ++kk)
#pragma unroll
            for (int i = 0; i < 4; ++i)
#pragma unroll
                for (int j = 0; j < 2; ++j)
                    acc[1][i][j] = mfma16(a[kk][i], b0[kk][j], acc[1][i][j]);
        __builtin_amdgcn_s_setprio(0);
        __builtin_amdgcn_s_barrier();
        __builtin_amdgcn_sched_barrier(0);

        // ---- phase 3: stage A(t+2); MFMA quad (1,1); per-tile vmcnt
        if (pf) { stageA(t + 2, 0); stageA(t + 2, 1); }
        __builtin_amdgcn_s_barrier();
        __builtin_amdgcn_sched_barrier(0);
        __builtin_amdgcn_s_setprio(1);
#pragma unroll
        for (int kk = 0; kk < 2; ++kk)
#pragma unroll
            for (int i = 0; i < 4; ++i)
#pragma unroll
                for (int j = 0; j < 2; ++j)
                    acc[1][i][2 + j] = mfma16(a[kk][i], b1[kk][j], acc[1][i][2 + j]);
        __builtin_amdgcn_s_setprio(0);
        if (pf) asm volatile("s_waitcnt vmcnt(8)" ::: "memory");
        else    asm volatile("s_waitcnt vmcnt(0)" ::: "memory");
        __builtin_amdgcn_s_barrier();
        __builtin_amdgcn_sched_barrier(0);
    }

    // epilogue: ROW-MAJOR order (R8): full 128B line per row, consecutive.
    float bv[4];
#pragma unroll
    for (int q = 0; q < 4; ++q) bv[q] = bias[bn + wn + q * 16 + lc];
#pragma unroll
    for (int rh = 0; rh < 2; ++rh)
#pragma unroll
        for (int i = 0; i < 4; ++i)
#pragma unroll
            for (int r = 0; r < 4; ++r) {
                const int row = bm + wm * 128 + rh * 64 + i * 16 + lq * 4 + r;
                const size_t base = (size_t)row * N + bn + wn + lc;
#pragma unroll
                for (int ch = 0; ch < 2; ++ch)
#pragma unroll
                    for (int j = 0; j < 2; ++j) {
                        float v = (acc[rh][i][ch * 2 + j][r] + bv[ch * 2 + j]) * scale;
                        if (relu) v = fmaxf(v, 0.f);
                        C[base + ch * 32 + j * 16] = (__bf16)v;
                    }
            }
}

// ---------------------------------------------------------------------------
// Pipelined 256x128 GEMM (ff2 / out-proj, N=1024 -> 256 blocks).
// 8 waves as 4Mx2N: per-wave 64x64 output, 16 b128 reads/wave/tile.
__global__ __launch_bounds__(512, 2) void gemm8pN(
    const __bf16* __restrict__ A, const __bf16* __restrict__ B,
    const float* __restrict__ bias, __bf16* __restrict__ C,
    int N, int K, float scale, int relu)
{
    __shared__ __bf16 L[6][8192];      // 96 KiB: [par*3 + {0:A-top,1:A-bot,2:B}]
    const int tid = threadIdx.x;
    const int wid = tid >> 6, lane = tid & 63;
    const int lq = lane >> 4, lc = lane & 15;
    const int wr = (wid >> 1) * 64;    // wave row base: 0,64,128,192
    const int wc = (wid & 1) * 64;     // wave col base: 0 or 64
    const int ha = wr >> 7;            // A half slot (0/1)
    const int lr = wr & 127;           // row offset within half (0 or 64)
    const int sw = lc & 7;
    const int w = swz8(blockIdx.x, gridDim.x);
    const int nt = N >> 7;             // column panels (fastest within XCD run)
    const int bm = (w / nt) * 256, bn = (w % nt) * 128;
    const int NT = K >> 6;

    auto stageA = [&](int kt, int h) {
#pragma unroll
        for (int p = 0; p < 2; ++p) {
            const int cc = p * 512 + tid;
            const int row = cc >> 3, gk = ((cc & 7) ^ (row & 7)) * 8;
            load_lds16(A + (size_t)(bm + h * 128 + row) * K + (kt * 64 + gk),
                       &L[(kt & 1) * 3 + h][(size_t)cc * 8]);
        }
    };
    auto stageB = [&](int kt) {
#pragma unroll
        for (int p = 0; p < 2; ++p) {
            const int cc = p * 512 + tid;
            const int row = cc >> 3, gk = ((cc & 7) ^ (row & 7)) * 8;
            load_lds16(B + (size_t)(bn + row) * K + (kt * 64 + gk),
                       &L[(kt & 1) * 3 + 2][(size_t)cc * 8]);
        }
    };

    // prologue: stage K-tiles 0 and 1 (12 loads); wait tile 0 landed (6 left)
    stageA(0, 0); stageA(0, 1); stageB(0);
    stageA(1, 0); stageA(1, 1); stageB(1);
    asm volatile("s_waitcnt vmcnt(6)" ::: "memory");
    __builtin_amdgcn_s_barrier();
    __builtin_amdgcn_sched_barrier(0);

    const f32x4 fz = {0.f, 0.f, 0.f, 0.f};
    f32x4 acc[4][4];                    // [i rows][j cols]
#pragma unroll
    for (int i = 0; i < 4; ++i)
#pragma unroll
        for (int j = 0; j < 4; ++j) acc[i][j] = fz;

    for (int t = 0; t < NT; ++t) {
        const __bf16* __restrict__ Ah = &L[(t & 1) * 3 + ha][0];
        const __bf16* __restrict__ Bb = &L[(t & 1) * 3 + 2][0];
        const int pf = (t + 2 < NT);
        bf16x8 a[2][4], b[2][4];

        // ---- phase 0: read ALL tile-t fragments (16 b128); MFMA kk=0
#pragma unroll
        for (int kk = 0; kk < 2; ++kk) {
            const int sl = ((kk * 4 + lq) ^ sw) * 8;
#pragma unroll
            for (int i = 0; i < 4; ++i)
                a[kk][i] = *(const bf16x8*)&Ah[(lr + i * 16 + lc) * 64 + sl];
#pragma unroll
            for (int j = 0; j < 4; ++j)
                b[kk][j] = *(const bf16x8*)&Bb[(wc + j * 16 + lc) * 64 + sl];
        }
        __builtin_amdgcn_s_barrier();
        asm volatile("s_waitcnt lgkmcnt(0)" ::: "memory");
        __builtin_amdgcn_sched_barrier(0);
        __builtin_amdgcn_s_setprio(1);
#pragma unroll
        for (int i = 0; i < 4; ++i)
#pragma unroll
            for (int j = 0; j < 4; ++j)
                acc[i][j] = mfma16(a[0][i], b[0][j], acc[i][j]);
        __builtin_amdgcn_s_setprio(0);
        __builtin_amdgcn_s_barrier();
        __builtin_amdgcn_sched_barrier(0);

        // ---- phase 1: stage tile t+2 (all reads of parity done); MFMA kk=1
        if (pf) { stageB(t + 2); stageA(t + 2, 0); stageA(t + 2, 1); }
        __builtin_amdgcn_s_setprio(1);
#pragma unroll
        for (int i = 0; i < 4; ++i)
#pragma unroll
            for (int j = 0; j < 4; ++j)
                acc[i][j] = mfma16(a[1][i], b[1][j], acc[i][j]);
        __builtin_amdgcn_s_setprio(0);
        if (pf) asm volatile("s_waitcnt vmcnt(6)" ::: "memory");
        else    asm volatile("s_waitcnt vmcnt(0)" ::: "memory");
        __builtin_amdgcn_s_barrier();
        __builtin_amdgcn_sched_barrier(0);
    }

    // epilogue: row-major, full 128B line (4 x 16-col chunks) per row
    float bv[4];
#pragma unroll
    for (int q = 0; q < 4; ++q) bv[q] = bias[bn + wc + q * 16 + lc];
#pragma unroll
    for (int i = 0; i < 4; ++i)
#pragma unroll
        for (int r = 0; r < 4; ++r) {
            const int row = bm + wr + i * 16 + lq * 4 + r;
            const size_t base = (size_t)row * N + bn + wc + lc;
#pragma unroll
            for (int j = 0; j < 4; ++j) {
                float v = (acc[i][j][r] + bv[j]) * scale;
                if (relu) v = fmaxf(v, 0.f);
                C[base + j * 16] = (__bf16)v;
            }
        }
}

// ---------------------------------------------------------------------------
// Legacy 2-phase core (qkv): C[128 x BN] tile, BK=64, R3 swizzle.
template <int BN>
__device__ __forceinline__ void gemm_core(
    const __bf16* __restrict__ A, const __bf16* __restrict__ B,
    const float* __restrict__ bias, __bf16* __restrict__ C,
    int M, int N, int K, float scale, int relu, int bm, int bn,
    __bf16* As, __bf16* Bs)
{
    const int tid = threadIdx.x;
    const int wave = tid >> 6, lane = tid & 63;
    const int lq = lane >> 4, lc = lane & 15;
    const int WN = BN / 2;
    const int JT = WN / 16;
    const int wm = (wave >> 1) * 64, wn = (wave & 1) * WN;

    const f32x4 fz = {0.f, 0.f, 0.f, 0.f};
    f32x4 acc[4][4];
#pragma unroll
    for (int i = 0; i < 4; ++i)
#pragma unroll
        for (int j = 0; j < JT; ++j) acc[i][j] = fz;

    const int sw = lc & 7;

    for (int k0 = 0; k0 < K; k0 += 64) {
        __syncthreads();
#pragma unroll
        for (int i = 0; i < 4; ++i) {
            const int c = tid + 256 * i;
            const int row = c >> 3, gk = ((c & 7) ^ (row & 7)) * 8;
            load_lds16(A + (size_t)(bm + row) * K + (k0 + gk),
                       As + (size_t)c * 8);
        }
#pragma unroll
        for (int i = 0; i < BN / 32; ++i) {
            const int c = tid + 256 * i;
            const int row = c >> 3, gk = ((c & 7) ^ (row & 7)) * 8;
            load_lds16(B + (size_t)(bn + row) * K + (k0 + gk),
                       Bs + (size_t)c * 8);
        }
        __syncthreads();
#pragma unroll
        for (int kk = 0; kk < 2; ++kk) {
            bf16x8 af[4], bw[4];
            const int slot = ((kk * 4 + lq) ^ sw) * 8;
#pragma unroll
            for (int i = 0; i < 4; ++i)
                af[i] = *(const bf16x8*)&As[(wm + i * 16 + lc) * 64 + slot];
#pragma unroll
            for (int j = 0; j < JT; ++j)
                bw[j] = *(const bf16x8*)&Bs[(wn + j * 16 + lc) * 64 + slot];
#pragma unroll
            for (int i = 0; i < 4; ++i)
#pragma unroll
                for (int j = 0; j < JT; ++j)
                    acc[i][j] = mfma16(af[i], bw[j], acc[i][j]);
        }
    }

#pragma unroll
    for (int j = 0; j < JT; ++j) {
        const int col = bn + wn + j * 16 + lc;
        const float bv = bias[col];
#pragma unroll
        for (int i = 0; i < 4; ++i) {
#pragma unroll
            for (int r = 0; r < 4; ++r) {
                float v = (acc[i][j][r] + bv) * scale;
                if (relu) v = fmaxf(v, 0.f);
                const int row = bm + wm + i * 16 + lq * 4 + r;
                C[(size_t)row * N + col] = (__bf16)v;
            }
        }
    }
}

// Fused q/k/v projection: flat grid 1536 blocks, BN=64.
__global__ __launch_bounds__(256) void gemm_qkv(
    const __bf16* __restrict__ TGT, const __bf16* __restrict__ KIN,
    const __bf16* __restrict__ VIN, const __bf16* __restrict__ W,
    const float* __restrict__ bias, __bf16* __restrict__ PROJ,
    __bf16* __restrict__ KB, __bf16* __restrict__ VB)
{
    __shared__ __bf16 As[128 * 64];
    __shared__ __bf16 Bs[64 * 64];
    const int bid = swz8(blockIdx.x, 1536);   // XCD-contiguous tile runs
    const __bf16* A; __bf16* Cout; int M, t, seg; float scale;
    if (bid < 1024)      { seg = 0; t = bid;        A = TGT; Cout = PROJ; M = 8192; scale = 0.125f; }
    else if (bid < 1280) { seg = 1; t = bid - 1024; A = KIN; Cout = KB;   M = 2048; scale = 1.f; }
    else                 { seg = 2; t = bid - 1280; A = VIN; Cout = VB;   M = 2048; scale = 1.f; }
    gemm_core<64>(A, W + (size_t)seg * 1048576, bias + seg * 1024, Cout,
                  M, 1024, 1024, scale, 0, (t >> 4) * 128, (t & 15) * 64, As, Bs);
}

// ---------------------------------------------------------------------------
// transpose V per (n,h): vt[(n*16+h)*64 + d][s] = v[(s*2+n)*1024 + h*64 + d]
__global__ __launch_bounds__(256) void transpose_v(const __bf16* __restrict__ v,
                                                   __bf16* __restrict__ vt) {
    __shared__ __bf16 t[64][72];
    const int tid = threadIdx.x;
    const int s0 = blockIdx.x * 64, h = blockIdx.y, n = blockIdx.z;
#pragma unroll
    for (int i = 0; i < 2; ++i) {
        const int cc = tid + 256 * i, row = cc >> 3, kc = (cc & 7) * 8;
        *(uint4*)&t[row][kc] =
            *(const uint4*)(v + ((size_t)((s0 + row) * 2 + n)) * 1024 + h * 64 + kc);
    }
    __syncthreads();
#pragma unroll
    for (int i = 0; i < 2; ++i) {
        const int cc = tid + 256 * i, d = cc >> 3, jc = (cc & 7) * 8;
        __attribute__((aligned(16))) __bf16 tmp[8];
#pragma unroll
        for (int u = 0; u < 8; ++u) tmp[u] = t[jc + u][d];
        *(uint4*)(vt + ((size_t)((n * 16 + h) * 64 + d)) * 1024 + s0 + jc) = *(uint4*)tmp;
    }
}

// ---------------------------------------------------------------------------
// Fused attention (R2 math): O = (sum e^s v) / (1 + sum e^s); cvec saved.
// R12 layout: Q frags in registers (direct global), K/V in [64][64]
// XOR-swizzled LDS via global_load_lds, es [64][64] swizzled-chunk.
__global__ __launch_bounds__(256) void attn_fused(
    const __bf16* __restrict__ q, const __bf16* __restrict__ kk,
    const __bf16* __restrict__ vt, float* __restrict__ cvec,
    __bf16* __restrict__ aout)
{
    __shared__ __bf16 ks[64 * 64];
    __shared__ __bf16 vs[64 * 64];
    __shared__ __bf16 es[64 * 64];
    const int tid = threadIdx.x, wave = tid >> 6, lane = tid & 63;
    const int lq = lane >> 4, lc = lane & 15;
    const int o = (blockIdx.z * 16 + blockIdx.y) * 64 + blockIdx.x;
    const int w = swz8(o, 2048);
    const int l0 = (w & 63) * 64, h = (w >> 6) & 15, n = w >> 10;
    const int wr = wave * 16;
    const int sw = lc & 7;

    // Q fragments hoisted: row l0+wr+lc, cols k2*32+lq*8 (16B contiguous)
    bf16x8 aq[2];
#pragma unroll
    for (int k2 = 0; k2 < 2; ++k2)
        aq[k2] = *(const bf16x8*)(q + ((size_t)((l0 + wr + lc) * 2 + n)) * 1024
                                  + h * 64 + k2 * 32 + lq * 8);

    const f32x4 fz = {0.f, 0.f, 0.f, 0.f};
    f32x4 oacc[4];
#pragma unroll
    for (int dj = 0; dj < 4; ++dj) oacc[dj] = fz;
    float den[4] = {0.f, 0.f, 0.f, 0.f};

    for (int st = 0; st < 16; ++st) {
        __syncthreads();
        // async stage K,V tiles: pre-swizzled global source, linear LDS dest
#pragma unroll
        for (int i = 0; i < 2; ++i) {
            const int cc = tid + 256 * i;
            const int row = cc >> 3, gk = ((cc & 7) ^ (row & 7)) * 8;
            load_lds16(kk + ((size_t)((st * 64 + row) * 2 + n)) * 1024 + h * 64 + gk,
                       ks + (size_t)cc * 8);
            load_lds16(vt + ((size_t)((n * 16 + h) * 64 + row)) * 1024 + st * 64 + gk,
                       vs + (size_t)cc * 8);
        }
        __syncthreads();
#pragma unroll
        for (int sj = 0; sj < 4; ++sj) {
            f32x4 acc = fz;
#pragma unroll
            for (int k2 = 0; k2 < 2; ++k2) {
                const bf16x8 b =
                    *(const bf16x8*)&ks[(sj * 16 + lc) * 64 + ((k2 * 4 + lq) ^ sw) * 8];
                acc = mfma16(aq[k2], b, acc);
            }
#pragma unroll
            for (int r = 0; r < 4; ++r) {
                const float e = __expf(acc[r]);
                den[r] += e;
                const int R = wr + lq * 4 + r;
                es[R * 64 + (((sj * 2 + (lc >> 3)) ^ (R & 7)) * 8) + (lc & 7)] =
                    (__bf16)e;
            }
        }
        bf16x8 wv[2];
#pragma unroll
        for (int k2 = 0; k2 < 2; ++k2)
            wv[k2] = *(const bf16x8*)&es[(wr + lc) * 64 + ((k2 * 4 + lq) ^ sw) * 8];
#pragma unroll
        for (int dj = 0; dj < 4; ++dj) {
#pragma unroll
            for (int k2 = 0; k2 < 2; ++k2) {
                const bf16x8 vv =
                    *(const bf16x8*)&vs[(dj * 16 + lc) * 64 + ((k2 * 4 + lq) ^ sw) * 8];
                oacc[dj] = mfma16(wv[k2], vv, oacc[dj]);
            }
        }
    }
#pragma unroll
    for (int m = 1; m < 16; m <<= 1)
#pragma unroll
        for (int r = 0; r < 4; ++r) den[r] += __shfl_xor(den[r], m);
    float c_r[4];
#pragma unroll
    for (int r = 0; r < 4; ++r) c_r[r] = 1.f / (den[r] + 1.f);
    if (lc == 0) {
#pragma unroll
        for (int r = 0; r < 4; ++r)
            cvec[((size_t)(n * 16 + h)) * 4096 + (l0 + wr + lq * 4 + r)] = c_r[r];
    }
    // row-major store: each row's 128B head-slice in 4 consecutive stores
#pragma unroll
    for (int r = 0; r < 4; ++r) {
        const int l = l0 + wr + lq * 4 + r;
        const size_t base = ((size_t)l * 2 + n) * 1024 + h * 64 + lc;
#pragma unroll
        for (int dj = 0; dj < 4; ++dj)
            aout[base + dj * 16] = (__bf16)(oacc[dj][r] * c_r[r]);
    }
}

// ---------------------------------------------------------------------------
// attn_map[n][l][s] = mean_h sigmoid(w); sigmoid via Taylor poly on (0,1).
// R12: Q frags direct-global per h; K in [64][64] swizzled LDS (async).
__global__ __launch_bounds__(256) void attn_map_k(
    const __bf16* __restrict__ q, const __bf16* __restrict__ kk,
    const float* __restrict__ cvec, float* __restrict__ amap)
{
    __shared__ __bf16 ks[64 * 64];
    const int tid = threadIdx.x, wave = tid >> 6, lane = tid & 63;
    const int lq = lane >> 4, lc = lane & 15;
    const int o = (blockIdx.z * 16 + blockIdx.y) * 64 + blockIdx.x;
    const int w = swz8(o, 2048);
    const int l0 = (w & 63) * 64, st = (w >> 6) & 15, n = w >> 10;
    const int wr = wave * 16;
    const int sw = lc & 7;
    float sig[4][4];
#pragma unroll
    for (int sj = 0; sj < 4; ++sj)
#pragma unroll
        for (int r = 0; r < 4; ++r) sig[sj][r] = 0.f;

    for (int h = 0; h < 16; ++h) {
        __syncthreads();
#pragma unroll
        for (int i = 0; i < 2; ++i) {
            const int cc = tid + 256 * i;
            const int row = cc >> 3, gk = ((cc & 7) ^ (row & 7)) * 8;
            load_lds16(kk + ((size_t)((st * 64 + row) * 2 + n)) * 1024 + h * 64 + gk,
                       ks + (size_t)cc * 8);
        }
        __syncthreads();
        float c_r[4];
#pragma unroll
        for (int r = 0; r < 4; ++r)
            c_r[r] = cvec[((size_t)(n * 16 + h)) * 4096 + (l0 + wr + lq * 4 + r)];
        bf16x8 aq[2];
#pragma unroll
        for (int k2 = 0; k2 < 2; ++k2)
            aq[k2] = *(const bf16x8*)(q + ((size_t)((l0 + wr + lc) * 2 + n)) * 1024
                                      + h * 64 + k2 * 32 + lq * 8);
#pragma unroll
        for (int sj = 0; sj < 4; ++sj) {
            const f32x4 fz = {0.f, 0.f, 0.f, 0.f};
            f32x4 acc = fz;
#pragma unroll
            for (int k2 = 0; k2 < 2; ++k2) {
                const bf16x8 b =
                    *(const bf16x8*)&ks[(sj * 16 + lc) * 64 + ((k2 * 4 + lq) ^ sw) * 8];
                acc = mfma16(aq[k2], b, acc);
            }
#pragma unroll
            for (int r = 0; r < 4; ++r) {
                const float ww = __expf(acc[r]) * c_r[r];   // w in (0,1)
                const float w2 = ww * ww;
                sig[sj][r] += 0.5f + ww * (0.25f - w2 * (1.f / 48.f - w2 * (1.f / 480.f)));
            }
        }
    }
    // row-major store: each row's 256B s-slice in 4 consecutive stores
#pragma unroll
    for (int r = 0; r < 4; ++r) {
        const int l = l0 + wr + lq * 4 + r;
        const size_t base = ((size_t)n * 4096 + l) * 1024 + st * 64 + lc;
#pragma unroll
        for (int sj = 0; sj < 4; ++sj)
            amap[base + sj * 16] = sig[sj][r] * (1.f / 16.f);
    }
}

// ---------------------------------------------------------------------------
// y = LN(base + add) * g + b; base is f32 (basef) or bf16 (baseb).
__global__ __launch_bounds__(256) void ln_k(
    const float* __restrict__ basef, const __bf16* __restrict__ baseb,
    const __bf16* __restrict__ add,
    const float* __restrict__ g, const float* __restrict__ bb,
    float* __restrict__ out_f32, __bf16* __restrict__ out_bf)
{
    __shared__ float red[8];
    const int row = blockIdx.x, tid = threadIdx.x;
    const int col = tid * 4;
    const size_t off = (size_t)row * 1024 + col;
    float v[4];
    if (basef) {
        float4 t = *(const float4*)(basef + off);
        v[0] = t.x; v[1] = t.y; v[2] = t.z; v[3] = t.w;
    } else {
        union { uint2 u; __bf16 h[4]; } tb;
        tb.u = *(const uint2*)(baseb + off);
#pragma unroll
        for (int j = 0; j < 4; ++j) v[j] = (float)tb.h[j];
    }
    {
        union { uint2 u; __bf16 h[4]; } ub;
        ub.u = *(const uint2*)(add + off);
#pragma unroll
        for (int j = 0; j < 4; ++j) v[j] += (float)ub.h[j];
    }
    float s = v[0] + v[1] + v[2] + v[3];
    float q = v[0] * v[0] + v[1] * v[1] + v[2] * v[2] + v[3] * v[3];
#pragma unroll
    for (int m = 1; m < 64; m <<= 1) { s += __shfl_xor(s, m); q += __shfl_xor(q, m); }
    const int wave = tid >> 6, lane = tid & 63;
    if (lane == 0) { red[wave] = s; red[4 + wave] = q; }
    __syncthreads();
    s = red[0] + red[1] + red[2] + red[3];
    q = red[4] + red[5] + red[6] + red[7];
    const float mu = s * (1.f / 1024.f);
    const float var = q * (1.f / 1024.f) - mu * mu;
    const float rs = rsqrtf(var + 1e-5f);
    const float4 gv = *(const float4*)(g + col);
    const float4 bv = *(const float4*)(bb + col);
    float y[4];
    y[0] = (v[0] - mu) * rs * gv.x + bv.x;
    y[1] = (v[1] - mu) * rs * gv.y + bv.y;
    y[2] = (v[2] - mu) * rs * gv.z + bv.z;
    y[3] = (v[3] - mu) * rs * gv.w + bv.w;
    if (out_f32) {
        float4 o; o.x = y[0]; o.y = y[1]; o.z = y[2]; o.w = y[3];
        *(float4*)(out_f32 + off) = o;
    }
    if (out_bf) {
        union { uint2 u; __bf16 h[4]; } ob;
#pragma unroll
        for (int j = 0; j < 4; ++j) ob.h[j] = (__bf16)y[j];
        *(uint2*)(out_bf + off) = ob.u;
    }
}

// ---------------------------------------------------------------------------
extern "C" void kernel_launch(void* const* d_in, const int* in_sizes, int n_in,
                              void* d_out, int out_size, void* d_ws, size_t ws_size,
                              hipStream_t stream) {
    const float* key_in    = (const float*)d_in[0];
    const float* value_in  = (const float*)d_in[1];
    const float* query     = (const float*)d_in[2];
    const float* in_proj_w = (const float*)d_in[3];
    const float* in_proj_b = (const float*)d_in[4];
    const float* out_w     = (const float*)d_in[5];
    const float* out_b     = (const float*)d_in[6];
    const float* ln1_g     = (const float*)d_in[7];
    const float* ln1_b     = (const float*)d_in[8];
    const float* ln2_g     = (const float*)d_in[9];
    const float* ln2_b     = (const float*)d_in[10];
    const float* ff1_w     = (const float*)d_in[11];
    const float* ff1_b     = (const float*)d_in[12];
    const float* ff2_w     = (const float*)d_in[13];
    const float* ff2_b     = (const float*)d_in[14];
    float* outp = (float*)d_out;

    __bf16* ws = (__bf16*)d_ws;
    const size_t M1 = 1048576;
    __bf16* WQKV = ws;               // 6 M1 (both layers)
    __bf16* WOUT = ws + 6 * M1;      // 2
    __bf16* WF1  = ws + 8 * M1;      // 8
    __bf16* WF2  = ws + 16 * M1;     // 8
    __bf16* KIN  = ws + 24 * M1;     // 2
    __bf16* VIN  = ws + 26 * M1;     // 2
    __bf16* TGT  = ws + 28 * M1;     // 8
    __bf16* PROJ = ws + 36 * M1;     // 8 (q-proj out; out-proj out)
    __bf16* KB   = ws + 44 * M1;     // 2
    __bf16* VB   = ws + 46 * M1;     // 2
    __bf16* VT   = ws + 48 * M1;     // 2
    __bf16* AOUT = ws + 50 * M1;     // 8 (attn out; ff2 out)
    __bf16* XB   = ws + 58 * M1;     // 8 (ln1 out, bf16)
    __bf16* H1   = ws + 66 * M1;     // 32
    float*  CVEC = (float*)(ws + 98 * M1);   // 131072 f32

    // upfront casts: inputs + ALL weights (both layers)
    cast_k<<<8192, 256, 0, stream>>>(query, TGT, 2097152);
    cast_k<<<2048, 256, 0, stream>>>(key_in, KIN, 524288);
    cast_k<<<2048, 256, 0, stream>>>(value_in, VIN, 524288);
    cast_k<<<6144, 256, 0, stream>>>(in_proj_w, WQKV, 1572864);
    cast_k<<<2048, 256, 0, stream>>>(out_w, WOUT, 524288);
    cast_k<<<8192, 256, 0, stream>>>(ff1_w, WF1, 2097152);
    cast_k<<<8192, 256, 0, stream>>>(ff2_w, WF2, 2097152);

    for (int i = 0; i < 2; ++i) {
        __bf16* WQKVi = WQKV + (size_t)i * 3 * M1;
        __bf16* WOUTi = WOUT + (size_t)i * M1;
        __bf16* WF1i  = WF1 + (size_t)i * 4 * M1;
        __bf16* WF2i  = WF2 + (size_t)i * 4 * M1;

        // fused q/k/v projections (one dispatch, 1536 blocks)
        gemm_qkv<<<1536, 256, 0, stream>>>(TGT, KIN, VIN, WQKVi,
                                           in_proj_b + i * 3072, PROJ, KB, VB);
        transpose_v<<<dim3(16, 16, 2), 256, 0, stream>>>(VB, VT);

        attn_fused<<<dim3(64, 16, 2), 256, 0, stream>>>(PROJ, KB, VT, CVEC, AOUT);
        if (i == 1)
            attn_map_k<<<dim3(64, 16, 2), 256, 0, stream>>>(PROJ, KB, CVEC,
                                                            outp + 8388608);

        // out projection: pipelined 256x128 (256 blocks = 1 CU round)
        gemm8pN<<<256, 512, 0, stream>>>(AOUT, WOUTi, out_b + i * 1024,
                                         PROJ, 1024, 1024, 1.f, 0);
        // LN1: base = query (f32, layer 0) or TGT (bf16)
        ln_k<<<8192, 256, 0, stream>>>(i == 0 ? query : nullptr,
                                       i == 0 ? nullptr : TGT,
                                       PROJ, ln1_g + i * 1024, ln1_b + i * 1024,
                                       nullptr, XB);
        // FFN: ff1 via 8-phase 256x256 pipeline (512 blocks = 2 CU rounds),
        // ff2 via 256x128 pipeline (256 blocks, K=4096 deep pipeline)
        gemm8p<<<512, 512, 0, stream>>>(XB, WF1i, ff1_b + i * 4096,
                                        H1, 4096, 1024, 1.f, 1);
        gemm8pN<<<256, 512, 0, stream>>>(H1, WF2i, ff2_b + i * 1024,
                                         AOUT, 1024, 4096, 1.f, 0);
        // LN2: base = XB (bf16); final layer also writes f32 tgt to d_out
        ln_k<<<8192, 256, 0, stream>>>(nullptr, XB, AOUT,
                                       ln2_g + i * 1024, ln2_b + i * 1024,
                                       i == 1 ? outp : nullptr, TGT);
    }
}